// Round 12
// baseline (320.430 us; speedup 1.0000x reference)
//
#include <hip/hip_runtime.h>
#include <math.h>

typedef __attribute__((ext_vector_type(8))) short short8;
typedef __attribute__((ext_vector_type(4))) float f32x4;

#define BB 2
#define NN 2048
#define KK 32
#define HH 128
#define DFF 512
#define EPSF 1e-6f
#define INFV 1e30f

#define KNN_BLK 1024
#define PACK_BLK 2656
#define ORIENT_BLK 16

#define MFMA16(a, b, c) __builtin_amdgcn_mfma_f32_16x16x32_bf16((a), (b), (c), 0, 0, 0)

// ---------- helpers ----------

__device__ __forceinline__ unsigned short f2bf(float f) {
    unsigned u = __float_as_uint(f);
    u += 0x7fffu + ((u >> 16) & 1u);          // round-to-nearest-even
    return (unsigned short)(u >> 16);
}

__device__ __forceinline__ float bf2f(unsigned short h) {
    return __uint_as_float(((unsigned)h) << 16);
}

// split x into hi+lo bf16 pair — WEIGHTS only (systematic error must stay split)
__device__ __forceinline__ void f2bf2(float x, short& hi, short& lo) {
    unsigned short h = f2bf(x);
    hi = (short)h;
    lo = (short)f2bf(x - bf2f(h));
}

// pack 8 floats -> hi-plane short8
__device__ __forceinline__ short8 cvt8h(f32x4 a, f32x4 b) {
    short8 h8;
    #pragma unroll
    for (int i = 0; i < 4; i++) h8[i] = (short)f2bf(a[i]);
    #pragma unroll
    for (int i = 0; i < 4; i++) h8[4 + i] = (short)f2bf(b[i]);
    return h8;
}

__device__ __forceinline__ float sgnf(float x) {
    return (x > 0.f) ? 1.f : ((x < 0.f) ? -1.f : 0.f);
}

__device__ __forceinline__ void norm3(float& x, float& y, float& z) {
    float n = sqrtf(x * x + y * y + z * z);
    n = fmaxf(n, 1e-12f);
    x /= n; y /= n; z /= n;
}

// ---------- device bodies ----------

__device__ void knn_body(int bid4, const float* __restrict__ X,
                         const float* __restrict__ mask,
                         int* __restrict__ E_idx,
                         float* __restrict__ D_nb) {
    int w = threadIdx.x >> 6, lane = threadIdx.x & 63;
    int g = bid4 * 4 + w;
    int b = g >> 11, n = g & 2047;
    const float* Xb = X + (size_t)b * NN * 3;
    const float* mb = mask + (size_t)b * NN;

    float xn0 = Xb[n * 3], xn1 = Xb[n * 3 + 1], xn2 = Xb[n * 3 + 2];
    float mn = mb[n];

    float Dv[32], m2a[32];
    float lmax = -1e30f;
    #pragma unroll
    for (int s = 0; s < 32; s++) {
        int j = s * 64 + lane;
        float dx = Xb[j * 3] - xn0, dy = Xb[j * 3 + 1] - xn1, dz = Xb[j * 3 + 2] - xn2;
        float d = sqrtf(dx * dx + dy * dy + dz * dz + EPSF);
        float m2 = mn * mb[j];
        float v = m2 * d;
        Dv[s] = v; m2a[s] = m2;
        lmax = fmaxf(lmax, v);
    }
    #pragma unroll
    for (int off = 1; off <= 32; off <<= 1) lmax = fmaxf(lmax, __shfl_xor(lmax, off));
    float Dmax = lmax;
    #pragma unroll
    for (int s = 0; s < 32; s++) Dv[s] += (1.f - m2a[s]) * Dmax;

    // per-lane top-2 (strict < keeps earliest slot on exact ties)
    float l1 = INFV, l2 = INFV; int s1 = 0, s2 = 0;
    #pragma unroll
    for (int s = 0; s < 32; s++) {
        float v = Dv[s];
        bool lt1 = v < l1;
        bool lt2 = v < l2;
        float o1 = l1; int os1 = s1;
        l1 = lt1 ? v : l1;  s1 = lt1 ? s : s1;
        l2 = lt1 ? o1 : (lt2 ? v : l2);
        s2 = lt1 ? os1 : (lt2 ? s : s2);
    }

    unsigned used = 0u;
    float keepd = 0.f; int keepj = 0;

    for (int s = 0; s < KK; s++) {
        float m = l1;
        #pragma unroll
        for (int off = 1; off <= 32; off <<= 1) m = fminf(m, __shfl_xor(m, off));
        unsigned long long ball = __ballot(l1 == m);
        int jwin;
        if (__popcll(ball) == 1) {
            int src = (int)(__ffsll((long long)ball) - 1);
            jwin = __shfl(s1 * 64 + lane, src);
        } else {
            int jme = (l1 == m) ? (s1 * 64 + lane) : 0x7FFFFFFF;
            jwin = jme;
            #pragma unroll
            for (int off = 1; off <= 32; off <<= 1) jwin = min(jwin, __shfl_xor(jwin, off));
        }
        if (lane == s) { keepd = m; keepj = jwin; }
        if (lane == (jwin & 63)) {
            used |= 1u << s1;
            l1 = l2; s1 = s2;
            l2 = INFV;
            if (l1 >= INFV) {   // rare refill
                l1 = INFV; l2 = INFV;
                #pragma unroll
                for (int i = 0; i < 32; i++) {
                    float v = ((used >> i) & 1u) ? INFV : Dv[i];
                    bool lt1 = v < l1;
                    bool lt2 = v < l2;
                    float o1 = l1; int os1 = s1;
                    l1 = lt1 ? v : l1;  s1 = lt1 ? i : s1;
                    l2 = lt1 ? o1 : (lt2 ? v : l2);
                    s2 = lt1 ? os1 : (lt2 ? i : s2);
                }
            }
        }
    }
    if (lane < KK) {
        E_idx[(size_t)g * KK + lane] = keepj;
        D_nb[(size_t)g * KK + lane] = keepd;
    }
}

__device__ __forceinline__ void packB(const float* __restrict__ src, short* __restrict__ dH,
                                      short* __restrict__ dL, int e, int KC, int N, int Kreal) {
    int j = e & 7, ln = (e >> 3) & 63, t = e >> 9;
    int kc = t % KC, nt = t / KC;
    int k = kc * 32 + (ln >> 4) * 8 + j;
    int n = nt * 16 + (ln & 15);
    float v = (k < Kreal) ? src[(size_t)k * N + n] : 0.f;
    short hi, lo; f2bf2(v, hi, lo);
    dH[e] = hi; dL[e] = lo;
}

__device__ void pack_body(int e,
                          const float* __restrict__ We, const float* __restrict__ Wq,
                          const float* __restrict__ lW1, const float* __restrict__ lW2,
                          const float* __restrict__ lW3, const float* __restrict__ lWi,
                          const float* __restrict__ lWo, const float* __restrict__ Wv,
                          short* __restrict__ WeP, short* __restrict__ WqP,
                          short* __restrict__ W1bP, short* __restrict__ W2P,
                          short* __restrict__ W3P, short* __restrict__ WiP,
                          short* __restrict__ WoP, short* __restrict__ W1acP,
                          short* __restrict__ WvP) {
    if (e < 8192) { packB(We, WeP, WeP + 8192, e, 2, 128, 39); return; }
    e -= 8192;
    if (e < 16384) { packB(Wq, WqP, WqP + 16384, e, 4, 128, 128); return; }
    e -= 16384;
    if (e < 49152) {
        int l = e >> 14, r = e & 16383;
        packB(lW1 + (size_t)l * 49152 + 16384, W1bP + l * 32768, W1bP + l * 32768 + 16384, r, 4, 128, 128);
        return;
    }
    e -= 49152;
    if (e < 49152) {
        int l = e >> 14, r = e & 16383;
        packB(lW2 + (size_t)l * 16384, W2P + l * 32768, W2P + l * 32768 + 16384, r, 4, 128, 128);
        return;
    }
    e -= 49152;
    if (e < 49152) {
        int l = e >> 14, r = e & 16383;
        packB(lW3 + (size_t)l * 16384, W3P + l * 32768, W3P + l * 32768 + 16384, r, 4, 128, 128);
        return;
    }
    e -= 49152;
    if (e < 196608) {
        int l = e / 65536, r = e % 65536;
        packB(lWi + (size_t)l * 65536, WiP + l * 131072, WiP + l * 131072 + 65536, r, 4, 512, 128);
        return;
    }
    e -= 196608;
    if (e < 196608) {
        int l = e / 65536, r = e % 65536;
        packB(lWo + (size_t)l * 65536, WoP + l * 131072, WoP + l * 131072 + 65536, r, 16, 128, 512);
        return;
    }
    e -= 196608;
    if (e < 98304) {
        int l = e / 32768, r = e % 32768;
        int j = r & 7, ln = (r >> 3) & 63, t = r >> 9;
        int kc = t & 3, nt = t >> 2;
        int k = kc * 32 + (ln >> 4) * 8 + j;
        int n = nt * 16 + (ln & 15);
        const float* base = lW1 + (size_t)l * 49152;
        float v = (n < 128) ? base[(size_t)k * 128 + n] : base[(size_t)(256 + k) * 128 + (n - 128)];
        short hi, lo; f2bf2(v, hi, lo);
        short* dH = W1acP + l * 65536;
        dH[r] = hi; dH[32768 + r] = lo;
        return;
    }
    e -= 98304;
    // Wv pack (16384 elements)
    packB(Wv, WvP, WvP + 16384, e, 4, 128, 128);
}

__device__ void orient_body(int t, const float* __restrict__ X,
                            float* __restrict__ AD, float* __restrict__ Of) {
    if (t >= BB * NN) return;
    int b = t / NN, n = t % NN;
    float* ad = AD + (size_t)t * 3;
    float* of = Of + (size_t)t * 9;
    if (n < 1 || n > NN - 3) {
        ad[0] = ad[1] = ad[2] = 0.f;
        #pragma unroll
        for (int i = 0; i < 9; i++) of[i] = 0.f;
        return;
    }
    const float* Xb = X + (size_t)b * NN * 3;
    float p0x = Xb[(n - 1) * 3], p0y = Xb[(n - 1) * 3 + 1], p0z = Xb[(n - 1) * 3 + 2];
    float p1x = Xb[n * 3],       p1y = Xb[n * 3 + 1],       p1z = Xb[n * 3 + 2];
    float p2x = Xb[(n + 1) * 3], p2y = Xb[(n + 1) * 3 + 1], p2z = Xb[(n + 1) * 3 + 2];
    float p3x = Xb[(n + 2) * 3], p3y = Xb[(n + 2) * 3 + 1], p3z = Xb[(n + 2) * 3 + 2];

    float u2x = p1x - p0x, u2y = p1y - p0y, u2z = p1z - p0z; norm3(u2x, u2y, u2z);
    float u1x = p2x - p1x, u1y = p2y - p1y, u1z = p2z - p1z; norm3(u1x, u1y, u1z);
    float u0x = p3x - p2x, u0y = p3y - p2y, u0z = p3z - p2z; norm3(u0x, u0y, u0z);

    float n2x = u2y * u1z - u2z * u1y, n2y = u2z * u1x - u2x * u1z, n2z = u2x * u1y - u2y * u1x;
    norm3(n2x, n2y, n2z);
    float n1x = u1y * u0z - u1z * u0y, n1y = u1z * u0x - u1x * u0z, n1z = u1x * u0y - u1y * u0x;
    norm3(n1x, n1y, n1z);

    float cosA = -(u1x * u0x + u1y * u0y + u1z * u0z);
    cosA = fminf(fmaxf(cosA, -1.f + EPSF), 1.f - EPSF);
    float A = acosf(cosA);
    float cosD = n2x * n1x + n2y * n1y + n2z * n1z;
    cosD = fminf(fmaxf(cosD, -1.f + EPSF), 1.f - EPSF);
    float sg = sgnf(u2x * n1x + u2y * n1y + u2z * n1z);
    float Dih = sg * acosf(cosD);

    ad[0] = cosf(A);
    ad[1] = sinf(A) * cosf(Dih);
    ad[2] = sinf(A) * sinf(Dih);

    float o1x = u2x - u1x, o1y = u2y - u1y, o1z = u2z - u1z; norm3(o1x, o1y, o1z);
    float cx = o1y * n2z - o1z * n2y, cy = o1z * n2x - o1x * n2z, cz = o1x * n2y - o1y * n2x;
    of[0] = o1x; of[1] = o1y; of[2] = o1z;
    of[3] = n2x; of[4] = n2y; of[5] = n2z;
    of[6] = cx;  of[7] = cy;  of[8] = cz;
}

// ---------- FRONT: knn (blocks 0..1023) | pack (1024..3679) | orient (3680..3695) ----------

__global__ __launch_bounds__(256) void front_kernel(const float* __restrict__ X,
                                                    const float* __restrict__ mask,
                                                    int* __restrict__ E_idx,
                                                    float* __restrict__ D_nb,
                                                    const float* __restrict__ We,
                                                    const float* __restrict__ Wq,
                                                    const float* __restrict__ lW1,
                                                    const float* __restrict__ lW2,
                                                    const float* __restrict__ lW3,
                                                    const float* __restrict__ lWi,
                                                    const float* __restrict__ lWo,
                                                    const float* __restrict__ Wv,
                                                    short* __restrict__ WeP,
                                                    short* __restrict__ WqP,
                                                    short* __restrict__ W1bP,
                                                    short* __restrict__ W2P,
                                                    short* __restrict__ W3P,
                                                    short* __restrict__ WiP,
                                                    short* __restrict__ WoP,
                                                    short* __restrict__ W1acP,
                                                    short* __restrict__ WvP,
                                                    float* __restrict__ ADb,
                                                    float* __restrict__ Ofb) {
    int blk = blockIdx.x;
    if (blk < KNN_BLK) {
        knn_body(blk, X, mask, E_idx, D_nb);
    } else if (blk < KNN_BLK + PACK_BLK) {
        pack_body((blk - KNN_BLK) * 256 + threadIdx.x,
                  We, Wq, lW1, lW2, lW3, lWi, lWo, Wv,
                  WeP, WqP, W1bP, W2P, W3P, WiP, WoP, W1acP, WvP);
    } else {
        orient_body((blk - KNN_BLK - PACK_BLK) * 256 + threadIdx.x, X, ADb, Ofb);
    }
}

// ---------- MID: edge_feat (blocks 0..4095) | node_feat16 (4096..4351) ----------
// edge_feat: waves split over OUTPUT col-tiles (nt); hEbH output staged through
// LDS (AeH reuse) for coalesced short8 stores; Wq phase hi/lo split into two
// independent accumulator chains (2x MFMA ILP).

__global__ __launch_bounds__(128) void mid_kernel(const float* __restrict__ X,
                                                  const int* __restrict__ E_idx,
                                                  const float* __restrict__ D_nb,
                                                  const float* __restrict__ Of,
                                                  const float* __restrict__ be,
                                                  const float* __restrict__ ge,
                                                  const float* __restrict__ he,
                                                  const float* __restrict__ bq,
                                                  const short* __restrict__ WeP,
                                                  const short* __restrict__ WqP,
                                                  unsigned short* __restrict__ hEbH,
                                                  const float* __restrict__ AD,
                                                  const float* __restrict__ Wn,
                                                  const float* __restrict__ bn,
                                                  const float* __restrict__ gn,
                                                  const float* __restrict__ hn,
                                                  const short* __restrict__ WvP,
                                                  const float* __restrict__ bv,
                                                  const short* __restrict__ W1acP0,
                                                  const float* __restrict__ b1_0,
                                                  float* __restrict__ hV,
                                                  float* __restrict__ P,
                                                  float* __restrict__ Q) {
    __shared__ __align__(16) char smemRaw[15872];

    if (blockIdx.x < (unsigned)(BB * NN)) {
        // ----- edge_feat body -----
        short* AefH = (short*)smemRaw;                 // 32*72*2   = 4608 B
        short* AeH  = (short*)(smemRaw + 4608);        // 32*136*2  = 8704 B
        float* beS  = (float*)(smemRaw + 13312);       // 512 B
        float* geS  = beS + HH;
        float* heS  = geS + HH;
        float* bqS  = heS + HH;
        float* redSe = (float*)(smemRaw + 15360);      // [2][2][32] = 512 B

        int bid = blockIdx.x; int b = bid >> 11, n = bid & 2047; int tid = threadIdx.x;
        int lane = tid & 63, w = tid >> 6;
        beS[tid] = be[tid]; geS[tid] = ge[tid]; heS[tid] = he[tid]; bqS[tid] = bq[tid];
        {
            unsigned* Az = (unsigned*)AefH;
            for (int i = tid; i < 32 * 72 / 2; i += 128) Az[i] = 0u;
        }
        __syncthreads();

        int part = tid >> 5, k = tid & 31;
        int e = E_idx[(size_t)bid * KK + k];
        float dpos = (float)e - (float)n;
        if (part == 1 || part == 2) {
            int p0 = (part - 1) * 4;
            #pragma unroll
            for (int p = 0; p < 4; p++) {
                // freq = 10000^(-(p0+p)/8) = 10^(-(p0+p)/2) — compile-time constants
                float fr = (part == 1)
                    ? ((p == 0) ? 1.f : (p == 1) ? 0.31622776601683794f
                       : (p == 2) ? 0.1f : 0.031622776601683791f)
                    : ((p == 0) ? 0.01f : (p == 1) ? 0.0031622776601683794f
                       : (p == 2) ? 0.001f : 0.00031622776601683794f);
                float ang = dpos * fr;
                AefH[k * 72 + p0 + p]     = (short)f2bf(__cosf(ang));
                AefH[k * 72 + 8 + p0 + p] = (short)f2bf(__sinf(ang));
            }
        } else if (part == 3) {
            float Dv = D_nb[(size_t)bid * KK + k];
            #pragma unroll
            for (int i = 0; i < 16; i++) {
                float m = (20.f / 15.f) * (float)i;
                float z = (Dv - m) * 0.8f;
                AefH[k * 72 + 16 + i] = (short)f2bf(__expf(-z * z));
            }
        } else {
            const float* Omp = Of + (size_t)(b * NN + n) * 9;
            const float* Onp = Of + (size_t)(b * NN + e) * 9;
            float Om[9], On[9];
            #pragma unroll
            for (int i = 0; i < 9; i++) { Om[i] = Omp[i]; On[i] = Onp[i]; }
            float vx = X[(size_t)(b * NN + e) * 3 + 0] - X[(size_t)(b * NN + n) * 3 + 0];
            float vy = X[(size_t)(b * NN + e) * 3 + 1] - X[(size_t)(b * NN + n) * 3 + 1];
            float vz = X[(size_t)(b * NN + e) * 3 + 2] - X[(size_t)(b * NN + n) * 3 + 2];
            float t0 = Om[0] * vx + Om[1] * vy + Om[2] * vz;
            float t1 = Om[3] * vx + Om[4] * vy + Om[5] * vz;
            float t2 = Om[6] * vx + Om[7] * vy + Om[8] * vz;
            float nr = fmaxf(sqrtf(t0 * t0 + t1 * t1 + t2 * t2), 1e-12f);
            AefH[k * 72 + 32] = (short)f2bf(t0 / nr);
            AefH[k * 72 + 33] = (short)f2bf(t1 / nr);
            AefH[k * 72 + 34] = (short)f2bf(t2 / nr);
            float R[9];
            #pragma unroll
            for (int i = 0; i < 3; i++)
                #pragma unroll
                for (int l = 0; l < 3; l++)
                    R[i * 3 + l] = Om[0 + i] * On[0 + l] + Om[3 + i] * On[3 + l] + Om[6 + i] * On[6 + l];
            float Rxx = R[0], Ryy = R[4], Rzz = R[8];
            float mx = 0.5f * sqrtf(fabsf(1.f + Rxx - Ryy - Rzz));
            float my = 0.5f * sqrtf(fabsf(1.f - Rxx + Ryy - Rzz));
            float mz = 0.5f * sqrtf(fabsf(1.f - Rxx - Ryy + Rzz));
            float qx = sgnf(R[7] - R[5]) * mx;
            float qy = sgnf(R[2] - R[6]) * my;
            float qz = sgnf(R[3] - R[1]) * mz;
            float qw = 0.5f * sqrtf(fmaxf(1.f + Rxx + Ryy + Rzz, 0.f));
            float qn = fmaxf(sqrtf(qx * qx + qy * qy + qz * qz + qw * qw), 1e-12f);
            AefH[k * 72 + 35] = (short)f2bf(qx / qn);
            AefH[k * 72 + 36] = (short)f2bf(qy / qn);
            AefH[k * 72 + 37] = (short)f2bf(qz / qn);
            AefH[k * 72 + 38] = (short)f2bf(qw / qn);
        }
        __syncthreads();

        int m = lane & 15, q = lane >> 4;
        // A-frags: both row-tiles (t), this wave covers all 32 edges
        short8 aW[2][2];
        #pragma unroll
        for (int t = 0; t < 2; t++) {
            int row = (t * 16 + m) * 72;
            aW[t][0] = *(const short8*)&AefH[row + q * 8];
            aW[t][1] = *(const short8*)&AefH[row + 32 + q * 8];
        }
        f32x4 accA[4][2];   // [nt4][t]
        #pragma unroll
        for (int nt4 = 0; nt4 < 4; nt4++) {
            int ntg = w * 4 + nt4;
            const short* B0 = &WeP[((ntg * 2 + 0) * 64 + lane) * 8];
            const short* B1 = &WeP[((ntg * 2 + 1) * 64 + lane) * 8];
            short8 b0h = *(const short8*)B0, b0l = *(const short8*)(B0 + 8192);
            short8 b1h = *(const short8*)B1, b1l = *(const short8*)(B1 + 8192);
            float bc = beS[ntg * 16 + m];
            #pragma unroll
            for (int t = 0; t < 2; t++) {
                f32x4 acc = {bc, bc, bc, bc};
                acc = MFMA16(aW[t][0], b0h, acc);
                acc = MFMA16(aW[t][0], b0l, acc);
                acc = MFMA16(aW[t][1], b1h, acc);
                acc = MFMA16(aW[t][1], b1l, acc);
                accA[nt4][t] = acc;
            }
        }
        // cross-wave LN: partial su/sq per row over this wave's 64 cols
        #pragma unroll
        for (int t = 0; t < 2; t++)
            #pragma unroll
            for (int r = 0; r < 4; r++) {
                float su = accA[0][t][r] + accA[1][t][r] + accA[2][t][r] + accA[3][t][r];
                float sq2 = accA[0][t][r] * accA[0][t][r] + accA[1][t][r] * accA[1][t][r]
                          + accA[2][t][r] * accA[2][t][r] + accA[3][t][r] * accA[3][t][r];
                #pragma unroll
                for (int off = 1; off <= 8; off <<= 1) {
                    su += __shfl_xor(su, off); sq2 += __shfl_xor(sq2, off);
                }
                if (m == 0) {
                    int row = t * 16 + q * 4 + r;
                    redSe[(w * 2 + 0) * 32 + row] = su;
                    redSe[(w * 2 + 1) * 32 + row] = sq2;
                }
            }
        __syncthreads();
        float muA[2][4], invA[2][4];
        #pragma unroll
        for (int t = 0; t < 2; t++)
            #pragma unroll
            for (int r = 0; r < 4; r++) {
                int row = t * 16 + q * 4 + r;
                float S  = redSe[0 * 32 + row] + redSe[2 * 32 + row];
                float Q2 = redSe[1 * 32 + row] + redSe[3 * 32 + row];
                float mu = S * (1.f / HH);
                float var = (Q2 - (float)HH * mu * mu) * (1.f / (HH - 1));
                muA[t][r] = mu;
                invA[t][r] = 1.f / (sqrtf(var + EPSF) + EPSF);
            }
        #pragma unroll
        for (int nt4 = 0; nt4 < 4; nt4++) {
            int col = (w * 4 + nt4) * 16 + m;
            float g = geS[col], hh = heS[col];
            #pragma unroll
            for (int t = 0; t < 2; t++)
                #pragma unroll
                for (int r = 0; r < 4; r++) {
                    int edge = t * 16 + q * 4 + r;
                    float y = g * (accA[nt4][t][r] - muA[t][r]) * invA[t][r] + hh;
                    AeH[edge * 136 + col] = (short)f2bf(y);
                }
        }
        __syncthreads();

        short8 ah[2][4];
        #pragma unroll
        for (int t = 0; t < 2; t++)
            #pragma unroll
            for (int kc = 0; kc < 4; kc++)
                ah[t][kc] = *(const short8*)&AeH[(t * 16 + m) * 136 + kc * 32 + q * 8];
        __syncthreads();   // all A-frag preloads done — AeH becomes output staging

        #pragma unroll
        for (int nt4 = 0; nt4 < 4; nt4++) {
            int ntg = w * 4 + nt4;
            int col = ntg * 16 + m;
            short8 qh[4], ql[4];
            #pragma unroll
            for (int kc = 0; kc < 4; kc++) {
                const short* Bp = &WqP[((ntg * 4 + kc) * 64 + lane) * 8];
                qh[kc] = *(const short8*)Bp;
                ql[kc] = *(const short8*)(Bp + 16384);
            }
            float bc = bqS[col];
            #pragma unroll
            for (int t = 0; t < 2; t++) {
                f32x4 accH = {bc, bc, bc, bc};
                f32x4 accL = {0.f, 0.f, 0.f, 0.f};
                #pragma unroll
                for (int kc = 0; kc < 4; kc++) {
                    accH = MFMA16(ah[t][kc], qh[kc], accH);
                    accL = MFMA16(ah[t][kc], ql[kc], accL);
                }
                #pragma unroll
                for (int r = 0; r < 4; r++) {
                    int edge = t * 16 + q * 4 + r;
                    AeH[edge * 136 + col] = (short)f2bf(accH[r] + accL[r]);
                }
            }
        }
        __syncthreads();

        // coalesced copy-out: 512 short8 chunks, 4 per thread (256B contiguous/row)
        {
            unsigned short* outp = hEbH + (size_t)bid * (KK * HH);
            #pragma unroll
            for (int it = 0; it < 4; it++) {
                int idx = it * 128 + tid;       // 0..511
                int row = idx >> 4, c8 = idx & 15;
                *(short8*)(outp + row * HH + c8 * 8) = *(const short8*)&AeH[row * 136 + c8 * 8];
            }
        }
    } else {
        // ----- node_feat body: 16 nodes per block, MFMA path -----
        short* yH  = (short*)smemRaw;                  // 16*136*2 = 4352 B
        short* hvH = (short*)(smemRaw + 4352);         // 4352 B

        int nb = blockIdx.x - BB * NN;
        int g0 = nb * 16;
        int tid = threadIdx.x;
        int lane = tid & 63, w = tid >> 6;
        int m = lane & 15, q = lane >> 4;

        // step 1: V = AD @ Wn + bn, per-node LN -> y (bf16 in LDS)
        {
            int i = tid >> 3;          // node 0..15
            int j = tid & 7;           // column group (16 cols each)
            int h0 = j * 16;
            const float* ad = AD + (size_t)(g0 + i) * 3;
            float a0 = ad[0], a1 = ad[1], a2 = ad[2];
            float v[16];
            float su = 0.f, sq = 0.f;
            #pragma unroll
            for (int c = 0; c < 16; c++) {
                int h = h0 + c;
                float t = bn[h] + a0 * Wn[h] + a1 * Wn[HH + h] + a2 * Wn[2 * HH + h];
                v[c] = t; su += t; sq += t * t;
            }
            #pragma unroll
            for (int off = 1; off <= 4; off <<= 1) {
                su += __shfl_xor(su, off); sq += __shfl_xor(sq, off);
            }
            float mu = su * (1.f / HH);
            float var = (sq - (float)HH * mu * mu) * (1.f / (HH - 1));
            float inv = 1.f / (sqrtf(var + EPSF) + EPSF);
            #pragma unroll
            for (int c = 0; c < 16; c++) {
                int h = h0 + c;
                yH[i * 136 + h] = (short)f2bf(gn[h] * (v[c] - mu) * inv + hn[h]);
            }
        }
        __syncthreads();

        // step 2: hV = y @ Wv + bv  (wave handles 4 of 8 col-tiles)
        short8 ayh[4];
        #pragma unroll
        for (int kc = 0; kc < 4; kc++)
            ayh[kc] = *(const short8*)&yH[m * 136 + kc * 32 + q * 8];
        #pragma unroll
        for (int u = 0; u < 4; u++) {
            int nt = w * 4 + u;
            int col = nt * 16 + m;
            float bc = bv[col];
            f32x4 aH = {bc, bc, bc, bc};
            f32x4 aL = {0.f, 0.f, 0.f, 0.f};
            #pragma unroll
            for (int kc = 0; kc < 4; kc++) {
                const short* Bp = &WvP[((nt * 4 + kc) * 64 + lane) * 8];
                short8 bh = *(const short8*)Bp, bl = *(const short8*)(Bp + 16384);
                aH = MFMA16(ayh[kc], bh, aH);
                aL = MFMA16(ayh[kc], bl, aL);
            }
            #pragma unroll
            for (int r = 0; r < 4; r++) {
                int rw = q * 4 + r;
                float vv = aH[r] + aL[r];
                hV[(size_t)(g0 + rw) * HH + col] = vv;
                hvH[rw * 136 + col] = (short)f2bf(vv);
            }
        }
        __syncthreads();

        // step 3: layer-0 premix P/Q = hV @ W1_0[a|c] (+b1 for P), via packed W1acP[0]
        short8 avh[4];
        #pragma unroll
        for (int kc = 0; kc < 4; kc++)
            avh[kc] = *(const short8*)&hvH[m * 136 + kc * 32 + q * 8];
        #pragma unroll
        for (int u = 0; u < 8; u++) {
            int nt = w * 8 + u;
            int col = nt * 16 + m;
            float b0 = (nt < 8) ? b1_0[col] : 0.f;
            f32x4 aH = {b0, b0, b0, b0};
            f32x4 aL = {0.f, 0.f, 0.f, 0.f};
            #pragma unroll
            for (int kc = 0; kc < 4; kc++) {
                const short* Bp = &W1acP0[((nt * 4 + kc) * 64 + lane) * 8];
                short8 bh = *(const short8*)Bp, bl = *(const short8*)(Bp + 32768);
                aH = MFMA16(avh[kc], bh, aH);
                aL = MFMA16(avh[kc], bl, aL);
            }
            #pragma unroll
            for (int r = 0; r < 4; r++) {
                size_t rw = g0 + q * 4 + r;
                float vv = aH[r] + aL[r];
                if (nt < 8) P[rw * HH + col] = vv;
                else        Q[rw * HH + (col - 128)] = vv;
            }
        }
    }
}

// ---------- message kernel: block = 2 nodes, 4 waves, 2 nt-tiles per wave ----------
// hi/lo weight planes accumulate in independent chains (2x MFMA ILP per phase).

__global__ __launch_bounds__(256) void msg_kernel(const float* __restrict__ mask,
                                                  const int* __restrict__ E_idx,
                                                  const unsigned short* __restrict__ hEbH,
                                                  const float* __restrict__ P,
                                                  const float* __restrict__ Q,
                                                  const short* __restrict__ W1bP,
                                                  const short* __restrict__ W2P,
                                                  const float* __restrict__ b2,
                                                  float* __restrict__ sOut,
                                                  float* __restrict__ cntOut) {
    __shared__ short stg[2][32 * 136];   // staged h_E (bf16) per node
    __shared__ short AmH[2][32 * 136];   // m1 (bf16) per node

    int tid = threadIdx.x;
    int w = tid >> 6, lane = tid & 63;
    int gA = blockIdx.x * 2;             // nodes gA, gA+1 (same batch: NN even)
    int b = gA >> 11;
    int m = lane & 15, q = lane >> 4;

    // ---- stage hEbH for both nodes (fully coalesced short8 loads) ----
    {
        const short8* src = (const short8*)(hEbH + (size_t)gA * (KK * HH));
        #pragma unroll
        for (int it = 0; it < 4; it++) {
            int idx = it * 256 + tid;        // 0..1023 short8 chunks
            int nd = idx >> 9;
            int rem = idx & 511;
            int e = rem >> 4;                // edge
            int c8 = rem & 15;               // col/8
            short8 v = src[idx];
            *(short8*)&stg[nd][e * 136 + c8 * 8] = v;
        }
    }

    int qbase[2][2][4]; float mt[2][2][4];
    #pragma unroll
    for (int nd = 0; nd < 2; nd++) {
        float maskv = mask[gA + nd];
        #pragma unroll
        for (int t = 0; t < 2; t++)
            #pragma unroll
            for (int r = 0; r < 4; r++) {
                int row = t * 16 + q * 4 + r;
                int e = E_idx[(size_t)(gA + nd) * KK + row];
                qbase[nd][t][r] = (b * NN + e) * HH;
                mt[nd][t][r] = maskv * mask[b * NN + e];
            }
    }
    if (w < 2) {
        // wave w (0,1) produces cnt for node w
        float c8 = mt[w][0][0] + mt[w][0][1] + mt[w][0][2] + mt[w][0][3]
                 + mt[w][1][0] + mt[w][1][1] + mt[w][1][2] + mt[w][1][3];
        c8 += __shfl_xor(c8, 16);
        c8 += __shfl_xor(c8, 32);
        if (lane == 0) cntOut[gA + w] = c8;
    }

    float preg[2][2], b2reg[2];
    #pragma unroll
    for (int u = 0; u < 2; u++) {
        int colg = (w * 2 + u) * 16 + m;
        b2reg[u] = b2[colg];
        preg[0][u] = P[(size_t)gA * HH + colg];
        preg[1][u] = P[(size_t)(gA + 1) * HH + colg];
    }
    __syncthreads();

    // phase 1: m1 = relu(P + Q[nbr] + h_E @ W1b) — wave handles 2 nt tiles, both nodes
    #pragma unroll
    for (int u = 0; u < 2; u++) {
        int ntg = w * 2 + u;
        int colg = ntg * 16 + m;
        short8 bh[4], bl[4];
        #pragma unroll
        for (int kc = 0; kc < 4; kc++) {
            const short* Bp = &W1bP[((ntg * 4 + kc) * 64 + lane) * 8];
            bh[kc] = *(const short8*)Bp;
            bl[kc] = *(const short8*)(Bp + 16384);
        }
        #pragma unroll
        for (int nd = 0; nd < 2; nd++) {
            f32x4 t0a = {0.f, 0.f, 0.f, 0.f}, t0b = {0.f, 0.f, 0.f, 0.f};
            f32x4 t1a = {0.f, 0.f, 0.f, 0.f}, t1b = {0.f, 0.f, 0.f, 0.f};
            #pragma unroll
            for (int kc = 0; kc < 4; kc++) {
                short8 a0 = *(const short8*)&stg[nd][(0 * 16 + m) * 136 + kc * 32 + q * 8];
                short8 a1 = *(const short8*)&stg[nd][(1 * 16 + m) * 136 + kc * 32 + q * 8];
                t0a = MFMA16(a0, bh[kc], t0a);
                t0b = MFMA16(a0, bl[kc], t0b);
                t1a = MFMA16(a1, bh[kc], t1a);
                t1b = MFMA16(a1, bl[kc], t1b);
            }
            float pp = preg[nd][u];
            #pragma unroll
            for (int r = 0; r < 4; r++) {
                float v0 = fmaxf(t0a[r] + t0b[r] + pp + Q[(size_t)qbase[nd][0][r] + colg], 0.f);
                AmH[nd][(q * 4 + r) * 136 + colg] = (short)f2bf(v0);
                float v1 = fmaxf(t1a[r] + t1b[r] + pp + Q[(size_t)qbase[nd][1][r] + colg], 0.f);
                AmH[nd][(16 + q * 4 + r) * 136 + colg] = (short)f2bf(v1);
            }
        }
    }
    __syncthreads();

    // phase 2: m2 = relu(m1 @ W2 + b2); masked sum over 32 edges
    #pragma unroll
    for (int u = 0; u < 2; u++) {
        int ntg = w * 2 + u;
        short8 bh[4], bl[4];
        #pragma unroll
        for (int kc = 0; kc < 4; kc++) {
            const short* Bp = &W2P[((ntg * 4 + kc) * 64 + lane) * 8];
            bh[kc] = *(const short8*)Bp;
            bl[kc] = *(const short8*)(Bp + 16384);
        }
        float bc = b2reg[u];
        #pragma unroll
        for (int nd = 0; nd < 2; nd++) {
            f32x4 a0a = {bc, bc, bc, bc}, a0b = {0.f, 0.f, 0.f, 0.f};
            f32x4 a1a = {bc, bc, bc, bc}, a1b = {0.f, 0.f, 0.f, 0.f};
            #pragma unroll
            for (int kc = 0; kc < 4; kc++) {
                short8 m0 = *(const short8*)&AmH[nd][(0 * 16 + m) * 136 + kc * 32 + q * 8];
                short8 m1 = *(const short8*)&AmH[nd][(1 * 16 + m) * 136 + kc * 32 + q * 8];
                a0a = MFMA16(m0, bh[kc], a0a);
                a0b = MFMA16(m0, bl[kc], a0b);
                a1a = MFMA16(m1, bh[kc], a1a);
                a1b = MFMA16(m1, bl[kc], a1b);
            }
            float part = 0.f;
            #pragma unroll
            for (int r = 0; r < 4; r++)
                part += fmaxf(a0a[r] + a0b[r], 0.f) * mt[nd][0][r]
                      + fmaxf(a1a[r] + a1b[r], 0.f) * mt[nd][1][r];
            part += __shfl_xor(part, 16);
            part += __shfl_xor(part, 32);
            if (q == 0) sOut[(size_t)(gA + nd) * HH + ntg * 16 + m] = part;
        }
    }
}

// ---------- node kernel: 8 waves (512 threads), 16 nodes/block ----------
// hi/lo weight planes accumulate in independent chains (2x MFMA ILP per phase).

#define HSTR 520   // LDS stride (shorts) for 512-wide hidden staging

__global__ __launch_bounds__(512, 2) void node_kernel(const float* __restrict__ mask,
                                                      const float* __restrict__ sbuf,
                                                      const float* __restrict__ cntb,
                                                      const float* __restrict__ hVin,
                                                      const short* __restrict__ W3P,
                                                      const float* __restrict__ b3,
                                                      const short* __restrict__ WiP,
                                                      const float* __restrict__ biN,
                                                      const short* __restrict__ WoP,
                                                      const float* __restrict__ boN,
                                                      const float* __restrict__ g0,
                                                      const float* __restrict__ h0,
                                                      const float* __restrict__ g1,
                                                      const float* __restrict__ h1,
                                                      const short* __restrict__ W1P,
                                                      const float* __restrict__ b1n,
                                                      float* __restrict__ hVout,
                                                      float* __restrict__ Pn,
                                                      float* __restrict__ Qn) {
    __shared__ short rbH[16 * 136];
    __shared__ short hbH[16 * HSTR];
    __shared__ float redS[8][2][16];
    __shared__ float g0S[128], h0S[128], g1S[128], h1S[128], b3S[128], boS[128], b1S[128];
    __shared__ float biS[512];

    int tid = threadIdx.x;
    int w = tid >> 6, lane = tid & 63;
    int m = lane & 15, q = lane >> 4;
    int rowT = blockIdx.x * 16;

    if (tid < 128) {
        int i = tid;
        g0S[i] = g0[i]; h0S[i] = h0[i]; g1S[i] = g1[i]; h1S[i] = h1[i];
        b3S[i] = b3[i]; boS[i] = boN[i]; b1S[i] = W1P ? b1n[i] : 0.f;
    }
    biS[tid] = biN[tid];
    __syncthreads();

    short8 ash[4];
    #pragma unroll
    for (int kc = 0; kc < 4; kc++) {
        const float* sp = &sbuf[(size_t)(rowT + m) * HH + kc * 32 + q * 8];
        f32x4 x0 = *(const f32x4*)sp;
        f32x4 x1 = *(const f32x4*)(sp + 4);
        ash[kc] = cvt8h(x0, x1);
    }
    float cntr[4];
    #pragma unroll
    for (int r = 0; r < 4; r++) cntr[r] = cntb[rowT + q * 4 + r];

    // W3: wave w owns col-tile w
    f32x4 vC;
    {
        f32x4 aH = {0.f, 0.f, 0.f, 0.f};
        f32x4 aL = {0.f, 0.f, 0.f, 0.f};
        #pragma unroll
        for (int kc = 0; kc < 4; kc++) {
            const short* Bp = &W3P[((w * 4 + kc) * 64 + lane) * 8];
            short8 bh = *(const short8*)Bp, bl = *(const short8*)(Bp + 16384);
            aH = MFMA16(ash[kc], bh, aH);
            aL = MFMA16(ash[kc], bl, aL);
        }
        int col = w * 16 + m;
        #pragma unroll
        for (int r = 0; r < 4; r++) {
            float tv = (aH[r] + aL[r] + cntr[r] * b3S[col]) * (1.f / 30.f);
            vC[r] = hVin[(size_t)(rowT + q * 4 + r) * HH + col] + tv;
        }
    }

    // LN0 (cross-8-wave)
    {
        float su[4], sq[4];
        #pragma unroll
        for (int r = 0; r < 4; r++) { float v = vC[r]; su[r] = v; sq[r] = v * v; }
        #pragma unroll
        for (int off = 1; off <= 8; off <<= 1)
            #pragma unroll
            for (int r = 0; r < 4; r++) { su[r] += __shfl_xor(su[r], off); sq[r] += __shfl_xor(sq[r], off); }
        if (m == 0) {
            #pragma unroll
            for (int r = 0; r < 4; r++) { redS[w][0][q * 4 + r] = su[r]; redS[w][1][q * 4 + r] = sq[r]; }
        }
    }
    __syncthreads();
    float mu[4], inv[4];
    #pragma unroll
    for (int r = 0; r < 4; r++) {
        int row = q * 4 + r;
        float S = 0.f, Q2 = 0.f;
        #pragma unroll
        for (int ww = 0; ww < 8; ww++) { S += redS[ww][0][row]; Q2 += redS[ww][1][row]; }
        mu[r] = S * (1.f / HH);
        float var = (Q2 - (float)HH * mu[r] * mu[r]) * (1.f / (HH - 1));
        inv[r] = 1.f / (sqrtf(var + EPSF) + EPSF);
    }
    {
        int col = w * 16 + m;
        #pragma unroll
        for (int r = 0; r < 4; r++) {
            vC[r] = g0S[col] * (vC[r] - mu[r]) * inv[r] + h0S[col];
            rbH[(q * 4 + r) * 136 + col] = (short)f2bf(vC[r]);
        }
    }
    __syncthreads();

    short8 avh[4];
    #pragma unroll
    for (int kc = 0; kc < 4; kc++)
        avh[kc] = *(const short8*)&rbH[m * 136 + kc * 32 + q * 8];

    // FFN-in: wave's 64 hidden cols (4 of 32 tiles)
    #pragma unroll
    for (int u = 0; u < 4; u++) {
        int nt = w * 4 + u;
        int jcol = nt * 16 + m;
        float bb = biS[jcol];
        f32x4 aH = {bb, bb, bb, bb};
        f32x4 aL = {0.f, 0.f, 0.f, 0.f};
        #pragma unroll
        for (int kc = 0; kc < 4; kc++) {
            const short* Bp = &WiP[((nt * 4 + kc) * 64 + lane) * 8];
            short8 bh = *(const short8*)Bp, bl = *(const short8*)(Bp + 65536);
            aH = MFMA16(avh[kc], bh, aH);
            aL = MFMA16(avh[kc], bl, aL);
        }
        #pragma unroll
        for (int r = 0; r < 4; r++)
            hbH[(q * 4 + r) * HSTR + jcol] = (short)f2bf(fmaxf(aH[r] + aL[r], 0.f));
    }
    __syncthreads();

    // FFN-out: wave's col-tile w over ALL 512 hidden (hi/lo chains)
    f32x4 oH = {0.f, 0.f, 0.f, 0.f};
    f32x4 oL = {0.f, 0.f, 0.f, 0.f};
    for (int kc2 = 0; kc2 < 16; kc2++) {
        short8 ahh = *(const short8*)&hbH[m * HSTR + kc2 * 32 + q * 8];
        const short* Bp = &WoP[((w * 16 + kc2) * 64 + lane) * 8];
        short8 bh = *(const short8*)Bp, bl = *(const short8*)(Bp + 65536);
        oH = MFMA16(ahh, bh, oH);
        oL = MFMA16(ahh, bl, oL);
    }
    f32x4 oC;
    {
        int col = w * 16 + m;
        #pragma unroll
        for (int r = 0; r < 4; r++)
            oC[r] = oH[r] + oL[r] + boS[col] + vC[r];
    }

    // LN1 (cross-8-wave)
    {
        float su[4], sq[4];
        #pragma unroll
        for (int r = 0; r < 4; r++) { float v = oC[r]; su[r] = v; sq[r] = v * v; }
        #pragma unroll
        for (int off = 1; off <= 8; off <<= 1)
            #pragma unroll
            for (int r = 0; r < 4; r++) { su[r] += __shfl_xor(su[r], off); sq[r] += __shfl_xor(sq[r], off); }
        __syncthreads();   // redS reuse
        if (m == 0) {
            #pragma unroll
            for (int r = 0; r < 4; r++) { redS[w][0][q * 4 + r] = su[r]; redS[w][1][q * 4 + r] = sq[r]; }
        }
    }
    __syncthreads();
    #pragma unroll
    for (int r = 0; r < 4; r++) {
        int row = q * 4 + r;
        float S = 0.f, Q2 = 0.f;
        #pragma unroll
        for (int ww = 0; ww < 8; ww++) { S += redS[ww][0][row]; Q2 += redS[ww][1][row]; }
        mu[r] = S * (1.f / HH);
        float var = (Q2 - (float)HH * mu[r] * mu[r]) * (1.f / (HH - 1));
        inv[r] = 1.f / (sqrtf(var + EPSF) + EPSF);
    }
    float mk[4];
    #pragma unroll
    for (int r = 0; r < 4; r++) mk[r] = mask[rowT + q * 4 + r];
    {
        int col = w * 16 + m;
        #pragma unroll
        for (int r = 0; r < 4; r++) {
            float y = g1S[col] * (oC[r] - mu[r]) * inv[r] + h1S[col];
            y *= mk[r];
            oC[r] = y;
            hVout[(size_t)(rowT + q * 4 + r) * HH + col] = y;
        }
    }

    // fused next-layer premix (wave's 2 of 16 col-tiles)
    if (W1P) {
        __syncthreads();
        {
            int col = w * 16 + m;
            #pragma unroll
            for (int r = 0; r < 4; r++)
                rbH[(q * 4 + r) * 136 + col] = (short)f2bf(oC[r]);
        }
        __syncthreads();
        short8 ayh[4];
        #pragma unroll
        for (int kc = 0; kc < 4; kc++)
            ayh[kc] = *(const short8*)&rbH[m * 136 + kc * 32 + q * 8];
        #pragma unroll
        for (int u = 0; u < 2; u++) {
            int nt = w * 2 + u;
            int col = nt * 16 + m;
            float b0 = (nt < 8) ? b1S[col] : 0.f;
            f32x4 aH = {b0, b0, b0, b0};
            f32x4 aL = {0.f, 0.f, 0.f, 0.f};
            #pragma unroll
            for (int kc = 0; kc < 4; kc++) {
                const short* Bp = &W1P[((nt * 4 + kc) * 64 + lane) * 8];
                short8 bh = *(const short8*)Bp, bl = *(const short8*)(Bp + 32768);
                aH = MFMA16(ayh[kc], bh, aH);
                aL = MFMA16(ayh[kc], bl, aL);
            }
            #pragma unroll
            for (int r = 0; r < 4; r++) {
                size_t row = rowT + q * 4 + r;
                float vv = aH[r] + aL[r];
                if (nt < 8) Pn[row * HH + col] = vv;
                else        Qn[row * HH + (col - 128)] = vv;
            }
        }
    }
}

// ---------- launch ----------

extern "C" void kernel_launch(void* const* d_in, const int* in_sizes, int n_in,
                              void* d_out, int out_size, void* d_ws, size_t ws_size,
                              hipStream_t stream) {
    const float* X    = (const float*)d_in[0];
    const float* mask = (const float*)d_in[1];
    const float* Wn   = (const float*)d_in[2];
    const float* bn   = (const float*)d_in[3];
    const float* gn   = (const float*)d_in[4];
    const float* hn   = (const float*)d_in[5];
    const float* We   = (const float*)d_in[6];
    const float* be   = (const float*)d_in[7];
    const float* ge   = (const float*)d_in[8];
    const float* he   = (const float*)d_in[9];
    const float* Wv   = (const float*)d_in[10];
    const float* bv   = (const float*)d_in[11];
    const float* Wq   = (const float*)d_in[12];
    const float* bq   = (const float*)d_in[13];
    const float* lW1  = (const float*)d_in[14];
    const float* lb1  = (const float*)d_in[15];
    const float* lW2  = (const float*)d_in[16];
    const float* lb2  = (const float*)d_in[17];
    const float* lW3  = (const float*)d_in[18];
    const float* lb3  = (const float*)d_in[19];
    const float* lWi  = (const float*)d_in[20];
    const float* lbi  = (const float*)d_in[21];
    const float* lWo  = (const float*)d_in[22];
    const float* lbo  = (const float*)d_in[23];
    const float* lg0  = (const float*)d_in[24];
    const float* lh0  = (const float*)d_in[25];
    const float* lg1  = (const float*)d_in[26];
    const float* lh1  = (const float*)d_in[27];

    char* ws = (char*)d_ws;
    size_t off = 0;
    auto alloc = [&](size_t nbytes) { void* p = ws + off; off += (nbytes + 15) & ~(size_t)15; return p; };
    int*   E_idx = (int*)  alloc((size_t)BB * NN * KK * 4);
    float* D_nb  = (float*)alloc((size_t)BB * NN * KK * 4);
    float* ADb   = (float*)alloc((size_t)BB * NN * 3 * 4);
    float* Ofb   = (float*)alloc((size_t)BB * NN * 9 * 4);
    float* hV    = (float*)alloc((size_t)BB * NN * HH * 4);
    unsigned short* hEbH = (unsigned short*)alloc((size_t)BB * NN * KK * HH * 2);
    float* Pb    = (float*)alloc((size_t)BB * NN * HH * 4);
    float* Qb    = (float*)alloc((size_t)BB * NN * HH * 4);
    float* sBuf  = (float*)alloc((size_t)BB * NN * HH * 4);
    float* cntB  = (float*)alloc((size_t)BB * NN * 4);
    short* WeP   = (short*)alloc(2 * 8192 * 2);
    short* WqP   = (short*)alloc(2 * 16384 * 2);
    short* W1bP  = (short*)alloc(3 * 2 * 16384 * 2);
    short* W2P   = (short*)alloc(3 * 2 * 16384 * 2);
    short* W3P   = (short*)alloc(3 * 2 * 16384 * 2);
    short* WiP   = (short*)alloc(3 * 2 * 65536 * 2);
    short* WoP   = (short*)alloc(3 * 2 * 65536 * 2);
    short* W1acP = (short*)alloc(3 * 2 * 32768 * 2);
    short* WvP   = (short*)alloc(2 * 16384 * 2);
    if (off > ws_size) return;

    // Dispatch 1: knn | pack | orient (mutually independent)
    front_kernel<<<KNN_BLK + PACK_BLK + ORIENT_BLK, 256, 0, stream>>>(
        X, mask, E_idx, D_nb,
        We, Wq, lW1, lW2, lW3, lWi, lWo, Wv,
        WeP, WqP, W1bP, W2P, W3P, WiP, WoP, W1acP, WvP,
        ADb, Ofb);

    // Dispatch 2: edge_feat | node_feat16 (mutually independent; both need dispatch 1)
    mid_kernel<<<BB * NN + BB * NN / 16, 128, 0, stream>>>(
        X, E_idx, D_nb, Ofb, be, ge, he, bq, WeP, WqP, hEbH,
        ADb, Wn, bn, gn, hn, WvP, bv, W1acP, lb1, hV, Pb, Qb);

    for (int l = 0; l < 3; l++) {
        int last = (l == 2);
        msg_kernel<<<BB * NN / 2, 256, 0, stream>>>(
            mask, E_idx, hEbH, Pb, Qb,
            W1bP + (size_t)l * 32768,
            W2P + (size_t)l * 32768, lb2 + (size_t)l * HH,
            sBuf, cntB);
        node_kernel<<<BB * NN / 16, 512, 0, stream>>>(
            mask, sBuf, cntB, hV,
            W3P + (size_t)l * 32768, lb3 + (size_t)l * HH,
            WiP + (size_t)l * 131072, lbi + (size_t)l * DFF,
            WoP + (size_t)l * 131072, lbo + (size_t)l * HH,
            lg0 + (size_t)l * HH, lh0 + (size_t)l * HH,
            lg1 + (size_t)l * HH, lh1 + (size_t)l * HH,
            last ? nullptr : (W1acP + (size_t)(l + 1) * 65536),
            last ? nullptr : (lb1 + (size_t)(l + 1) * HH),
            last ? (float*)d_out : hV,
            Pb, Qb);
    }
}

// Round 13
// 315.348 us; speedup vs baseline: 1.0161x; 1.0161x over previous
//
#include <hip/hip_runtime.h>
#include <math.h>

typedef __attribute__((ext_vector_type(8))) short short8;
typedef __attribute__((ext_vector_type(4))) float f32x4;

#define BB 2
#define NN 2048
#define KK 32
#define HH 128
#define DFF 512
#define EPSF 1e-6f
#define INFV 1e30f

#define KNN_BLK 1024
#define PACK_BLK 2656
#define ORIENT_BLK 16

#define MFMA16(a, b, c) __builtin_amdgcn_mfma_f32_16x16x32_bf16((a), (b), (c), 0, 0, 0)

// ---------- helpers ----------

__device__ __forceinline__ unsigned short f2bf(float f) {
    unsigned u = __float_as_uint(f);
    u += 0x7fffu + ((u >> 16) & 1u);          // round-to-nearest-even
    return (unsigned short)(u >> 16);
}

__device__ __forceinline__ float bf2f(unsigned short h) {
    return __uint_as_float(((unsigned)h) << 16);
}

// split x into hi+lo bf16 pair — WEIGHTS only (systematic error must stay split)
__device__ __forceinline__ void f2bf2(float x, short& hi, short& lo) {
    unsigned short h = f2bf(x);
    hi = (short)h;
    lo = (short)f2bf(x - bf2f(h));
}

// pack 8 floats -> hi-plane short8
__device__ __forceinline__ short8 cvt8h(f32x4 a, f32x4 b) {
    short8 h8;
    #pragma unroll
    for (int i = 0; i < 4; i++) h8[i] = (short)f2bf(a[i]);
    #pragma unroll
    for (int i = 0; i < 4; i++) h8[4 + i] = (short)f2bf(b[i]);
    return h8;
}

__device__ __forceinline__ float sgnf(float x) {
    return (x > 0.f) ? 1.f : ((x < 0.f) ? -1.f : 0.f);
}

__device__ __forceinline__ void norm3(float& x, float& y, float& z) {
    float n = sqrtf(x * x + y * y + z * z);
    n = fmaxf(n, 1e-12f);
    x /= n; y /= n; z /= n;
}

// ---------- device bodies ----------

__device__ void knn_body(int bid4, const float* __restrict__ X,
                         const float* __restrict__ mask,
                         int* __restrict__ E_idx,
                         float* __restrict__ D_nb) {
    int w = threadIdx.x >> 6, lane = threadIdx.x & 63;
    int g = bid4 * 4 + w;
    int b = g >> 11, n = g & 2047;
    const float* Xb = X + (size_t)b * NN * 3;
    const float* mb = mask + (size_t)b * NN;

    float xn0 = Xb[n * 3], xn1 = Xb[n * 3 + 1], xn2 = Xb[n * 3 + 2];
    float mn = mb[n];

    float Dv[32], m2a[32];
    float lmax = -1e30f;
    #pragma unroll
    for (int s = 0; s < 32; s++) {
        int j = s * 64 + lane;
        float dx = Xb[j * 3] - xn0, dy = Xb[j * 3 + 1] - xn1, dz = Xb[j * 3 + 2] - xn2;
        float d = sqrtf(dx * dx + dy * dy + dz * dz + EPSF);
        float m2 = mn * mb[j];
        float v = m2 * d;
        Dv[s] = v; m2a[s] = m2;
        lmax = fmaxf(lmax, v);
    }
    #pragma unroll
    for (int off = 1; off <= 32; off <<= 1) lmax = fmaxf(lmax, __shfl_xor(lmax, off));
    float Dmax = lmax;
    #pragma unroll
    for (int s = 0; s < 32; s++) Dv[s] += (1.f - m2a[s]) * Dmax;

    // per-lane top-2 (strict < keeps earliest slot on exact ties)
    float l1 = INFV, l2 = INFV; int s1 = 0, s2 = 0;
    #pragma unroll
    for (int s = 0; s < 32; s++) {
        float v = Dv[s];
        bool lt1 = v < l1;
        bool lt2 = v < l2;
        float o1 = l1; int os1 = s1;
        l1 = lt1 ? v : l1;  s1 = lt1 ? s : s1;
        l2 = lt1 ? o1 : (lt2 ? v : l2);
        s2 = lt1 ? os1 : (lt2 ? s : s2);
    }

    unsigned used = 0u;
    float keepd = 0.f; int keepj = 0;

    for (int s = 0; s < KK; s++) {
        float m = l1;
        #pragma unroll
        for (int off = 1; off <= 32; off <<= 1) m = fminf(m, __shfl_xor(m, off));
        unsigned long long ball = __ballot(l1 == m);
        int jwin;
        if (__popcll(ball) == 1) {
            int src = (int)(__ffsll((long long)ball) - 1);
            jwin = __shfl(s1 * 64 + lane, src);
        } else {
            int jme = (l1 == m) ? (s1 * 64 + lane) : 0x7FFFFFFF;
            jwin = jme;
            #pragma unroll
            for (int off = 1; off <= 32; off <<= 1) jwin = min(jwin, __shfl_xor(jwin, off));
        }
        if (lane == s) { keepd = m; keepj = jwin; }
        if (lane == (jwin & 63)) {
            used |= 1u << s1;
            l1 = l2; s1 = s2;
            l2 = INFV;
            if (l1 >= INFV) {   // rare refill
                l1 = INFV; l2 = INFV;
                #pragma unroll
                for (int i = 0; i < 32; i++) {
                    float v = ((used >> i) & 1u) ? INFV : Dv[i];
                    bool lt1 = v < l1;
                    bool lt2 = v < l2;
                    float o1 = l1; int os1 = s1;
                    l1 = lt1 ? v : l1;  s1 = lt1 ? i : s1;
                    l2 = lt1 ? o1 : (lt2 ? v : l2);
                    s2 = lt1 ? os1 : (lt2 ? i : s2);
                }
            }
        }
    }
    if (lane < KK) {
        E_idx[(size_t)g * KK + lane] = keepj;
        D_nb[(size_t)g * KK + lane] = keepd;
    }
}

__device__ __forceinline__ void packB(const float* __restrict__ src, short* __restrict__ dH,
                                      short* __restrict__ dL, int e, int KC, int N, int Kreal) {
    int j = e & 7, ln = (e >> 3) & 63, t = e >> 9;
    int kc = t % KC, nt = t / KC;
    int k = kc * 32 + (ln >> 4) * 8 + j;
    int n = nt * 16 + (ln & 15);
    float v = (k < Kreal) ? src[(size_t)k * N + n] : 0.f;
    short hi, lo; f2bf2(v, hi, lo);
    dH[e] = hi; dL[e] = lo;
}

__device__ void pack_body(int e,
                          const float* __restrict__ We, const float* __restrict__ Wq,
                          const float* __restrict__ lW1, const float* __restrict__ lW2,
                          const float* __restrict__ lW3, const float* __restrict__ lWi,
                          const float* __restrict__ lWo, const float* __restrict__ Wv,
                          short* __restrict__ WeP, short* __restrict__ WqP,
                          short* __restrict__ W1bP, short* __restrict__ W2P,
                          short* __restrict__ W3P, short* __restrict__ WiP,
                          short* __restrict__ WoP, short* __restrict__ W1acP,
                          short* __restrict__ WvP) {
    if (e < 8192) { packB(We, WeP, WeP + 8192, e, 2, 128, 39); return; }
    e -= 8192;
    if (e < 16384) { packB(Wq, WqP, WqP + 16384, e, 4, 128, 128); return; }
    e -= 16384;
    if (e < 49152) {
        int l = e >> 14, r = e & 16383;
        packB(lW1 + (size_t)l * 49152 + 16384, W1bP + l * 32768, W1bP + l * 32768 + 16384, r, 4, 128, 128);
        return;
    }
    e -= 49152;
    if (e < 49152) {
        int l = e >> 14, r = e & 16383;
        packB(lW2 + (size_t)l * 16384, W2P + l * 32768, W2P + l * 32768 + 16384, r, 4, 128, 128);
        return;
    }
    e -= 49152;
    if (e < 49152) {
        int l = e >> 14, r = e & 16383;
        packB(lW3 + (size_t)l * 16384, W3P + l * 32768, W3P + l * 32768 + 16384, r, 4, 128, 128);
        return;
    }
    e -= 49152;
    if (e < 196608) {
        int l = e / 65536, r = e % 65536;
        packB(lWi + (size_t)l * 65536, WiP + l * 131072, WiP + l * 131072 + 65536, r, 4, 512, 128);
        return;
    }
    e -= 196608;
    if (e < 196608) {
        int l = e / 65536, r = e % 65536;
        packB(lWo + (size_t)l * 65536, WoP + l * 131072, WoP + l * 131072 + 65536, r, 16, 128, 512);
        return;
    }
    e -= 196608;
    if (e < 98304) {
        int l = e / 32768, r = e % 32768;
        int j = r & 7, ln = (r >> 3) & 63, t = r >> 9;
        int kc = t & 3, nt = t >> 2;
        int k = kc * 32 + (ln >> 4) * 8 + j;
        int n = nt * 16 + (ln & 15);
        const float* base = lW1 + (size_t)l * 49152;
        float v = (n < 128) ? base[(size_t)k * 128 + n] : base[(size_t)(256 + k) * 128 + (n - 128)];
        short hi, lo; f2bf2(v, hi, lo);
        short* dH = W1acP + l * 65536;
        dH[r] = hi; dH[32768 + r] = lo;
        return;
    }
    e -= 98304;
    // Wv pack (16384 elements)
    packB(Wv, WvP, WvP + 16384, e, 4, 128, 128);
}

__device__ void orient_body(int t, const float* __restrict__ X,
                            float* __restrict__ AD, float* __restrict__ Of) {
    if (t >= BB * NN) return;
    int b = t / NN, n = t % NN;
    float* ad = AD + (size_t)t * 3;
    float* of = Of + (size_t)t * 9;
    if (n < 1 || n > NN - 3) {
        ad[0] = ad[1] = ad[2] = 0.f;
        #pragma unroll
        for (int i = 0; i < 9; i++) of[i] = 0.f;
        return;
    }
    const float* Xb = X + (size_t)b * NN * 3;
    float p0x = Xb[(n - 1) * 3], p0y = Xb[(n - 1) * 3 + 1], p0z = Xb[(n - 1) * 3 + 2];
    float p1x = Xb[n * 3],       p1y = Xb[n * 3 + 1],       p1z = Xb[n * 3 + 2];
    float p2x = Xb[(n + 1) * 3], p2y = Xb[(n + 1) * 3 + 1], p2z = Xb[(n + 1) * 3 + 2];
    float p3x = Xb[(n + 2) * 3], p3y = Xb[(n + 2) * 3 + 1], p3z = Xb[(n + 2) * 3 + 2];

    float u2x = p1x - p0x, u2y = p1y - p0y, u2z = p1z - p0z; norm3(u2x, u2y, u2z);
    float u1x = p2x - p1x, u1y = p2y - p1y, u1z = p2z - p1z; norm3(u1x, u1y, u1z);
    float u0x = p3x - p2x, u0y = p3y - p2y, u0z = p3z - p2z; norm3(u0x, u0y, u0z);

    float n2x = u2y * u1z - u2z * u1y, n2y = u2z * u1x - u2x * u1z, n2z = u2x * u1y - u2y * u1x;
    norm3(n2x, n2y, n2z);
    float n1x = u1y * u0z - u1z * u0y, n1y = u1z * u0x - u1x * u0z, n1z = u1x * u0y - u1y * u0x;
    norm3(n1x, n1y, n1z);

    float cosA = -(u1x * u0x + u1y * u0y + u1z * u0z);
    cosA = fminf(fmaxf(cosA, -1.f + EPSF), 1.f - EPSF);
    float A = acosf(cosA);
    float cosD = n2x * n1x + n2y * n1y + n2z * n1z;
    cosD = fminf(fmaxf(cosD, -1.f + EPSF), 1.f - EPSF);
    float sg = sgnf(u2x * n1x + u2y * n1y + u2z * n1z);
    float Dih = sg * acosf(cosD);

    ad[0] = cosf(A);
    ad[1] = sinf(A) * cosf(Dih);
    ad[2] = sinf(A) * sinf(Dih);

    float o1x = u2x - u1x, o1y = u2y - u1y, o1z = u2z - u1z; norm3(o1x, o1y, o1z);
    float cx = o1y * n2z - o1z * n2y, cy = o1z * n2x - o1x * n2z, cz = o1x * n2y - o1y * n2x;
    of[0] = o1x; of[1] = o1y; of[2] = o1z;
    of[3] = n2x; of[4] = n2y; of[5] = n2z;
    of[6] = cx;  of[7] = cy;  of[8] = cz;
}

// ---------- FRONT: knn (blocks 0..1023) | pack (1024..3679) | orient (3680..3695) ----------

__global__ __launch_bounds__(256) void front_kernel(const float* __restrict__ X,
                                                    const float* __restrict__ mask,
                                                    int* __restrict__ E_idx,
                                                    float* __restrict__ D_nb,
                                                    const float* __restrict__ We,
                                                    const float* __restrict__ Wq,
                                                    const float* __restrict__ lW1,
                                                    const float* __restrict__ lW2,
                                                    const float* __restrict__ lW3,
                                                    const float* __restrict__ lWi,
                                                    const float* __restrict__ lWo,
                                                    const float* __restrict__ Wv,
                                                    short* __restrict__ WeP,
                                                    short* __restrict__ WqP,
                                                    short* __restrict__ W1bP,
                                                    short* __restrict__ W2P,
                                                    short* __restrict__ W3P,
                                                    short* __restrict__ WiP,
                                                    short* __restrict__ WoP,
                                                    short* __restrict__ W1acP,
                                                    short* __restrict__ WvP,
                                                    float* __restrict__ ADb,
                                                    float* __restrict__ Ofb) {
    int blk = blockIdx.x;
    if (blk < KNN_BLK) {
        knn_body(blk, X, mask, E_idx, D_nb);
    } else if (blk < KNN_BLK + PACK_BLK) {
        pack_body((blk - KNN_BLK) * 256 + threadIdx.x,
                  We, Wq, lW1, lW2, lW3, lWi, lWo, Wv,
                  WeP, WqP, W1bP, W2P, W3P, WiP, WoP, W1acP, WvP);
    } else {
        orient_body((blk - KNN_BLK - PACK_BLK) * 256 + threadIdx.x, X, ADb, Ofb);
    }
}

// ---------- MID: edge_feat (blocks 0..4095) | node_feat16 (4096..4351) ----------
// edge_feat: waves split over OUTPUT col-tiles (nt); hEbH output staged through
// LDS (AeH reuse) for coalesced short8 stores instead of 32 scalar 2B stores.

__global__ __launch_bounds__(128) void mid_kernel(const float* __restrict__ X,
                                                  const int* __restrict__ E_idx,
                                                  const float* __restrict__ D_nb,
                                                  const float* __restrict__ Of,
                                                  const float* __restrict__ be,
                                                  const float* __restrict__ ge,
                                                  const float* __restrict__ he,
                                                  const float* __restrict__ bq,
                                                  const short* __restrict__ WeP,
                                                  const short* __restrict__ WqP,
                                                  unsigned short* __restrict__ hEbH,
                                                  const float* __restrict__ AD,
                                                  const float* __restrict__ Wn,
                                                  const float* __restrict__ bn,
                                                  const float* __restrict__ gn,
                                                  const float* __restrict__ hn,
                                                  const short* __restrict__ WvP,
                                                  const float* __restrict__ bv,
                                                  const short* __restrict__ W1acP0,
                                                  const float* __restrict__ b1_0,
                                                  float* __restrict__ hV,
                                                  float* __restrict__ P,
                                                  float* __restrict__ Q) {
    __shared__ __align__(16) char smemRaw[15872];

    if (blockIdx.x < (unsigned)(BB * NN)) {
        // ----- edge_feat body -----
        short* AefH = (short*)smemRaw;                 // 32*72*2   = 4608 B
        short* AeH  = (short*)(smemRaw + 4608);        // 32*136*2  = 8704 B
        float* beS  = (float*)(smemRaw + 13312);       // 512 B
        float* geS  = beS + HH;
        float* heS  = geS + HH;
        float* bqS  = heS + HH;
        float* redSe = (float*)(smemRaw + 15360);      // [2][2][32] = 512 B

        int bid = blockIdx.x; int b = bid >> 11, n = bid & 2047; int tid = threadIdx.x;
        int lane = tid & 63, w = tid >> 6;
        beS[tid] = be[tid]; geS[tid] = ge[tid]; heS[tid] = he[tid]; bqS[tid] = bq[tid];
        {
            unsigned* Az = (unsigned*)AefH;
            for (int i = tid; i < 32 * 72 / 2; i += 128) Az[i] = 0u;
        }
        __syncthreads();

        int part = tid >> 5, k = tid & 31;
        int e = E_idx[(size_t)bid * KK + k];
        float dpos = (float)e - (float)n;
        if (part == 1 || part == 2) {
            int p0 = (part - 1) * 4;
            #pragma unroll
            for (int p = 0; p < 4; p++) {
                // freq = 10000^(-(p0+p)/8) = 10^(-(p0+p)/2) — compile-time constants
                float fr = (part == 1)
                    ? ((p == 0) ? 1.f : (p == 1) ? 0.31622776601683794f
                       : (p == 2) ? 0.1f : 0.031622776601683791f)
                    : ((p == 0) ? 0.01f : (p == 1) ? 0.0031622776601683794f
                       : (p == 2) ? 0.001f : 0.00031622776601683794f);
                float ang = dpos * fr;
                AefH[k * 72 + p0 + p]     = (short)f2bf(__cosf(ang));
                AefH[k * 72 + 8 + p0 + p] = (short)f2bf(__sinf(ang));
            }
        } else if (part == 3) {
            float Dv = D_nb[(size_t)bid * KK + k];
            #pragma unroll
            for (int i = 0; i < 16; i++) {
                float m = (20.f / 15.f) * (float)i;
                float z = (Dv - m) * 0.8f;
                AefH[k * 72 + 16 + i] = (short)f2bf(__expf(-z * z));
            }
        } else {
            const float* Omp = Of + (size_t)(b * NN + n) * 9;
            const float* Onp = Of + (size_t)(b * NN + e) * 9;
            float Om[9], On[9];
            #pragma unroll
            for (int i = 0; i < 9; i++) { Om[i] = Omp[i]; On[i] = Onp[i]; }
            float vx = X[(size_t)(b * NN + e) * 3 + 0] - X[(size_t)(b * NN + n) * 3 + 0];
            float vy = X[(size_t)(b * NN + e) * 3 + 1] - X[(size_t)(b * NN + n) * 3 + 1];
            float vz = X[(size_t)(b * NN + e) * 3 + 2] - X[(size_t)(b * NN + n) * 3 + 2];
            float t0 = Om[0] * vx + Om[1] * vy + Om[2] * vz;
            float t1 = Om[3] * vx + Om[4] * vy + Om[5] * vz;
            float t2 = Om[6] * vx + Om[7] * vy + Om[8] * vz;
            float nr = fmaxf(sqrtf(t0 * t0 + t1 * t1 + t2 * t2), 1e-12f);
            AefH[k * 72 + 32] = (short)f2bf(t0 / nr);
            AefH[k * 72 + 33] = (short)f2bf(t1 / nr);
            AefH[k * 72 + 34] = (short)f2bf(t2 / nr);
            float R[9];
            #pragma unroll
            for (int i = 0; i < 3; i++)
                #pragma unroll
                for (int l = 0; l < 3; l++)
                    R[i * 3 + l] = Om[0 + i] * On[0 + l] + Om[3 + i] * On[3 + l] + Om[6 + i] * On[6 + l];
            float Rxx = R[0], Ryy = R[4], Rzz = R[8];
            float mx = 0.5f * sqrtf(fabsf(1.f + Rxx - Ryy - Rzz));
            float my = 0.5f * sqrtf(fabsf(1.f - Rxx + Ryy - Rzz));
            float mz = 0.5f * sqrtf(fabsf(1.f - Rxx - Ryy + Rzz));
            float qx = sgnf(R[7] - R[5]) * mx;
            float qy = sgnf(R[2] - R[6]) * my;
            float qz = sgnf(R[3] - R[1]) * mz;
            float qw = 0.5f * sqrtf(fmaxf(1.f + Rxx + Ryy + Rzz, 0.f));
            float qn = fmaxf(sqrtf(qx * qx + qy * qy + qz * qz + qw * qw), 1e-12f);
            AefH[k * 72 + 35] = (short)f2bf(qx / qn);
            AefH[k * 72 + 36] = (short)f2bf(qy / qn);
            AefH[k * 72 + 37] = (short)f2bf(qz / qn);
            AefH[k * 72 + 38] = (short)f2bf(qw / qn);
        }
        __syncthreads();

        int m = lane & 15, q = lane >> 4;
        // A-frags: both row-tiles (t), this wave covers all 32 edges
        short8 aW[2][2];
        #pragma unroll
        for (int t = 0; t < 2; t++) {
            int row = (t * 16 + m) * 72;
            aW[t][0] = *(const short8*)&AefH[row + q * 8];
            aW[t][1] = *(const short8*)&AefH[row + 32 + q * 8];
        }
        f32x4 accA[4][2];   // [nt4][t]
        #pragma unroll
        for (int nt4 = 0; nt4 < 4; nt4++) {
            int ntg = w * 4 + nt4;
            const short* B0 = &WeP[((ntg * 2 + 0) * 64 + lane) * 8];
            const short* B1 = &WeP[((ntg * 2 + 1) * 64 + lane) * 8];
            short8 b0h = *(const short8*)B0, b0l = *(const short8*)(B0 + 8192);
            short8 b1h = *(const short8*)B1, b1l = *(const short8*)(B1 + 8192);
            float bc = beS[ntg * 16 + m];
            #pragma unroll
            for (int t = 0; t < 2; t++) {
                f32x4 acc = {bc, bc, bc, bc};
                acc = MFMA16(aW[t][0], b0h, acc);
                acc = MFMA16(aW[t][0], b0l, acc);
                acc = MFMA16(aW[t][1], b1h, acc);
                acc = MFMA16(aW[t][1], b1l, acc);
                accA[nt4][t] = acc;
            }
        }
        // cross-wave LN: partial su/sq per row over this wave's 64 cols
        #pragma unroll
        for (int t = 0; t < 2; t++)
            #pragma unroll
            for (int r = 0; r < 4; r++) {
                float su = accA[0][t][r] + accA[1][t][r] + accA[2][t][r] + accA[3][t][r];
                float sq2 = accA[0][t][r] * accA[0][t][r] + accA[1][t][r] * accA[1][t][r]
                          + accA[2][t][r] * accA[2][t][r] + accA[3][t][r] * accA[3][t][r];
                #pragma unroll
                for (int off = 1; off <= 8; off <<= 1) {
                    su += __shfl_xor(su, off); sq2 += __shfl_xor(sq2, off);
                }
                if (m == 0) {
                    int row = t * 16 + q * 4 + r;
                    redSe[(w * 2 + 0) * 32 + row] = su;
                    redSe[(w * 2 + 1) * 32 + row] = sq2;
                }
            }
        __syncthreads();
        float muA[2][4], invA[2][4];
        #pragma unroll
        for (int t = 0; t < 2; t++)
            #pragma unroll
            for (int r = 0; r < 4; r++) {
                int row = t * 16 + q * 4 + r;
                float S  = redSe[0 * 32 + row] + redSe[2 * 32 + row];
                float Q2 = redSe[1 * 32 + row] + redSe[3 * 32 + row];
                float mu = S * (1.f / HH);
                float var = (Q2 - (float)HH * mu * mu) * (1.f / (HH - 1));
                muA[t][r] = mu;
                invA[t][r] = 1.f / (sqrtf(var + EPSF) + EPSF);
            }
        #pragma unroll
        for (int nt4 = 0; nt4 < 4; nt4++) {
            int col = (w * 4 + nt4) * 16 + m;
            float g = geS[col], hh = heS[col];
            #pragma unroll
            for (int t = 0; t < 2; t++)
                #pragma unroll
                for (int r = 0; r < 4; r++) {
                    int edge = t * 16 + q * 4 + r;
                    float y = g * (accA[nt4][t][r] - muA[t][r]) * invA[t][r] + hh;
                    AeH[edge * 136 + col] = (short)f2bf(y);
                }
        }
        __syncthreads();

        short8 ah[2][4];
        #pragma unroll
        for (int t = 0; t < 2; t++)
            #pragma unroll
            for (int kc = 0; kc < 4; kc++)
                ah[t][kc] = *(const short8*)&AeH[(t * 16 + m) * 136 + kc * 32 + q * 8];
        __syncthreads();   // all A-frag preloads done — AeH becomes output staging

        #pragma unroll
        for (int nt4 = 0; nt4 < 4; nt4++) {
            int ntg = w * 4 + nt4;
            int col = ntg * 16 + m;
            short8 qh[4], ql[4];
            #pragma unroll
            for (int kc = 0; kc < 4; kc++) {
                const short* Bp = &WqP[((ntg * 4 + kc) * 64 + lane) * 8];
                qh[kc] = *(const short8*)Bp;
                ql[kc] = *(const short8*)(Bp + 16384);
            }
            float bc = bqS[col];
            #pragma unroll
            for (int t = 0; t < 2; t++) {
                f32x4 acc = {bc, bc, bc, bc};
                #pragma unroll
                for (int kc = 0; kc < 4; kc++) {
                    acc = MFMA16(ah[t][kc], qh[kc], acc);
                    acc = MFMA16(ah[t][kc], ql[kc], acc);
                }
                #pragma unroll
                for (int r = 0; r < 4; r++) {
                    int edge = t * 16 + q * 4 + r;
                    AeH[edge * 136 + col] = (short)f2bf(acc[r]);
                }
            }
        }
        __syncthreads();

        // coalesced copy-out: 512 short8 chunks, 4 per thread (256B contiguous/row)
        {
            unsigned short* outp = hEbH + (size_t)bid * (KK * HH);
            #pragma unroll
            for (int it = 0; it < 4; it++) {
                int idx = it * 128 + tid;       // 0..511
                int row = idx >> 4, c8 = idx & 15;
                *(short8*)(outp + row * HH + c8 * 8) = *(const short8*)&AeH[row * 136 + c8 * 8];
            }
        }
    } else {
        // ----- node_feat body: 16 nodes per block, MFMA path -----
        short* yH  = (short*)smemRaw;                  // 16*136*2 = 4352 B
        short* hvH = (short*)(smemRaw + 4352);         // 4352 B

        int nb = blockIdx.x - BB * NN;
        int g0 = nb * 16;
        int tid = threadIdx.x;
        int lane = tid & 63, w = tid >> 6;
        int m = lane & 15, q = lane >> 4;

        // step 1: V = AD @ Wn + bn, per-node LN -> y (bf16 in LDS)
        {
            int i = tid >> 3;          // node 0..15
            int j = tid & 7;           // column group (16 cols each)
            int h0 = j * 16;
            const float* ad = AD + (size_t)(g0 + i) * 3;
            float a0 = ad[0], a1 = ad[1], a2 = ad[2];
            float v[16];
            float su = 0.f, sq = 0.f;
            #pragma unroll
            for (int c = 0; c < 16; c++) {
                int h = h0 + c;
                float t = bn[h] + a0 * Wn[h] + a1 * Wn[HH + h] + a2 * Wn[2 * HH + h];
                v[c] = t; su += t; sq += t * t;
            }
            #pragma unroll
            for (int off = 1; off <= 4; off <<= 1) {
                su += __shfl_xor(su, off); sq += __shfl_xor(sq, off);
            }
            float mu = su * (1.f / HH);
            float var = (sq - (float)HH * mu * mu) * (1.f / (HH - 1));
            float inv = 1.f / (sqrtf(var + EPSF) + EPSF);
            #pragma unroll
            for (int c = 0; c < 16; c++) {
                int h = h0 + c;
                yH[i * 136 + h] = (short)f2bf(gn[h] * (v[c] - mu) * inv + hn[h]);
            }
        }
        __syncthreads();

        // step 2: hV = y @ Wv + bv  (wave handles 4 of 8 col-tiles)
        short8 ayh[4];
        #pragma unroll
        for (int kc = 0; kc < 4; kc++)
            ayh[kc] = *(const short8*)&yH[m * 136 + kc * 32 + q * 8];
        #pragma unroll
        for (int u = 0; u < 4; u++) {
            int nt = w * 4 + u;
            int col = nt * 16 + m;
            float bc = bv[col];
            f32x4 a = {bc, bc, bc, bc};
            #pragma unroll
            for (int kc = 0; kc < 4; kc++) {
                const short* Bp = &WvP[((nt * 4 + kc) * 64 + lane) * 8];
                short8 bh = *(const short8*)Bp, bl = *(const short8*)(Bp + 16384);
                a = MFMA16(ayh[kc], bh, a);
                a = MFMA16(ayh[kc], bl, a);
            }
            #pragma unroll
            for (int r = 0; r < 4; r++) {
                int rw = q * 4 + r;
                hV[(size_t)(g0 + rw) * HH + col] = a[r];
                hvH[rw * 136 + col] = (short)f2bf(a[r]);
            }
        }
        __syncthreads();

        // step 3: layer-0 premix P/Q = hV @ W1_0[a|c] (+b1 for P), via packed W1acP[0]
        short8 avh[4];
        #pragma unroll
        for (int kc = 0; kc < 4; kc++)
            avh[kc] = *(const short8*)&hvH[m * 136 + kc * 32 + q * 8];
        #pragma unroll
        for (int u = 0; u < 8; u++) {
            int nt = w * 8 + u;
            int col = nt * 16 + m;
            float b0 = (nt < 8) ? b1_0[col] : 0.f;
            f32x4 a = {b0, b0, b0, b0};
            #pragma unroll
            for (int kc = 0; kc < 4; kc++) {
                const short* Bp = &W1acP0[((nt * 4 + kc) * 64 + lane) * 8];
                short8 bh = *(const short8*)Bp, bl = *(const short8*)(Bp + 32768);
                a = MFMA16(avh[kc], bh, a);
                a = MFMA16(avh[kc], bl, a);
            }
            #pragma unroll
            for (int r = 0; r < 4; r++) {
                size_t rw = g0 + q * 4 + r;
                if (nt < 8) P[rw * HH + col] = a[r];
                else        Q[rw * HH + (col - 128)] = a[r];
            }
        }
    }
}

// ---------- message kernel: block = 2 nodes, 4 waves, 2 nt-tiles per wave ----------
// (r7 form — best measured) A-side staged in LDS; weights loaded once per nt-tile
// per wave and reused for both nodes; 4 blocks/CU = 16 waves/CU.

__global__ __launch_bounds__(256) void msg_kernel(const float* __restrict__ mask,
                                                  const int* __restrict__ E_idx,
                                                  const unsigned short* __restrict__ hEbH,
                                                  const float* __restrict__ P,
                                                  const float* __restrict__ Q,
                                                  const short* __restrict__ W1bP,
                                                  const short* __restrict__ W2P,
                                                  const float* __restrict__ b2,
                                                  float* __restrict__ sOut,
                                                  float* __restrict__ cntOut) {
    __shared__ short stg[2][32 * 136];   // staged h_E (bf16) per node
    __shared__ short AmH[2][32 * 136];   // m1 (bf16) per node

    int tid = threadIdx.x;
    int w = tid >> 6, lane = tid & 63;
    int gA = blockIdx.x * 2;             // nodes gA, gA+1 (same batch: NN even)
    int b = gA >> 11;
    int m = lane & 15, q = lane >> 4;

    // ---- stage hEbH for both nodes (fully coalesced short8 loads) ----
    {
        const short8* src = (const short8*)(hEbH + (size_t)gA * (KK * HH));
        #pragma unroll
        for (int it = 0; it < 4; it++) {
            int idx = it * 256 + tid;        // 0..1023 short8 chunks
            int nd = idx >> 9;
            int rem = idx & 511;
            int e = rem >> 4;                // edge
            int c8 = rem & 15;               // col/8
            short8 v = src[idx];
            *(short8*)&stg[nd][e * 136 + c8 * 8] = v;
        }
    }

    int qbase[2][2][4]; float mt[2][2][4];
    #pragma unroll
    for (int nd = 0; nd < 2; nd++) {
        float maskv = mask[gA + nd];
        #pragma unroll
        for (int t = 0; t < 2; t++)
            #pragma unroll
            for (int r = 0; r < 4; r++) {
                int row = t * 16 + q * 4 + r;
                int e = E_idx[(size_t)(gA + nd) * KK + row];
                qbase[nd][t][r] = (b * NN + e) * HH;
                mt[nd][t][r] = maskv * mask[b * NN + e];
            }
    }
    if (w < 2) {
        // wave w (0,1) produces cnt for node w
        float c8 = mt[w][0][0] + mt[w][0][1] + mt[w][0][2] + mt[w][0][3]
                 + mt[w][1][0] + mt[w][1][1] + mt[w][1][2] + mt[w][1][3];
        c8 += __shfl_xor(c8, 16);
        c8 += __shfl_xor(c8, 32);
        if (lane == 0) cntOut[gA + w] = c8;
    }

    float preg[2][2], b2reg[2];
    #pragma unroll
    for (int u = 0; u < 2; u++) {
        int colg = (w * 2 + u) * 16 + m;
        b2reg[u] = b2[colg];
        preg[0][u] = P[(size_t)gA * HH + colg];
        preg[1][u] = P[(size_t)(gA + 1) * HH + colg];
    }
    __syncthreads();

    // phase 1: m1 = relu(P + Q[nbr] + h_E @ W1b) — wave handles 2 nt tiles, both nodes
    #pragma unroll
    for (int u = 0; u < 2; u++) {
        int ntg = w * 2 + u;
        int colg = ntg * 16 + m;
        short8 bh[4], bl[4];
        #pragma unroll
        for (int kc = 0; kc < 4; kc++) {
            const short* Bp = &W1bP[((ntg * 4 + kc) * 64 + lane) * 8];
            bh[kc] = *(const short8*)Bp;
            bl[kc] = *(const short8*)(Bp + 16384);
        }
        #pragma unroll
        for (int nd = 0; nd < 2; nd++) {
            f32x4 t0 = {0.f, 0.f, 0.f, 0.f}, t1 = {0.f, 0.f, 0.f, 0.f};
            #pragma unroll
            for (int kc = 0; kc < 4; kc++) {
                short8 a0 = *(const short8*)&stg[nd][(0 * 16 + m) * 136 + kc * 32 + q * 8];
                short8 a1 = *(const short8*)&stg[nd][(1 * 16 + m) * 136 + kc * 32 + q * 8];
                t0 = MFMA16(a0, bh[kc], t0);
                t0 = MFMA16(a0, bl[kc], t0);
                t1 = MFMA16(a1, bh[kc], t1);
                t1 = MFMA16(a1, bl[kc], t1);
            }
            float pp = preg[nd][u];
            #pragma unroll
            for (int r = 0; r < 4; r++) {
                float v0 = fmaxf(t0[r] + pp + Q[(size_t)qbase[nd][0][r] + colg], 0.f);
                AmH[nd][(q * 4 + r) * 136 + colg] = (short)f2bf(v0);
                float v1 = fmaxf(t1[r] + pp + Q[(size_t)qbase[nd][1][r] + colg], 0.f);
                AmH[nd][(16 + q * 4 + r) * 136 + colg] = (short)f2bf(v1);
            }
        }
    }
    __syncthreads();

    // phase 2: m2 = relu(m1 @ W2 + b2); masked sum over 32 edges
    #pragma unroll
    for (int u = 0; u < 2; u++) {
        int ntg = w * 2 + u;
        short8 bh[4], bl[4];
        #pragma unroll
        for (int kc = 0; kc < 4; kc++) {
            const short* Bp = &W2P[((ntg * 4 + kc) * 64 + lane) * 8];
            bh[kc] = *(const short8*)Bp;
            bl[kc] = *(const short8*)(Bp + 16384);
        }
        float bc = b2reg[u];
        #pragma unroll
        for (int nd = 0; nd < 2; nd++) {
            f32x4 a0 = {bc, bc, bc, bc}, a1 = {bc, bc, bc, bc};
            #pragma unroll
            for (int kc = 0; kc < 4; kc++) {
                short8 m0 = *(const short8*)&AmH[nd][(0 * 16 + m) * 136 + kc * 32 + q * 8];
                short8 m1 = *(const short8*)&AmH[nd][(1 * 16 + m) * 136 + kc * 32 + q * 8];
                a0 = MFMA16(m0, bh[kc], a0);
                a0 = MFMA16(m0, bl[kc], a0);
                a1 = MFMA16(m1, bh[kc], a1);
                a1 = MFMA16(m1, bl[kc], a1);
            }
            float part = 0.f;
            #pragma unroll
            for (int r = 0; r < 4; r++)
                part += fmaxf(a0[r], 0.f) * mt[nd][0][r] + fmaxf(a1[r], 0.f) * mt[nd][1][r];
            part += __shfl_xor(part, 16);
            part += __shfl_xor(part, 32);
            if (q == 0) sOut[(size_t)(gA + nd) * HH + ntg * 16 + m] = part;
        }
    }
}

// ---------- node kernel: 8 waves (512 threads), 16 nodes/block ----------

#define HSTR 520   // LDS stride (shorts) for 512-wide hidden staging

__global__ __launch_bounds__(512, 2) void node_kernel(const float* __restrict__ mask,
                                                      const float* __restrict__ sbuf,
                                                      const float* __restrict__ cntb,
                                                      const float* __restrict__ hVin,
                                                      const short* __restrict__ W3P,
                                                      const float* __restrict__ b3,
                                                      const short* __restrict__ WiP,
                                                      const float* __restrict__ biN,
                                                      const short* __restrict__ WoP,
                                                      const float* __restrict__ boN,
                                                      const float* __restrict__ g0,
                                                      const float* __restrict__ h0,
                                                      const float* __restrict__ g1,
                                                      const float* __restrict__ h1,
                                                      const short* __restrict__ W1P,
                                                      const float* __restrict__ b1n,
                                                      float* __restrict__ hVout,
                                                      float* __restrict__ Pn,
                                                      float* __restrict__ Qn) {
    __shared__ short rbH[16 * 136];
    __shared__ short hbH[16 * HSTR];
    __shared__ float redS[8][2][16];
    __shared__ float g0S[128], h0S[128], g1S[128], h1S[128], b3S[128], boS[128], b1S[128];
    __shared__ float biS[512];

    int tid = threadIdx.x;
    int w = tid >> 6, lane = tid & 63;
    int m = lane & 15, q = lane >> 4;
    int rowT = blockIdx.x * 16;

    if (tid < 128) {
        int i = tid;
        g0S[i] = g0[i]; h0S[i] = h0[i]; g1S[i] = g1[i]; h1S[i] = h1[i];
        b3S[i] = b3[i]; boS[i] = boN[i]; b1S[i] = W1P ? b1n[i] : 0.f;
    }
    biS[tid] = biN[tid];
    __syncthreads();

    short8 ash[4];
    #pragma unroll
    for (int kc = 0; kc < 4; kc++) {
        const float* sp = &sbuf[(size_t)(rowT + m) * HH + kc * 32 + q * 8];
        f32x4 x0 = *(const f32x4*)sp;
        f32x4 x1 = *(const f32x4*)(sp + 4);
        ash[kc] = cvt8h(x0, x1);
    }
    float cntr[4];
    #pragma unroll
    for (int r = 0; r < 4; r++) cntr[r] = cntb[rowT + q * 4 + r];

    // W3: wave w owns col-tile w
    f32x4 vC;
    {
        f32x4 a = {0.f, 0.f, 0.f, 0.f};
        #pragma unroll
        for (int kc = 0; kc < 4; kc++) {
            const short* Bp = &W3P[((w * 4 + kc) * 64 + lane) * 8];
            short8 bh = *(const short8*)Bp, bl = *(const short8*)(Bp + 16384);
            a = MFMA16(ash[kc], bh, a);
            a = MFMA16(ash[kc], bl, a);
        }
        int col = w * 16 + m;
        #pragma unroll
        for (int r = 0; r < 4; r++) {
            float tv = (a[r] + cntr[r] * b3S[col]) * (1.f / 30.f);
            a[r] = hVin[(size_t)(rowT + q * 4 + r) * HH + col] + tv;
        }
        vC = a;
    }

    // LN0 (cross-8-wave)
    {
        float su[4], sq[4];
        #pragma unroll
        for (int r = 0; r < 4; r++) { float v = vC[r]; su[r] = v; sq[r] = v * v; }
        #pragma unroll
        for (int off = 1; off <= 8; off <<= 1)
            #pragma unroll
            for (int r = 0; r < 4; r++) { su[r] += __shfl_xor(su[r], off); sq[r] += __shfl_xor(sq[r], off); }
        if (m == 0) {
            #pragma unroll
            for (int r = 0; r < 4; r++) { redS[w][0][q * 4 + r] = su[r]; redS[w][1][q * 4 + r] = sq[r]; }
        }
    }
    __syncthreads();
    float mu[4], inv[4];
    #pragma unroll
    for (int r = 0; r < 4; r++) {
        int row = q * 4 + r;
        float S = 0.f, Q2 = 0.f;
        #pragma unroll
        for (int ww = 0; ww < 8; ww++) { S += redS[ww][0][row]; Q2 += redS[ww][1][row]; }
        mu[r] = S * (1.f / HH);
        float var = (Q2 - (float)HH * mu[r] * mu[r]) * (1.f / (HH - 1));
        inv[r] = 1.f / (sqrtf(var + EPSF) + EPSF);
    }
    {
        int col = w * 16 + m;
        #pragma unroll
        for (int r = 0; r < 4; r++) {
            vC[r] = g0S[col] * (vC[r] - mu[r]) * inv[r] + h0S[col];
            rbH[(q * 4 + r) * 136 + col] = (short)f2bf(vC[r]);
        }
    }
    __syncthreads();

    short8 avh[4];
    #pragma unroll
    for (int kc = 0; kc < 4; kc++)
        avh[kc] = *(const short8*)&rbH[m * 136 + kc * 32 + q * 8];

    // FFN-in: wave's 64 hidden cols (4 of 32 tiles)
    #pragma unroll
    for (int u = 0; u < 4; u++) {
        int nt = w * 4 + u;
        int jcol = nt * 16 + m;
        float bb = biS[jcol];
        f32x4 a = {bb, bb, bb, bb};
        #pragma unroll
        for (int kc = 0; kc < 4; kc++) {
            const short* Bp = &WiP[((nt * 4 + kc) * 64 + lane) * 8];
            short8 bh = *(const short8*)Bp, bl = *(const short8*)(Bp + 65536);
            a = MFMA16(avh[kc], bh, a);
            a = MFMA16(avh[kc], bl, a);
        }
        #pragma unroll
        for (int r = 0; r < 4; r++)
            hbH[(q * 4 + r) * HSTR + jcol] = (short)f2bf(fmaxf(a[r], 0.f));
    }
    __syncthreads();

    // FFN-out: wave's col-tile w over ALL 512 hidden
    f32x4 oC = {0.f, 0.f, 0.f, 0.f};
    for (int kc2 = 0; kc2 < 16; kc2++) {
        short8 ahh = *(const short8*)&hbH[m * HSTR + kc2 * 32 + q * 8];
        const short* Bp = &WoP[((w * 16 + kc2) * 64 + lane) * 8];
        short8 bh = *(const short8*)Bp, bl = *(const short8*)(Bp + 65536);
        oC = MFMA16(ahh, bh, oC);
        oC = MFMA16(ahh, bl, oC);
    }
    {
        int col = w * 16 + m;
        #pragma unroll
        for (int r = 0; r < 4; r++)
            oC[r] += boS[col] + vC[r];
    }

    // LN1 (cross-8-wave)
    {
        float su[4], sq[4];
        #pragma unroll
        for (int r = 0; r < 4; r++) { float v = oC[r]; su[r] = v; sq[r] = v * v; }
        #pragma unroll
        for (int off = 1; off <= 8; off <<= 1)
            #pragma unroll
            for (int r = 0; r < 4; r++) { su[r] += __shfl_xor(su[r], off); sq[r] += __shfl_xor(sq[r], off); }
        __syncthreads();   // redS reuse
        if (m == 0) {
            #pragma unroll
            for (int r = 0; r < 4; r++) { redS[w][0][q * 4 + r] = su[r]; redS[w][1][q * 4 + r] = sq[r]; }
        }
    }
    __syncthreads();
    #pragma unroll
    for (int r = 0; r < 4; r++) {
        int row = q * 4 + r;
        float S = 0.f, Q2 = 0.f;
        #pragma unroll
        for (int ww = 0; ww < 8; ww++) { S += redS[ww][0][row]; Q2 += redS[ww][1][row]; }
        mu[r] = S * (1.f / HH);
        float var = (Q2 - (float)HH * mu[r] * mu[r]) * (1.f / (HH - 1));
        inv[r] = 1.f / (sqrtf(var + EPSF) + EPSF);
    }
    float mk[4];
    #pragma unroll
    for (int r = 0; r < 4; r++) mk[r] = mask[rowT + q * 4 + r];
    {
        int col = w * 16 + m;
        #pragma unroll
        for (int r = 0; r < 4; r++) {
            float y = g1S[col] * (oC[r] - mu[r]) * inv[r] + h1S[col];
            y *= mk[r];
            oC[r] = y;
            hVout[(size_t)(rowT + q * 4 + r) * HH + col] = y;
        }
    }

    // fused next-layer premix (wave's 2 of 16 col-tiles)
    if (W1P) {
        __syncthreads();
        {
            int col = w * 16 + m;
            #pragma unroll
            for (int r = 0; r < 4; r++)
                rbH[(q * 4 + r) * 136 + col] = (short)f2bf(oC[r]);
        }
        __syncthreads();
        short8 ayh[4];
        #pragma unroll
        for (int kc = 0; kc < 4; kc++)
            ayh[kc] = *(const short8*)&rbH[m * 136 + kc * 32 + q * 8];
        #pragma unroll
        for (int u = 0; u < 2; u++) {
            int nt = w * 2 + u;
            int col = nt * 16 + m;
            float b0 = (nt < 8) ? b1S[col] : 0.f;
            f32x4 a = {b0, b0, b0, b0};
            #pragma unroll
            for (int kc = 0; kc < 4; kc++) {
                const short* Bp = &W1P[((nt * 4 + kc) * 64 + lane) * 8];
                short8 bh = *(const short8*)Bp, bl = *(const short8*)(Bp + 32768);
                a = MFMA16(ayh[kc], bh, a);
                a = MFMA16(ayh[kc], bl, a);
            }
            #pragma unroll
            for (int r = 0; r < 4; r++) {
                size_t row = rowT + q * 4 + r;
                if (nt < 8) Pn[row * HH + col] = a[r];
                else        Qn[row * HH + (col - 128)] = a[r];
            }
        }
    }
}

// ---------- launch ----------

extern "C" void kernel_launch(void* const* d_in, const int* in_sizes, int n_in,
                              void* d_out, int out_size, void* d_ws, size_t ws_size,
                              hipStream_t stream) {
    const float* X    = (const float*)d_in[0];
    const float* mask = (const float*)d_in[1];
    const float* Wn   = (const float*)d_in[2];
    const float* bn   = (const float*)d_in[3];
    const float* gn   = (const float*)d_in[4];
    const float* hn   = (const float*)d_in[5];
    const float* We   = (const float*)d_in[6];
    const float* be   = (const float*)d_in[7];
    const float* ge   = (const float*)d_in[8];
    const float* he   = (const float*)d_in[9];
    const float* Wv   = (const float*)d_in[10];
    const float* bv   = (const float*)d_in[11];
    const float* Wq   = (const float*)d_in[12];
    const float* bq   = (const float*)d_in[13];
    const float* lW1  = (const float*)d_in[14];
    const float* lb1  = (const float*)d_in[15];
    const float* lW2  = (const float*)d_in[16];
    const float* lb2  = (const float*)d_in[17];
    const float* lW3  = (const float*)d_in[18];
    const float* lb3  = (const float*)d_in[19];
    const float* lWi  = (const float*)d_in[20];
    const float* lbi  = (const float*)d_in[21];
    const float* lWo  = (const float*)d_in[22];
    const float* lbo  = (const float*)d_in[23];
    const float* lg0  = (const float*)d_in[24];
    const float* lh0  = (const float*)d_in[25];
    const float* lg1  = (const float*)d_in[26];
    const float* lh1  = (const float*)d_in[27];

    char* ws = (char*)d_ws;
    size_t off = 0;
    auto alloc = [&](size_t nbytes) { void* p = ws + off; off += (nbytes + 15) & ~(size_t)15; return p; };
    int*   E_idx = (int*)  alloc((size_t)BB * NN * KK * 4);
    float* D_nb  = (float*)alloc((size_t)BB * NN * KK * 4);
    float* ADb   = (float*)alloc((size_t)BB * NN * 3 * 4);
    float* Ofb   = (float*)alloc((size_t)BB * NN * 9 * 4);
    float* hV    = (float*)alloc((size_t)BB * NN * HH * 4);
    unsigned short* hEbH = (unsigned short*)alloc((size_t)BB * NN * KK * HH * 2);
    float* Pb    = (float*)alloc((size_t)BB * NN * HH * 4);
    float* Qb    = (float*)alloc((size_t)BB * NN * HH * 4);
    float* sBuf  = (float*)alloc((size_t)BB * NN * HH * 4);
    float* cntB  = (float*)alloc((size_t)BB * NN * 4);
    short* WeP   = (short*)alloc(2 * 8192 * 2);
    short* WqP   = (short*)alloc(2 * 16384 * 2);
    short* W1bP  = (short*)alloc(3 * 2 * 16384 * 2);
    short* W2P   = (short*)alloc(3 * 2 * 16384 * 2);
    short* W3P   = (short*)alloc(3 * 2 * 16384 * 2);
    short* WiP   = (short*)alloc(3 * 2 * 65536 * 2);
    short* WoP   = (short*)alloc(3 * 2 * 65536 * 2);
    short* W1acP = (short*)alloc(3 * 2 * 32768 * 2);
    short* WvP   = (short*)alloc(2 * 16384 * 2);
    if (off > ws_size) return;

    // Dispatch 1: knn | pack | orient (mutually independent)
    front_kernel<<<KNN_BLK + PACK_BLK + ORIENT_BLK, 256, 0, stream>>>(
        X, mask, E_idx, D_nb,
        We, Wq, lW1, lW2, lW3, lWi, lWo, Wv,
        WeP, WqP, W1bP, W2P, W3P, WiP, WoP, W1acP, WvP,
        ADb, Ofb);

    // Dispatch 2: edge_feat | node_feat16 (mutually independent; both need dispatch 1)
    mid_kernel<<<BB * NN + BB * NN / 16, 128, 0, stream>>>(
        X, E_idx, D_nb, Ofb, be, ge, he, bq, WeP, WqP, hEbH,
        ADb, Wn, bn, gn, hn, WvP, bv, W1acP, lb1, hV, Pb, Qb);

    for (int l = 0; l < 3; l++) {
        int last = (l == 2);
        msg_kernel<<<BB * NN / 2, 256, 0, stream>>>(
            mask, E_idx, hEbH, Pb, Qb,
            W1bP + (size_t)l * 32768,
            W2P + (size_t)l * 32768, lb2 + (size_t)l * HH,
            sBuf, cntB);
        node_kernel<<<BB * NN / 16, 512, 0, stream>>>(
            mask, sBuf, cntB, hV,
            W3P + (size_t)l * 32768, lb3 + (size_t)l * HH,
            WiP + (size_t)l * 131072, lbi + (size_t)l * DFF,
            WoP + (size_t)l * 131072, lbo + (size_t)l * HH,
            lg0 + (size_t)l * HH, lh0 + (size_t)l * HH,
            lg1 + (size_t)l * HH, lh1 + (size_t)l * HH,
            last ? nullptr : (W1acP + (size_t)(l + 1) * 65536),
            last ? nullptr : (lb1 + (size_t)(l + 1) * HH),
            last ? (float*)d_out : hV,
            Pb, Qb);
    }
}

// Round 14
// 299.071 us; speedup vs baseline: 1.0714x; 1.0544x over previous
//
#include <hip/hip_runtime.h>
#include <math.h>

typedef __attribute__((ext_vector_type(8))) short short8;
typedef __attribute__((ext_vector_type(4))) float f32x4;

#define BB 2
#define NN 2048
#define KK 32
#define HH 128
#define DFF 512
#define EPSF 1e-6f
#define INFV 1e30f

#define KNN_BLK 1024
#define PACK_BLK 2656
#define ORIENT_BLK 16

#define MFMA16(a, b, c) __builtin_amdgcn_mfma_f32_16x16x32_bf16((a), (b), (c), 0, 0, 0)

// ---------- helpers ----------

__device__ __forceinline__ unsigned short f2bf(float f) {
    unsigned u = __float_as_uint(f);
    u += 0x7fffu + ((u >> 16) & 1u);          // round-to-nearest-even
    return (unsigned short)(u >> 16);
}

__device__ __forceinline__ float bf2f(unsigned short h) {
    return __uint_as_float(((unsigned)h) << 16);
}

// split x into hi+lo bf16 pair — WEIGHTS only (systematic error must stay split)
__device__ __forceinline__ void f2bf2(float x, short& hi, short& lo) {
    unsigned short h = f2bf(x);
    hi = (short)h;
    lo = (short)f2bf(x - bf2f(h));
}

// pack 8 floats -> hi-plane short8
__device__ __forceinline__ short8 cvt8h(f32x4 a, f32x4 b) {
    short8 h8;
    #pragma unroll
    for (int i = 0; i < 4; i++) h8[i] = (short)f2bf(a[i]);
    #pragma unroll
    for (int i = 0; i < 4; i++) h8[4 + i] = (short)f2bf(b[i]);
    return h8;
}

__device__ __forceinline__ float sgnf(float x) {
    return (x > 0.f) ? 1.f : ((x < 0.f) ? -1.f : 0.f);
}

__device__ __forceinline__ void norm3(float& x, float& y, float& z) {
    float n = sqrtf(x * x + y * y + z * z);
    n = fmaxf(n, 1e-12f);
    x /= n; y /= n; z /= n;
}

// ---------- device bodies ----------

__device__ void knn_body(int bid4, const float* __restrict__ X,
                         const float* __restrict__ mask,
                         int* __restrict__ E_idx,
                         float* __restrict__ D_nb) {
    int w = threadIdx.x >> 6, lane = threadIdx.x & 63;
    int g = bid4 * 4 + w;
    int b = g >> 11, n = g & 2047;
    const float* Xb = X + (size_t)b * NN * 3;
    const float* mb = mask + (size_t)b * NN;

    float xn0 = Xb[n * 3], xn1 = Xb[n * 3 + 1], xn2 = Xb[n * 3 + 2];
    float mn = mb[n];

    float Dv[32], m2a[32];
    float lmax = -1e30f;
    #pragma unroll
    for (int s = 0; s < 32; s++) {
        int j = s * 64 + lane;
        float dx = Xb[j * 3] - xn0, dy = Xb[j * 3 + 1] - xn1, dz = Xb[j * 3 + 2] - xn2;
        float d = sqrtf(dx * dx + dy * dy + dz * dz + EPSF);
        float m2 = mn * mb[j];
        float v = m2 * d;
        Dv[s] = v; m2a[s] = m2;
        lmax = fmaxf(lmax, v);
    }
    #pragma unroll
    for (int off = 1; off <= 32; off <<= 1) lmax = fmaxf(lmax, __shfl_xor(lmax, off));
    float Dmax = lmax;
    #pragma unroll
    for (int s = 0; s < 32; s++) Dv[s] += (1.f - m2a[s]) * Dmax;

    // per-lane top-4 sorted list (strict < keeps earliest slot on exact ties).
    // 4-deep => refill (full masked rescan) only on a lane's 4th win: E[refills]≈0.15
    // per wave vs ~8 with top-2 — removes ~2700 VALU ops/wave.
    float l1 = INFV, l2 = INFV, l3 = INFV, l4 = INFV;
    int s1 = 0, s2 = 0, s3 = 0, s4 = 0;
    #pragma unroll
    for (int s = 0; s < 32; s++) {
        float v = Dv[s];
        bool lt1 = v < l1, lt2 = v < l2, lt3 = v < l3, lt4 = v < l4;
        float o1 = l1, o2 = l2, o3 = l3;
        int os1 = s1, os2 = s2, os3 = s3;
        l1 = lt1 ? v : l1;                    s1 = lt1 ? s : s1;
        l2 = lt1 ? o1 : (lt2 ? v : l2);       s2 = lt1 ? os1 : (lt2 ? s : s2);
        l3 = lt2 ? o2 : (lt3 ? v : l3);       s3 = lt2 ? os2 : (lt3 ? s : s3);
        l4 = lt3 ? o3 : (lt4 ? v : l4);       s4 = lt3 ? os3 : (lt4 ? s : s4);
    }

    unsigned used = 0u;
    float keepd = 0.f; int keepj = 0;

    for (int s = 0; s < KK; s++) {
        float m = l1;
        #pragma unroll
        for (int off = 1; off <= 32; off <<= 1) m = fminf(m, __shfl_xor(m, off));
        unsigned long long ball = __ballot(l1 == m);
        int jwin;
        if (__popcll(ball) == 1) {
            int src = (int)(__ffsll((long long)ball) - 1);
            jwin = __shfl(s1 * 64 + lane, src);
        } else {
            int jme = (l1 == m) ? (s1 * 64 + lane) : 0x7FFFFFFF;
            jwin = jme;
            #pragma unroll
            for (int off = 1; off <= 32; off <<= 1) jwin = min(jwin, __shfl_xor(jwin, off));
        }
        if (lane == s) { keepd = m; keepj = jwin; }
        if (lane == (jwin & 63)) {
            used |= 1u << s1;
            l1 = l2; s1 = s2;
            l2 = l3; s2 = s3;
            l3 = l4; s3 = s4;
            l4 = INFV;
            if (l1 >= INFV) {   // rare refill (4th win of this lane)
                l1 = INFV; l2 = INFV; l3 = INFV; l4 = INFV;
                #pragma unroll
                for (int i = 0; i < 32; i++) {
                    float v = ((used >> i) & 1u) ? INFV : Dv[i];
                    bool lt1 = v < l1, lt2 = v < l2, lt3 = v < l3, lt4 = v < l4;
                    float o1 = l1, o2 = l2, o3 = l3;
                    int os1 = s1, os2 = s2, os3 = s3;
                    l1 = lt1 ? v : l1;                    s1 = lt1 ? i : s1;
                    l2 = lt1 ? o1 : (lt2 ? v : l2);       s2 = lt1 ? os1 : (lt2 ? i : s2);
                    l3 = lt2 ? o2 : (lt3 ? v : l3);       s3 = lt2 ? os2 : (lt3 ? i : s3);
                    l4 = lt3 ? o3 : (lt4 ? v : l4);       s4 = lt3 ? os3 : (lt4 ? i : s4);
                }
            }
        }
    }
    if (lane < KK) {
        E_idx[(size_t)g * KK + lane] = keepj;
        D_nb[(size_t)g * KK + lane] = keepd;
    }
}

__device__ __forceinline__ void packB(const float* __restrict__ src, short* __restrict__ dH,
                                      short* __restrict__ dL, int e, int KC, int N, int Kreal) {
    int j = e & 7, ln = (e >> 3) & 63, t = e >> 9;
    int kc = t % KC, nt = t / KC;
    int k = kc * 32 + (ln >> 4) * 8 + j;
    int n = nt * 16 + (ln & 15);
    float v = (k < Kreal) ? src[(size_t)k * N + n] : 0.f;
    short hi, lo; f2bf2(v, hi, lo);
    dH[e] = hi; dL[e] = lo;
}

__device__ void pack_body(int e,
                          const float* __restrict__ We, const float* __restrict__ Wq,
                          const float* __restrict__ lW1, const float* __restrict__ lW2,
                          const float* __restrict__ lW3, const float* __restrict__ lWi,
                          const float* __restrict__ lWo, const float* __restrict__ Wv,
                          short* __restrict__ WeP, short* __restrict__ WqP,
                          short* __restrict__ W1bP, short* __restrict__ W2P,
                          short* __restrict__ W3P, short* __restrict__ WiP,
                          short* __restrict__ WoP, short* __restrict__ W1acP,
                          short* __restrict__ WvP) {
    if (e < 8192) { packB(We, WeP, WeP + 8192, e, 2, 128, 39); return; }
    e -= 8192;
    if (e < 16384) { packB(Wq, WqP, WqP + 16384, e, 4, 128, 128); return; }
    e -= 16384;
    if (e < 49152) {
        int l = e >> 14, r = e & 16383;
        packB(lW1 + (size_t)l * 49152 + 16384, W1bP + l * 32768, W1bP + l * 32768 + 16384, r, 4, 128, 128);
        return;
    }
    e -= 49152;
    if (e < 49152) {
        int l = e >> 14, r = e & 16383;
        packB(lW2 + (size_t)l * 16384, W2P + l * 32768, W2P + l * 32768 + 16384, r, 4, 128, 128);
        return;
    }
    e -= 49152;
    if (e < 49152) {
        int l = e >> 14, r = e & 16383;
        packB(lW3 + (size_t)l * 16384, W3P + l * 32768, W3P + l * 32768 + 16384, r, 4, 128, 128);
        return;
    }
    e -= 49152;
    if (e < 196608) {
        int l = e / 65536, r = e % 65536;
        packB(lWi + (size_t)l * 65536, WiP + l * 131072, WiP + l * 131072 + 65536, r, 4, 512, 128);
        return;
    }
    e -= 196608;
    if (e < 196608) {
        int l = e / 65536, r = e % 65536;
        packB(lWo + (size_t)l * 65536, WoP + l * 131072, WoP + l * 131072 + 65536, r, 16, 128, 512);
        return;
    }
    e -= 196608;
    if (e < 98304) {
        int l = e / 32768, r = e % 32768;
        int j = r & 7, ln = (r >> 3) & 63, t = r >> 9;
        int kc = t & 3, nt = t >> 2;
        int k = kc * 32 + (ln >> 4) * 8 + j;
        int n = nt * 16 + (ln & 15);
        const float* base = lW1 + (size_t)l * 49152;
        float v = (n < 128) ? base[(size_t)k * 128 + n] : base[(size_t)(256 + k) * 128 + (n - 128)];
        short hi, lo; f2bf2(v, hi, lo);
        short* dH = W1acP + l * 65536;
        dH[r] = hi; dH[32768 + r] = lo;
        return;
    }
    e -= 98304;
    // Wv pack (16384 elements)
    packB(Wv, WvP, WvP + 16384, e, 4, 128, 128);
}

__device__ void orient_body(int t, const float* __restrict__ X,
                            float* __restrict__ AD, float* __restrict__ Of) {
    if (t >= BB * NN) return;
    int b = t / NN, n = t % NN;
    float* ad = AD + (size_t)t * 3;
    float* of = Of + (size_t)t * 9;
    if (n < 1 || n > NN - 3) {
        ad[0] = ad[1] = ad[2] = 0.f;
        #pragma unroll
        for (int i = 0; i < 9; i++) of[i] = 0.f;
        return;
    }
    const float* Xb = X + (size_t)b * NN * 3;
    float p0x = Xb[(n - 1) * 3], p0y = Xb[(n - 1) * 3 + 1], p0z = Xb[(n - 1) * 3 + 2];
    float p1x = Xb[n * 3],       p1y = Xb[n * 3 + 1],       p1z = Xb[n * 3 + 2];
    float p2x = Xb[(n + 1) * 3], p2y = Xb[(n + 1) * 3 + 1], p2z = Xb[(n + 1) * 3 + 2];
    float p3x = Xb[(n + 2) * 3], p3y = Xb[(n + 2) * 3 + 1], p3z = Xb[(n + 2) * 3 + 2];

    float u2x = p1x - p0x, u2y = p1y - p0y, u2z = p1z - p0z; norm3(u2x, u2y, u2z);
    float u1x = p2x - p1x, u1y = p2y - p1y, u1z = p2z - p1z; norm3(u1x, u1y, u1z);
    float u0x = p3x - p2x, u0y = p3y - p2y, u0z = p3z - p2z; norm3(u0x, u0y, u0z);

    float n2x = u2y * u1z - u2z * u1y, n2y = u2z * u1x - u2x * u1z, n2z = u2x * u1y - u2y * u1x;
    norm3(n2x, n2y, n2z);
    float n1x = u1y * u0z - u1z * u0y, n1y = u1z * u0x - u1x * u0z, n1z = u1x * u0y - u1y * u0x;
    norm3(n1x, n1y, n1z);

    float cosA = -(u1x * u0x + u1y * u0y + u1z * u0z);
    cosA = fminf(fmaxf(cosA, -1.f + EPSF), 1.f - EPSF);
    float A = acosf(cosA);
    float cosD = n2x * n1x + n2y * n1y + n2z * n1z;
    cosD = fminf(fmaxf(cosD, -1.f + EPSF), 1.f - EPSF);
    float sg = sgnf(u2x * n1x + u2y * n1y + u2z * n1z);
    float Dih = sg * acosf(cosD);

    ad[0] = cosf(A);
    ad[1] = sinf(A) * cosf(Dih);
    ad[2] = sinf(A) * sinf(Dih);

    float o1x = u2x - u1x, o1y = u2y - u1y, o1z = u2z - u1z; norm3(o1x, o1y, o1z);
    float cx = o1y * n2z - o1z * n2y, cy = o1z * n2x - o1x * n2z, cz = o1x * n2y - o1y * n2x;
    of[0] = o1x; of[1] = o1y; of[2] = o1z;
    of[3] = n2x; of[4] = n2y; of[5] = n2z;
    of[6] = cx;  of[7] = cy;  of[8] = cz;
}

// ---------- FRONT: knn (blocks 0..1023) | pack (1024..3679) | orient (3680..3695) ----------

__global__ __launch_bounds__(256) void front_kernel(const float* __restrict__ X,
                                                    const float* __restrict__ mask,
                                                    int* __restrict__ E_idx,
                                                    float* __restrict__ D_nb,
                                                    const float* __restrict__ We,
                                                    const float* __restrict__ Wq,
                                                    const float* __restrict__ lW1,
                                                    const float* __restrict__ lW2,
                                                    const float* __restrict__ lW3,
                                                    const float* __restrict__ lWi,
                                                    const float* __restrict__ lWo,
                                                    const float* __restrict__ Wv,
                                                    short* __restrict__ WeP,
                                                    short* __restrict__ WqP,
                                                    short* __restrict__ W1bP,
                                                    short* __restrict__ W2P,
                                                    short* __restrict__ W3P,
                                                    short* __restrict__ WiP,
                                                    short* __restrict__ WoP,
                                                    short* __restrict__ W1acP,
                                                    short* __restrict__ WvP,
                                                    float* __restrict__ ADb,
                                                    float* __restrict__ Ofb) {
    int blk = blockIdx.x;
    if (blk < KNN_BLK) {
        knn_body(blk, X, mask, E_idx, D_nb);
    } else if (blk < KNN_BLK + PACK_BLK) {
        pack_body((blk - KNN_BLK) * 256 + threadIdx.x,
                  We, Wq, lW1, lW2, lW3, lWi, lWo, Wv,
                  WeP, WqP, W1bP, W2P, W3P, WiP, WoP, W1acP, WvP);
    } else {
        orient_body((blk - KNN_BLK - PACK_BLK) * 256 + threadIdx.x, X, ADb, Ofb);
    }
}

// ---------- MID: edge_feat (blocks 0..4095) | node_feat16 (4096..4351) ----------
// edge_feat: waves split over OUTPUT col-tiles (nt); hEbH output staged through
// LDS (AeH reuse) for coalesced short8 stores instead of 32 scalar 2B stores.

__global__ __launch_bounds__(128) void mid_kernel(const float* __restrict__ X,
                                                  const int* __restrict__ E_idx,
                                                  const float* __restrict__ D_nb,
                                                  const float* __restrict__ Of,
                                                  const float* __restrict__ be,
                                                  const float* __restrict__ ge,
                                                  const float* __restrict__ he,
                                                  const float* __restrict__ bq,
                                                  const short* __restrict__ WeP,
                                                  const short* __restrict__ WqP,
                                                  unsigned short* __restrict__ hEbH,
                                                  const float* __restrict__ AD,
                                                  const float* __restrict__ Wn,
                                                  const float* __restrict__ bn,
                                                  const float* __restrict__ gn,
                                                  const float* __restrict__ hn,
                                                  const short* __restrict__ WvP,
                                                  const float* __restrict__ bv,
                                                  const short* __restrict__ W1acP0,
                                                  const float* __restrict__ b1_0,
                                                  float* __restrict__ hV,
                                                  float* __restrict__ P,
                                                  float* __restrict__ Q) {
    __shared__ __align__(16) char smemRaw[15872];

    if (blockIdx.x < (unsigned)(BB * NN)) {
        // ----- edge_feat body -----
        short* AefH = (short*)smemRaw;                 // 32*72*2   = 4608 B
        short* AeH  = (short*)(smemRaw + 4608);        // 32*136*2  = 8704 B
        float* beS  = (float*)(smemRaw + 13312);       // 512 B
        float* geS  = beS + HH;
        float* heS  = geS + HH;
        float* bqS  = heS + HH;
        float* redSe = (float*)(smemRaw + 15360);      // [2][2][32] = 512 B

        int bid = blockIdx.x; int b = bid >> 11, n = bid & 2047; int tid = threadIdx.x;
        int lane = tid & 63, w = tid >> 6;
        beS[tid] = be[tid]; geS[tid] = ge[tid]; heS[tid] = he[tid]; bqS[tid] = bq[tid];
        {
            unsigned* Az = (unsigned*)AefH;
            for (int i = tid; i < 32 * 72 / 2; i += 128) Az[i] = 0u;
        }
        __syncthreads();

        int part = tid >> 5, k = tid & 31;
        int e = E_idx[(size_t)bid * KK + k];
        float dpos = (float)e - (float)n;
        if (part == 1 || part == 2) {
            int p0 = (part - 1) * 4;
            #pragma unroll
            for (int p = 0; p < 4; p++) {
                // freq = 10000^(-(p0+p)/8) = 10^(-(p0+p)/2) — compile-time constants
                float fr = (part == 1)
                    ? ((p == 0) ? 1.f : (p == 1) ? 0.31622776601683794f
                       : (p == 2) ? 0.1f : 0.031622776601683791f)
                    : ((p == 0) ? 0.01f : (p == 1) ? 0.0031622776601683794f
                       : (p == 2) ? 0.001f : 0.00031622776601683794f);
                float ang = dpos * fr;
                AefH[k * 72 + p0 + p]     = (short)f2bf(__cosf(ang));
                AefH[k * 72 + 8 + p0 + p] = (short)f2bf(__sinf(ang));
            }
        } else if (part == 3) {
            float Dv = D_nb[(size_t)bid * KK + k];
            #pragma unroll
            for (int i = 0; i < 16; i++) {
                float m = (20.f / 15.f) * (float)i;
                float z = (Dv - m) * 0.8f;
                AefH[k * 72 + 16 + i] = (short)f2bf(__expf(-z * z));
            }
        } else {
            const float* Omp = Of + (size_t)(b * NN + n) * 9;
            const float* Onp = Of + (size_t)(b * NN + e) * 9;
            float Om[9], On[9];
            #pragma unroll
            for (int i = 0; i < 9; i++) { Om[i] = Omp[i]; On[i] = Onp[i]; }
            float vx = X[(size_t)(b * NN + e) * 3 + 0] - X[(size_t)(b * NN + n) * 3 + 0];
            float vy = X[(size_t)(b * NN + e) * 3 + 1] - X[(size_t)(b * NN + n) * 3 + 1];
            float vz = X[(size_t)(b * NN + e) * 3 + 2] - X[(size_t)(b * NN + n) * 3 + 2];
            float t0 = Om[0] * vx + Om[1] * vy + Om[2] * vz;
            float t1 = Om[3] * vx + Om[4] * vy + Om[5] * vz;
            float t2 = Om[6] * vx + Om[7] * vy + Om[8] * vz;
            float nr = fmaxf(sqrtf(t0 * t0 + t1 * t1 + t2 * t2), 1e-12f);
            AefH[k * 72 + 32] = (short)f2bf(t0 / nr);
            AefH[k * 72 + 33] = (short)f2bf(t1 / nr);
            AefH[k * 72 + 34] = (short)f2bf(t2 / nr);
            float R[9];
            #pragma unroll
            for (int i = 0; i < 3; i++)
                #pragma unroll
                for (int l = 0; l < 3; l++)
                    R[i * 3 + l] = Om[0 + i] * On[0 + l] + Om[3 + i] * On[3 + l] + Om[6 + i] * On[6 + l];
            float Rxx = R[0], Ryy = R[4], Rzz = R[8];
            float mx = 0.5f * sqrtf(fabsf(1.f + Rxx - Ryy - Rzz));
            float my = 0.5f * sqrtf(fabsf(1.f - Rxx + Ryy - Rzz));
            float mz = 0.5f * sqrtf(fabsf(1.f - Rxx - Ryy + Rzz));
            float qx = sgnf(R[7] - R[5]) * mx;
            float qy = sgnf(R[2] - R[6]) * my;
            float qz = sgnf(R[3] - R[1]) * mz;
            float qw = 0.5f * sqrtf(fmaxf(1.f + Rxx + Ryy + Rzz, 0.f));
            float qn = fmaxf(sqrtf(qx * qx + qy * qy + qz * qz + qw * qw), 1e-12f);
            AefH[k * 72 + 35] = (short)f2bf(qx / qn);
            AefH[k * 72 + 36] = (short)f2bf(qy / qn);
            AefH[k * 72 + 37] = (short)f2bf(qz / qn);
            AefH[k * 72 + 38] = (short)f2bf(qw / qn);
        }
        __syncthreads();

        int m = lane & 15, q = lane >> 4;
        // A-frags: both row-tiles (t), this wave covers all 32 edges
        short8 aW[2][2];
        #pragma unroll
        for (int t = 0; t < 2; t++) {
            int row = (t * 16 + m) * 72;
            aW[t][0] = *(const short8*)&AefH[row + q * 8];
            aW[t][1] = *(const short8*)&AefH[row + 32 + q * 8];
        }
        f32x4 accA[4][2];   // [nt4][t]
        #pragma unroll
        for (int nt4 = 0; nt4 < 4; nt4++) {
            int ntg = w * 4 + nt4;
            const short* B0 = &WeP[((ntg * 2 + 0) * 64 + lane) * 8];
            const short* B1 = &WeP[((ntg * 2 + 1) * 64 + lane) * 8];
            short8 b0h = *(const short8*)B0, b0l = *(const short8*)(B0 + 8192);
            short8 b1h = *(const short8*)B1, b1l = *(const short8*)(B1 + 8192);
            float bc = beS[ntg * 16 + m];
            #pragma unroll
            for (int t = 0; t < 2; t++) {
                f32x4 acc = {bc, bc, bc, bc};
                acc = MFMA16(aW[t][0], b0h, acc);
                acc = MFMA16(aW[t][0], b0l, acc);
                acc = MFMA16(aW[t][1], b1h, acc);
                acc = MFMA16(aW[t][1], b1l, acc);
                accA[nt4][t] = acc;
            }
        }
        // cross-wave LN: partial su/sq per row over this wave's 64 cols
        #pragma unroll
        for (int t = 0; t < 2; t++)
            #pragma unroll
            for (int r = 0; r < 4; r++) {
                float su = accA[0][t][r] + accA[1][t][r] + accA[2][t][r] + accA[3][t][r];
                float sq2 = accA[0][t][r] * accA[0][t][r] + accA[1][t][r] * accA[1][t][r]
                          + accA[2][t][r] * accA[2][t][r] + accA[3][t][r] * accA[3][t][r];
                #pragma unroll
                for (int off = 1; off <= 8; off <<= 1) {
                    su += __shfl_xor(su, off); sq2 += __shfl_xor(sq2, off);
                }
                if (m == 0) {
                    int row = t * 16 + q * 4 + r;
                    redSe[(w * 2 + 0) * 32 + row] = su;
                    redSe[(w * 2 + 1) * 32 + row] = sq2;
                }
            }
        __syncthreads();
        float muA[2][4], invA[2][4];
        #pragma unroll
        for (int t = 0; t < 2; t++)
            #pragma unroll
            for (int r = 0; r < 4; r++) {
                int row = t * 16 + q * 4 + r;
                float S  = redSe[0 * 32 + row] + redSe[2 * 32 + row];
                float Q2 = redSe[1 * 32 + row] + redSe[3 * 32 + row];
                float mu = S * (1.f / HH);
                float var = (Q2 - (float)HH * mu * mu) * (1.f / (HH - 1));
                muA[t][r] = mu;
                invA[t][r] = 1.f / (sqrtf(var + EPSF) + EPSF);
            }
        #pragma unroll
        for (int nt4 = 0; nt4 < 4; nt4++) {
            int col = (w * 4 + nt4) * 16 + m;
            float g = geS[col], hh = heS[col];
            #pragma unroll
            for (int t = 0; t < 2; t++)
                #pragma unroll
                for (int r = 0; r < 4; r++) {
                    int edge = t * 16 + q * 4 + r;
                    float y = g * (accA[nt4][t][r] - muA[t][r]) * invA[t][r] + hh;
                    AeH[edge * 136 + col] = (short)f2bf(y);
                }
        }
        __syncthreads();

        short8 ah[2][4];
        #pragma unroll
        for (int t = 0; t < 2; t++)
            #pragma unroll
            for (int kc = 0; kc < 4; kc++)
                ah[t][kc] = *(const short8*)&AeH[(t * 16 + m) * 136 + kc * 32 + q * 8];
        __syncthreads();   // all A-frag preloads done — AeH becomes output staging

        #pragma unroll
        for (int nt4 = 0; nt4 < 4; nt4++) {
            int ntg = w * 4 + nt4;
            int col = ntg * 16 + m;
            short8 qh[4], ql[4];
            #pragma unroll
            for (int kc = 0; kc < 4; kc++) {
                const short* Bp = &WqP[((ntg * 4 + kc) * 64 + lane) * 8];
                qh[kc] = *(const short8*)Bp;
                ql[kc] = *(const short8*)(Bp + 16384);
            }
            float bc = bqS[col];
            #pragma unroll
            for (int t = 0; t < 2; t++) {
                f32x4 acc = {bc, bc, bc, bc};
                #pragma unroll
                for (int kc = 0; kc < 4; kc++) {
                    acc = MFMA16(ah[t][kc], qh[kc], acc);
                    acc = MFMA16(ah[t][kc], ql[kc], acc);
                }
                #pragma unroll
                for (int r = 0; r < 4; r++) {
                    int edge = t * 16 + q * 4 + r;
                    AeH[edge * 136 + col] = (short)f2bf(acc[r]);
                }
            }
        }
        __syncthreads();

        // coalesced copy-out: 512 short8 chunks, 4 per thread (256B contiguous/row)
        {
            unsigned short* outp = hEbH + (size_t)bid * (KK * HH);
            #pragma unroll
            for (int it = 0; it < 4; it++) {
                int idx = it * 128 + tid;       // 0..511
                int row = idx >> 4, c8 = idx & 15;
                *(short8*)(outp + row * HH + c8 * 8) = *(const short8*)&AeH[row * 136 + c8 * 8];
            }
        }
    } else {
        // ----- node_feat body: 16 nodes per block, MFMA path -----
        short* yH  = (short*)smemRaw;                  // 16*136*2 = 4352 B
        short* hvH = (short*)(smemRaw + 4352);         // 4352 B

        int nb = blockIdx.x - BB * NN;
        int g0 = nb * 16;
        int tid = threadIdx.x;
        int lane = tid & 63, w = tid >> 6;
        int m = lane & 15, q = lane >> 4;

        // step 1: V = AD @ Wn + bn, per-node LN -> y (bf16 in LDS)
        {
            int i = tid >> 3;          // node 0..15
            int j = tid & 7;           // column group (16 cols each)
            int h0 = j * 16;
            const float* ad = AD + (size_t)(g0 + i) * 3;
            float a0 = ad[0], a1 = ad[1], a2 = ad[2];
            float v[16];
            float su = 0.f, sq = 0.f;
            #pragma unroll
            for (int c = 0; c < 16; c++) {
                int h = h0 + c;
                float t = bn[h] + a0 * Wn[h] + a1 * Wn[HH + h] + a2 * Wn[2 * HH + h];
                v[c] = t; su += t; sq += t * t;
            }
            #pragma unroll
            for (int off = 1; off <= 4; off <<= 1) {
                su += __shfl_xor(su, off); sq += __shfl_xor(sq, off);
            }
            float mu = su * (1.f / HH);
            float var = (sq - (float)HH * mu * mu) * (1.f / (HH - 1));
            float inv = 1.f / (sqrtf(var + EPSF) + EPSF);
            #pragma unroll
            for (int c = 0; c < 16; c++) {
                int h = h0 + c;
                yH[i * 136 + h] = (short)f2bf(gn[h] * (v[c] - mu) * inv + hn[h]);
            }
        }
        __syncthreads();

        // step 2: hV = y @ Wv + bv  (wave handles 4 of 8 col-tiles)
        short8 ayh[4];
        #pragma unroll
        for (int kc = 0; kc < 4; kc++)
            ayh[kc] = *(const short8*)&yH[m * 136 + kc * 32 + q * 8];
        #pragma unroll
        for (int u = 0; u < 4; u++) {
            int nt = w * 4 + u;
            int col = nt * 16 + m;
            float bc = bv[col];
            f32x4 a = {bc, bc, bc, bc};
            #pragma unroll
            for (int kc = 0; kc < 4; kc++) {
                const short* Bp = &WvP[((nt * 4 + kc) * 64 + lane) * 8];
                short8 bh = *(const short8*)Bp, bl = *(const short8*)(Bp + 16384);
                a = MFMA16(ayh[kc], bh, a);
                a = MFMA16(ayh[kc], bl, a);
            }
            #pragma unroll
            for (int r = 0; r < 4; r++) {
                int rw = q * 4 + r;
                hV[(size_t)(g0 + rw) * HH + col] = a[r];
                hvH[rw * 136 + col] = (short)f2bf(a[r]);
            }
        }
        __syncthreads();

        // step 3: layer-0 premix P/Q = hV @ W1_0[a|c] (+b1 for P), via packed W1acP[0]
        short8 avh[4];
        #pragma unroll
        for (int kc = 0; kc < 4; kc++)
            avh[kc] = *(const short8*)&hvH[m * 136 + kc * 32 + q * 8];
        #pragma unroll
        for (int u = 0; u < 8; u++) {
            int nt = w * 8 + u;
            int col = nt * 16 + m;
            float b0 = (nt < 8) ? b1_0[col] : 0.f;
            f32x4 a = {b0, b0, b0, b0};
            #pragma unroll
            for (int kc = 0; kc < 4; kc++) {
                const short* Bp = &W1acP0[((nt * 4 + kc) * 64 + lane) * 8];
                short8 bh = *(const short8*)Bp, bl = *(const short8*)(Bp + 32768);
                a = MFMA16(avh[kc], bh, a);
                a = MFMA16(avh[kc], bl, a);
            }
            #pragma unroll
            for (int r = 0; r < 4; r++) {
                size_t rw = g0 + q * 4 + r;
                if (nt < 8) P[rw * HH + col] = a[r];
                else        Q[rw * HH + (col - 128)] = a[r];
            }
        }
    }
}

// ---------- message kernel: block = 2 nodes, 4 waves, 2 nt-tiles per wave ----------
// (r7 form — best measured) A-side staged in LDS; weights loaded once per nt-tile
// per wave and reused for both nodes; 4 blocks/CU = 16 waves/CU.

__global__ __launch_bounds__(256) void msg_kernel(const float* __restrict__ mask,
                                                  const int* __restrict__ E_idx,
                                                  const unsigned short* __restrict__ hEbH,
                                                  const float* __restrict__ P,
                                                  const float* __restrict__ Q,
                                                  const short* __restrict__ W1bP,
                                                  const short* __restrict__ W2P,
                                                  const float* __restrict__ b2,
                                                  float* __restrict__ sOut,
                                                  float* __restrict__ cntOut) {
    __shared__ short stg[2][32 * 136];   // staged h_E (bf16) per node
    __shared__ short AmH[2][32 * 136];   // m1 (bf16) per node

    int tid = threadIdx.x;
    int w = tid >> 6, lane = tid & 63;
    int gA = blockIdx.x * 2;             // nodes gA, gA+1 (same batch: NN even)
    int b = gA >> 11;
    int m = lane & 15, q = lane >> 4;

    // ---- stage hEbH for both nodes (fully coalesced short8 loads) ----
    {
        const short8* src = (const short8*)(hEbH + (size_t)gA * (KK * HH));
        #pragma unroll
        for (int it = 0; it < 4; it++) {
            int idx = it * 256 + tid;        // 0..1023 short8 chunks
            int nd = idx >> 9;
            int rem = idx & 511;
            int e = rem >> 4;                // edge
            int c8 = rem & 15;               // col/8
            short8 v = src[idx];
            *(short8*)&stg[nd][e * 136 + c8 * 8] = v;
        }
    }

    int qbase[2][2][4]; float mt[2][2][4];
    #pragma unroll
    for (int nd = 0; nd < 2; nd++) {
        float maskv = mask[gA + nd];
        #pragma unroll
        for (int t = 0; t < 2; t++)
            #pragma unroll
            for (int r = 0; r < 4; r++) {
                int row = t * 16 + q * 4 + r;
                int e = E_idx[(size_t)(gA + nd) * KK + row];
                qbase[nd][t][r] = (b * NN + e) * HH;
                mt[nd][t][r] = maskv * mask[b * NN + e];
            }
    }
    if (w < 2) {
        // wave w (0,1) produces cnt for node w
        float c8 = mt[w][0][0] + mt[w][0][1] + mt[w][0][2] + mt[w][0][3]
                 + mt[w][1][0] + mt[w][1][1] + mt[w][1][2] + mt[w][1][3];
        c8 += __shfl_xor(c8, 16);
        c8 += __shfl_xor(c8, 32);
        if (lane == 0) cntOut[gA + w] = c8;
    }

    float preg[2][2], b2reg[2];
    #pragma unroll
    for (int u = 0; u < 2; u++) {
        int colg = (w * 2 + u) * 16 + m;
        b2reg[u] = b2[colg];
        preg[0][u] = P[(size_t)gA * HH + colg];
        preg[1][u] = P[(size_t)(gA + 1) * HH + colg];
    }
    __syncthreads();

    // phase 1: m1 = relu(P + Q[nbr] + h_E @ W1b) — wave handles 2 nt tiles, both nodes
    #pragma unroll
    for (int u = 0; u < 2; u++) {
        int ntg = w * 2 + u;
        int colg = ntg * 16 + m;
        short8 bh[4], bl[4];
        #pragma unroll
        for (int kc = 0; kc < 4; kc++) {
            const short* Bp = &W1bP[((ntg * 4 + kc) * 64 + lane) * 8];
            bh[kc] = *(const short8*)Bp;
            bl[kc] = *(const short8*)(Bp + 16384);
        }
        #pragma unroll
        for (int nd = 0; nd < 2; nd++) {
            f32x4 t0 = {0.f, 0.f, 0.f, 0.f}, t1 = {0.f, 0.f, 0.f, 0.f};
            #pragma unroll
            for (int kc = 0; kc < 4; kc++) {
                short8 a0 = *(const short8*)&stg[nd][(0 * 16 + m) * 136 + kc * 32 + q * 8];
                short8 a1 = *(const short8*)&stg[nd][(1 * 16 + m) * 136 + kc * 32 + q * 8];
                t0 = MFMA16(a0, bh[kc], t0);
                t0 = MFMA16(a0, bl[kc], t0);
                t1 = MFMA16(a1, bh[kc], t1);
                t1 = MFMA16(a1, bl[kc], t1);
            }
            float pp = preg[nd][u];
            #pragma unroll
            for (int r = 0; r < 4; r++) {
                float v0 = fmaxf(t0[r] + pp + Q[(size_t)qbase[nd][0][r] + colg], 0.f);
                AmH[nd][(q * 4 + r) * 136 + colg] = (short)f2bf(v0);
                float v1 = fmaxf(t1[r] + pp + Q[(size_t)qbase[nd][1][r] + colg], 0.f);
                AmH[nd][(16 + q * 4 + r) * 136 + colg] = (short)f2bf(v1);
            }
        }
    }
    __syncthreads();

    // phase 2: m2 = relu(m1 @ W2 + b2); masked sum over 32 edges
    #pragma unroll
    for (int u = 0; u < 2; u++) {
        int ntg = w * 2 + u;
        short8 bh[4], bl[4];
        #pragma unroll
        for (int kc = 0; kc < 4; kc++) {
            const short* Bp = &W2P[((ntg * 4 + kc) * 64 + lane) * 8];
            bh[kc] = *(const short8*)Bp;
            bl[kc] = *(const short8*)(Bp + 16384);
        }
        float bc = b2reg[u];
        #pragma unroll
        for (int nd = 0; nd < 2; nd++) {
            f32x4 a0 = {bc, bc, bc, bc}, a1 = {bc, bc, bc, bc};
            #pragma unroll
            for (int kc = 0; kc < 4; kc++) {
                short8 m0 = *(const short8*)&AmH[nd][(0 * 16 + m) * 136 + kc * 32 + q * 8];
                short8 m1 = *(const short8*)&AmH[nd][(1 * 16 + m) * 136 + kc * 32 + q * 8];
                a0 = MFMA16(m0, bh[kc], a0);
                a0 = MFMA16(m0, bl[kc], a0);
                a1 = MFMA16(m1, bh[kc], a1);
                a1 = MFMA16(m1, bl[kc], a1);
            }
            float part = 0.f;
            #pragma unroll
            for (int r = 0; r < 4; r++)
                part += fmaxf(a0[r], 0.f) * mt[nd][0][r] + fmaxf(a1[r], 0.f) * mt[nd][1][r];
            part += __shfl_xor(part, 16);
            part += __shfl_xor(part, 32);
            if (q == 0) sOut[(size_t)(gA + nd) * HH + ntg * 16 + m] = part;
        }
    }
}

// ---------- node kernel: 8 waves (512 threads), 16 nodes/block ----------

#define HSTR 520   // LDS stride (shorts) for 512-wide hidden staging

__global__ __launch_bounds__(512, 2) void node_kernel(const float* __restrict__ mask,
                                                      const float* __restrict__ sbuf,
                                                      const float* __restrict__ cntb,
                                                      const float* __restrict__ hVin,
                                                      const short* __restrict__ W3P,
                                                      const float* __restrict__ b3,
                                                      const short* __restrict__ WiP,
                                                      const float* __restrict__ biN,
                                                      const short* __restrict__ WoP,
                                                      const float* __restrict__ boN,
                                                      const float* __restrict__ g0,
                                                      const float* __restrict__ h0,
                                                      const float* __restrict__ g1,
                                                      const float* __restrict__ h1,
                                                      const short* __restrict__ W1P,
                                                      const float* __restrict__ b1n,
                                                      float* __restrict__ hVout,
                                                      float* __restrict__ Pn,
                                                      float* __restrict__ Qn) {
    __shared__ short rbH[16 * 136];
    __shared__ short hbH[16 * HSTR];
    __shared__ float redS[8][2][16];
    __shared__ float g0S[128], h0S[128], g1S[128], h1S[128], b3S[128], boS[128], b1S[128];
    __shared__ float biS[512];

    int tid = threadIdx.x;
    int w = tid >> 6, lane = tid & 63;
    int m = lane & 15, q = lane >> 4;
    int rowT = blockIdx.x * 16;

    if (tid < 128) {
        int i = tid;
        g0S[i] = g0[i]; h0S[i] = h0[i]; g1S[i] = g1[i]; h1S[i] = h1[i];
        b3S[i] = b3[i]; boS[i] = boN[i]; b1S[i] = W1P ? b1n[i] : 0.f;
    }
    biS[tid] = biN[tid];
    __syncthreads();

    short8 ash[4];
    #pragma unroll
    for (int kc = 0; kc < 4; kc++) {
        const float* sp = &sbuf[(size_t)(rowT + m) * HH + kc * 32 + q * 8];
        f32x4 x0 = *(const f32x4*)sp;
        f32x4 x1 = *(const f32x4*)(sp + 4);
        ash[kc] = cvt8h(x0, x1);
    }
    float cntr[4];
    #pragma unroll
    for (int r = 0; r < 4; r++) cntr[r] = cntb[rowT + q * 4 + r];

    // W3: wave w owns col-tile w
    f32x4 vC;
    {
        f32x4 a = {0.f, 0.f, 0.f, 0.f};
        #pragma unroll
        for (int kc = 0; kc < 4; kc++) {
            const short* Bp = &W3P[((w * 4 + kc) * 64 + lane) * 8];
            short8 bh = *(const short8*)Bp, bl = *(const short8*)(Bp + 16384);
            a = MFMA16(ash[kc], bh, a);
            a = MFMA16(ash[kc], bl, a);
        }
        int col = w * 16 + m;
        #pragma unroll
        for (int r = 0; r < 4; r++) {
            float tv = (a[r] + cntr[r] * b3S[col]) * (1.f / 30.f);
            a[r] = hVin[(size_t)(rowT + q * 4 + r) * HH + col] + tv;
        }
        vC = a;
    }

    // LN0 (cross-8-wave)
    {
        float su[4], sq[4];
        #pragma unroll
        for (int r = 0; r < 4; r++) { float v = vC[r]; su[r] = v; sq[r] = v * v; }
        #pragma unroll
        for (int off = 1; off <= 8; off <<= 1)
            #pragma unroll
            for (int r = 0; r < 4; r++) { su[r] += __shfl_xor(su[r], off); sq[r] += __shfl_xor(sq[r], off); }
        if (m == 0) {
            #pragma unroll
            for (int r = 0; r < 4; r++) { redS[w][0][q * 4 + r] = su[r]; redS[w][1][q * 4 + r] = sq[r]; }
        }
    }
    __syncthreads();
    float mu[4], inv[4];
    #pragma unroll
    for (int r = 0; r < 4; r++) {
        int row = q * 4 + r;
        float S = 0.f, Q2 = 0.f;
        #pragma unroll
        for (int ww = 0; ww < 8; ww++) { S += redS[ww][0][row]; Q2 += redS[ww][1][row]; }
        mu[r] = S * (1.f / HH);
        float var = (Q2 - (float)HH * mu[r] * mu[r]) * (1.f / (HH - 1));
        inv[r] = 1.f / (sqrtf(var + EPSF) + EPSF);
    }
    {
        int col = w * 16 + m;
        #pragma unroll
        for (int r = 0; r < 4; r++) {
            vC[r] = g0S[col] * (vC[r] - mu[r]) * inv[r] + h0S[col];
            rbH[(q * 4 + r) * 136 + col] = (short)f2bf(vC[r]);
        }
    }
    __syncthreads();

    short8 avh[4];
    #pragma unroll
    for (int kc = 0; kc < 4; kc++)
        avh[kc] = *(const short8*)&rbH[m * 136 + kc * 32 + q * 8];

    // FFN-in: wave's 64 hidden cols (4 of 32 tiles)
    #pragma unroll
    for (int u = 0; u < 4; u++) {
        int nt = w * 4 + u;
        int jcol = nt * 16 + m;
        float bb = biS[jcol];
        f32x4 a = {bb, bb, bb, bb};
        #pragma unroll
        for (int kc = 0; kc < 4; kc++) {
            const short* Bp = &WiP[((nt * 4 + kc) * 64 + lane) * 8];
            short8 bh = *(const short8*)Bp, bl = *(const short8*)(Bp + 65536);
            a = MFMA16(avh[kc], bh, a);
            a = MFMA16(avh[kc], bl, a);
        }
        #pragma unroll
        for (int r = 0; r < 4; r++)
            hbH[(q * 4 + r) * HSTR + jcol] = (short)f2bf(fmaxf(a[r], 0.f));
    }
    __syncthreads();

    // FFN-out: wave's col-tile w over ALL 512 hidden
    f32x4 oC = {0.f, 0.f, 0.f, 0.f};
    for (int kc2 = 0; kc2 < 16; kc2++) {
        short8 ahh = *(const short8*)&hbH[m * HSTR + kc2 * 32 + q * 8];
        const short* Bp = &WoP[((w * 16 + kc2) * 64 + lane) * 8];
        short8 bh = *(const short8*)Bp, bl = *(const short8*)(Bp + 65536);
        oC = MFMA16(ahh, bh, oC);
        oC = MFMA16(ahh, bl, oC);
    }
    {
        int col = w * 16 + m;
        #pragma unroll
        for (int r = 0; r < 4; r++)
            oC[r] += boS[col] + vC[r];
    }

    // LN1 (cross-8-wave)
    {
        float su[4], sq[4];
        #pragma unroll
        for (int r = 0; r < 4; r++) { float v = oC[r]; su[r] = v; sq[r] = v * v; }
        #pragma unroll
        for (int off = 1; off <= 8; off <<= 1)
            #pragma unroll
            for (int r = 0; r < 4; r++) { su[r] += __shfl_xor(su[r], off); sq[r] += __shfl_xor(sq[r], off); }
        __syncthreads();   // redS reuse
        if (m == 0) {
            #pragma unroll
            for (int r = 0; r < 4; r++) { redS[w][0][q * 4 + r] = su[r]; redS[w][1][q * 4 + r] = sq[r]; }
        }
    }
    __syncthreads();
    #pragma unroll
    for (int r = 0; r < 4; r++) {
        int row = q * 4 + r;
        float S = 0.f, Q2 = 0.f;
        #pragma unroll
        for (int ww = 0; ww < 8; ww++) { S += redS[ww][0][row]; Q2 += redS[ww][1][row]; }
        mu[r] = S * (1.f / HH);
        float var = (Q2 - (float)HH * mu[r] * mu[r]) * (1.f / (HH - 1));
        inv[r] = 1.f / (sqrtf(var + EPSF) + EPSF);
    }
    float mk[4];
    #pragma unroll
    for (int r = 0; r < 4; r++) mk[r] = mask[rowT + q * 4 + r];
    {
        int col = w * 16 + m;
        #pragma unroll
        for (int r = 0; r < 4; r++) {
            float y = g1S[col] * (oC[r] - mu[r]) * inv[r] + h1S[col];
            y *= mk[r];
            oC[r] = y;
            hVout[(size_t)(rowT + q * 4 + r) * HH + col] = y;
        }
    }

    // fused next-layer premix (wave's 2 of 16 col-tiles)
    if (W1P) {
        __syncthreads();
        {
            int col = w * 16 + m;
            #pragma unroll
            for (int r = 0; r < 4; r++)
                rbH[(q * 4 + r) * 136 + col] = (short)f2bf(oC[r]);
        }
        __syncthreads();
        short8 ayh[4];
        #pragma unroll
        for (int kc = 0; kc < 4; kc++)
            ayh[kc] = *(const short8*)&rbH[m * 136 + kc * 32 + q * 8];
        #pragma unroll
        for (int u = 0; u < 2; u++) {
            int nt = w * 2 + u;
            int col = nt * 16 + m;
            float b0 = (nt < 8) ? b1S[col] : 0.f;
            f32x4 a = {b0, b0, b0, b0};
            #pragma unroll
            for (int kc = 0; kc < 4; kc++) {
                const short* Bp = &W1P[((nt * 4 + kc) * 64 + lane) * 8];
                short8 bh = *(const short8*)Bp, bl = *(const short8*)(Bp + 32768);
                a = MFMA16(ayh[kc], bh, a);
                a = MFMA16(ayh[kc], bl, a);
            }
            #pragma unroll
            for (int r = 0; r < 4; r++) {
                size_t row = rowT + q * 4 + r;
                if (nt < 8) Pn[row * HH + col] = a[r];
                else        Qn[row * HH + (col - 128)] = a[r];
            }
        }
    }
}

// ---------- launch ----------

extern "C" void kernel_launch(void* const* d_in, const int* in_sizes, int n_in,
                              void* d_out, int out_size, void* d_ws, size_t ws_size,
                              hipStream_t stream) {
    const float* X    = (const float*)d_in[0];
    const float* mask = (const float*)d_in[1];
    const float* Wn   = (const float*)d_in[2];
    const float* bn   = (const float*)d_in[3];
    const float* gn   = (const float*)d_in[4];
    const float* hn   = (const float*)d_in[5];
    const float* We   = (const float*)d_in[6];
    const float* be   = (const float*)d_in[7];
    const float* ge   = (const float*)d_in[8];
    const float* he   = (const float*)d_in[9];
    const float* Wv   = (const float*)d_in[10];
    const float* bv   = (const float*)d_in[11];
    const float* Wq   = (const float*)d_in[12];
    const float* bq   = (const float*)d_in[13];
    const float* lW1  = (const float*)d_in[14];
    const float* lb1  = (const float*)d_in[15];
    const float* lW2  = (const float*)d_in[16];
    const float* lb2  = (const float*)d_in[17];
    const float* lW3  = (const float*)d_in[18];
    const float* lb3  = (const float*)d_in[19];
    const float* lWi  = (const float*)d_in[20];
    const float* lbi  = (const float*)d_in[21];
    const float* lWo  = (const float*)d_in[22];
    const float* lbo  = (const float*)d_in[23];
    const float* lg0  = (const float*)d_in[24];
    const float* lh0  = (const float*)d_in[25];
    const float* lg1  = (const float*)d_in[26];
    const float* lh1  = (const float*)d_in[27];

    char* ws = (char*)d_ws;
    size_t off = 0;
    auto alloc = [&](size_t nbytes) { void* p = ws + off; off += (nbytes + 15) & ~(size_t)15; return p; };
    int*   E_idx = (int*)  alloc((size_t)BB * NN * KK * 4);
    float* D_nb  = (float*)alloc((size_t)BB * NN * KK * 4);
    float* ADb   = (float*)alloc((size_t)BB * NN * 3 * 4);
    float* Ofb   = (float*)alloc((size_t)BB * NN * 9 * 4);
    float* hV    = (float*)alloc((size_t)BB * NN * HH * 4);
    unsigned short* hEbH = (unsigned short*)alloc((size_t)BB * NN * KK * HH * 2);
    float* Pb    = (float*)alloc((size_t)BB * NN * HH * 4);
    float* Qb    = (float*)alloc((size_t)BB * NN * HH * 4);
    float* sBuf  = (float*)alloc((size_t)BB * NN * HH * 4);
    float* cntB  = (float*)alloc((size_t)BB * NN * 4);
    short* WeP   = (short*)alloc(2 * 8192 * 2);
    short* WqP   = (short*)alloc(2 * 16384 * 2);
    short* W1bP  = (short*)alloc(3 * 2 * 16384 * 2);
    short* W2P   = (short*)alloc(3 * 2 * 16384 * 2);
    short* W3P   = (short*)alloc(3 * 2 * 16384 * 2);
    short* WiP   = (short*)alloc(3 * 2 * 65536 * 2);
    short* WoP   = (short*)alloc(3 * 2 * 65536 * 2);
    short* W1acP = (short*)alloc(3 * 2 * 32768 * 2);
    short* WvP   = (short*)alloc(2 * 16384 * 2);
    if (off > ws_size) return;

    // Dispatch 1: knn | pack | orient (mutually independent)
    front_kernel<<<KNN_BLK + PACK_BLK + ORIENT_BLK, 256, 0, stream>>>(
        X, mask, E_idx, D_nb,
        We, Wq, lW1, lW2, lW3, lWi, lWo, Wv,
        WeP, WqP, W1bP, W2P, W3P, WiP, WoP, W1acP, WvP,
        ADb, Ofb);

    // Dispatch 2: edge_feat | node_feat16 (mutually independent; both need dispatch 1)
    mid_kernel<<<BB * NN + BB * NN / 16, 128, 0, stream>>>(
        X, E_idx, D_nb, Ofb, be, ge, he, bq, WeP, WqP, hEbH,
        ADb, Wn, bn, gn, hn, WvP, bv, W1acP, lb1, hV, Pb, Qb);

    for (int l = 0; l < 3; l++) {
        int last = (l == 2);
        msg_kernel<<<BB * NN / 2, 256, 0, stream>>>(
            mask, E_idx, hEbH, Pb, Qb,
            W1bP + (size_t)l * 32768,
            W2P + (size_t)l * 32768, lb2 + (size_t)l * HH,
            sBuf, cntB);
        node_kernel<<<BB * NN / 16, 512, 0, stream>>>(
            mask, sBuf, cntB, hV,
            W3P + (size_t)l * 32768, lb3 + (size_t)l * HH,
            WiP + (size_t)l * 131072, lbi + (size_t)l * DFF,
            WoP + (size_t)l * 131072, lbo + (size_t)l * HH,
            lg0 + (size_t)l * HH, lh0 + (size_t)l * HH,
            lg1 + (size_t)l * HH, lh1 + (size_t)l * HH,
            last ? nullptr : (W1acP + (size_t)(l + 1) * 65536),
            last ? nullptr : (lb1 + (size_t)(l + 1) * HH),
            last ? (float*)d_out : hV,
            Pb, Qb);
    }
}

// Round 15
// 297.667 us; speedup vs baseline: 1.0765x; 1.0047x over previous
//
#include <hip/hip_runtime.h>
#include <math.h>

typedef __attribute__((ext_vector_type(8))) short short8;
typedef __attribute__((ext_vector_type(4))) float f32x4;

#define BB 2
#define NN 2048
#define KK 32
#define HH 128
#define DFF 512
#define EPSF 1e-6f
#define INFV 1e30f

#define KNN_BLK 1024
#define PACK_BLK 2656
#define ORIENT_BLK 16

#define MFMA16(a, b, c) __builtin_amdgcn_mfma_f32_16x16x32_bf16((a), (b), (c), 0, 0, 0)

// ---------- helpers ----------

__device__ __forceinline__ unsigned short f2bf(float f) {
    unsigned u = __float_as_uint(f);
    u += 0x7fffu + ((u >> 16) & 1u);          // round-to-nearest-even
    return (unsigned short)(u >> 16);
}

__device__ __forceinline__ float bf2f(unsigned short h) {
    return __uint_as_float(((unsigned)h) << 16);
}

// split x into hi+lo bf16 pair — WEIGHTS only (systematic error must stay split)
__device__ __forceinline__ void f2bf2(float x, short& hi, short& lo) {
    unsigned short h = f2bf(x);
    hi = (short)h;
    lo = (short)f2bf(x - bf2f(h));
}

// pack 8 floats -> hi-plane short8
__device__ __forceinline__ short8 cvt8h(f32x4 a, f32x4 b) {
    short8 h8;
    #pragma unroll
    for (int i = 0; i < 4; i++) h8[i] = (short)f2bf(a[i]);
    #pragma unroll
    for (int i = 0; i < 4; i++) h8[4 + i] = (short)f2bf(b[i]);
    return h8;
}

__device__ __forceinline__ float sgnf(float x) {
    return (x > 0.f) ? 1.f : ((x < 0.f) ? -1.f : 0.f);
}

__device__ __forceinline__ void norm3(float& x, float& y, float& z) {
    float n = sqrtf(x * x + y * y + z * z);
    n = fmaxf(n, 1e-12f);
    x /= n; y /= n; z /= n;
}

// ---------- device bodies ----------

__device__ void knn_body(int bid4, const float* __restrict__ X,
                         const float* __restrict__ mask,
                         int* __restrict__ E_idx,
                         float* __restrict__ D_nb) {
    int w = threadIdx.x >> 6, lane = threadIdx.x & 63;
    int g = bid4 * 4 + w;
    int b = g >> 11, n = g & 2047;
    const float* Xb = X + (size_t)b * NN * 3;
    const float* mb = mask + (size_t)b * NN;

    float xn0 = Xb[n * 3], xn1 = Xb[n * 3 + 1], xn2 = Xb[n * 3 + 2];
    float mn = mb[n];

    float Dv[32], m2a[32];
    float lmax = -1e30f;
    #pragma unroll
    for (int s = 0; s < 32; s++) {
        int j = s * 64 + lane;
        float dx = Xb[j * 3] - xn0, dy = Xb[j * 3 + 1] - xn1, dz = Xb[j * 3 + 2] - xn2;
        float d = sqrtf(dx * dx + dy * dy + dz * dz + EPSF);
        float m2 = mn * mb[j];
        float v = m2 * d;
        Dv[s] = v; m2a[s] = m2;
        lmax = fmaxf(lmax, v);
    }
    #pragma unroll
    for (int off = 1; off <= 32; off <<= 1) lmax = fmaxf(lmax, __shfl_xor(lmax, off));
    float Dmax = lmax;
    #pragma unroll
    for (int s = 0; s < 32; s++) Dv[s] += (1.f - m2a[s]) * Dmax;

    // per-lane top-4 sorted list (strict < keeps earliest slot on exact ties).
    // 4-deep => refill (full masked rescan) only on a lane's 4th win: E[refills]≈0.15
    // per wave vs ~8 with top-2 — removes ~2700 VALU ops/wave.
    float l1 = INFV, l2 = INFV, l3 = INFV, l4 = INFV;
    int s1 = 0, s2 = 0, s3 = 0, s4 = 0;
    #pragma unroll
    for (int s = 0; s < 32; s++) {
        float v = Dv[s];
        bool lt1 = v < l1, lt2 = v < l2, lt3 = v < l3, lt4 = v < l4;
        float o1 = l1, o2 = l2, o3 = l3;
        int os1 = s1, os2 = s2, os3 = s3;
        l1 = lt1 ? v : l1;                    s1 = lt1 ? s : s1;
        l2 = lt1 ? o1 : (lt2 ? v : l2);       s2 = lt1 ? os1 : (lt2 ? s : s2);
        l3 = lt2 ? o2 : (lt3 ? v : l3);       s3 = lt2 ? os2 : (lt3 ? s : s3);
        l4 = lt3 ? o3 : (lt4 ? v : l4);       s4 = lt3 ? os3 : (lt4 ? s : s4);
    }

    unsigned used = 0u;
    float keepd = 0.f; int keepj = 0;

    for (int s = 0; s < KK; s++) {
        float m = l1;
        #pragma unroll
        for (int off = 1; off <= 32; off <<= 1) m = fminf(m, __shfl_xor(m, off));
        unsigned long long ball = __ballot(l1 == m);
        int jwin;
        if (__popcll(ball) == 1) {
            int src = (int)(__ffsll((long long)ball) - 1);
            jwin = __shfl(s1 * 64 + lane, src);
        } else {
            int jme = (l1 == m) ? (s1 * 64 + lane) : 0x7FFFFFFF;
            jwin = jme;
            #pragma unroll
            for (int off = 1; off <= 32; off <<= 1) jwin = min(jwin, __shfl_xor(jwin, off));
        }
        if (lane == s) { keepd = m; keepj = jwin; }
        if (lane == (jwin & 63)) {
            used |= 1u << s1;
            l1 = l2; s1 = s2;
            l2 = l3; s2 = s3;
            l3 = l4; s3 = s4;
            l4 = INFV;
            if (l1 >= INFV) {   // rare refill (4th win of this lane)
                l1 = INFV; l2 = INFV; l3 = INFV; l4 = INFV;
                #pragma unroll
                for (int i = 0; i < 32; i++) {
                    float v = ((used >> i) & 1u) ? INFV : Dv[i];
                    bool lt1 = v < l1, lt2 = v < l2, lt3 = v < l3, lt4 = v < l4;
                    float o1 = l1, o2 = l2, o3 = l3;
                    int os1 = s1, os2 = s2, os3 = s3;
                    l1 = lt1 ? v : l1;                    s1 = lt1 ? i : s1;
                    l2 = lt1 ? o1 : (lt2 ? v : l2);       s2 = lt1 ? os1 : (lt2 ? i : s2);
                    l3 = lt2 ? o2 : (lt3 ? v : l3);       s3 = lt2 ? os2 : (lt3 ? i : s3);
                    l4 = lt3 ? o3 : (lt4 ? v : l4);       s4 = lt3 ? os3 : (lt4 ? i : s4);
                }
            }
        }
    }
    if (lane < KK) {
        E_idx[(size_t)g * KK + lane] = keepj;
        D_nb[(size_t)g * KK + lane] = keepd;
    }
}

__device__ __forceinline__ void packB(const float* __restrict__ src, short* __restrict__ dH,
                                      short* __restrict__ dL, int e, int KC, int N, int Kreal) {
    int j = e & 7, ln = (e >> 3) & 63, t = e >> 9;
    int kc = t % KC, nt = t / KC;
    int k = kc * 32 + (ln >> 4) * 8 + j;
    int n = nt * 16 + (ln & 15);
    float v = (k < Kreal) ? src[(size_t)k * N + n] : 0.f;
    short hi, lo; f2bf2(v, hi, lo);
    dH[e] = hi; dL[e] = lo;
}

__device__ void pack_body(int e,
                          const float* __restrict__ We, const float* __restrict__ Wq,
                          const float* __restrict__ lW1, const float* __restrict__ lW2,
                          const float* __restrict__ lW3, const float* __restrict__ lWi,
                          const float* __restrict__ lWo, const float* __restrict__ Wv,
                          short* __restrict__ WeP, short* __restrict__ WqP,
                          short* __restrict__ W1bP, short* __restrict__ W2P,
                          short* __restrict__ W3P, short* __restrict__ WiP,
                          short* __restrict__ WoP, short* __restrict__ W1acP,
                          short* __restrict__ WvP) {
    if (e < 8192) { packB(We, WeP, WeP + 8192, e, 2, 128, 39); return; }
    e -= 8192;
    if (e < 16384) { packB(Wq, WqP, WqP + 16384, e, 4, 128, 128); return; }
    e -= 16384;
    if (e < 49152) {
        int l = e >> 14, r = e & 16383;
        packB(lW1 + (size_t)l * 49152 + 16384, W1bP + l * 32768, W1bP + l * 32768 + 16384, r, 4, 128, 128);
        return;
    }
    e -= 49152;
    if (e < 49152) {
        int l = e >> 14, r = e & 16383;
        packB(lW2 + (size_t)l * 16384, W2P + l * 32768, W2P + l * 32768 + 16384, r, 4, 128, 128);
        return;
    }
    e -= 49152;
    if (e < 49152) {
        int l = e >> 14, r = e & 16383;
        packB(lW3 + (size_t)l * 16384, W3P + l * 32768, W3P + l * 32768 + 16384, r, 4, 128, 128);
        return;
    }
    e -= 49152;
    if (e < 196608) {
        int l = e / 65536, r = e % 65536;
        packB(lWi + (size_t)l * 65536, WiP + l * 131072, WiP + l * 131072 + 65536, r, 4, 512, 128);
        return;
    }
    e -= 196608;
    if (e < 196608) {
        int l = e / 65536, r = e % 65536;
        packB(lWo + (size_t)l * 65536, WoP + l * 131072, WoP + l * 131072 + 65536, r, 16, 128, 512);
        return;
    }
    e -= 196608;
    if (e < 98304) {
        int l = e / 32768, r = e % 32768;
        int j = r & 7, ln = (r >> 3) & 63, t = r >> 9;
        int kc = t & 3, nt = t >> 2;
        int k = kc * 32 + (ln >> 4) * 8 + j;
        int n = nt * 16 + (ln & 15);
        const float* base = lW1 + (size_t)l * 49152;
        float v = (n < 128) ? base[(size_t)k * 128 + n] : base[(size_t)(256 + k) * 128 + (n - 128)];
        short hi, lo; f2bf2(v, hi, lo);
        short* dH = W1acP + l * 65536;
        dH[r] = hi; dH[32768 + r] = lo;
        return;
    }
    e -= 98304;
    // Wv pack (16384 elements)
    packB(Wv, WvP, WvP + 16384, e, 4, 128, 128);
}

__device__ void orient_body(int t, const float* __restrict__ X,
                            float* __restrict__ AD, float* __restrict__ Of) {
    if (t >= BB * NN) return;
    int b = t / NN, n = t % NN;
    float* ad = AD + (size_t)t * 3;
    float* of = Of + (size_t)t * 9;
    if (n < 1 || n > NN - 3) {
        ad[0] = ad[1] = ad[2] = 0.f;
        #pragma unroll
        for (int i = 0; i < 9; i++) of[i] = 0.f;
        return;
    }
    const float* Xb = X + (size_t)b * NN * 3;
    float p0x = Xb[(n - 1) * 3], p0y = Xb[(n - 1) * 3 + 1], p0z = Xb[(n - 1) * 3 + 2];
    float p1x = Xb[n * 3],       p1y = Xb[n * 3 + 1],       p1z = Xb[n * 3 + 2];
    float p2x = Xb[(n + 1) * 3], p2y = Xb[(n + 1) * 3 + 1], p2z = Xb[(n + 1) * 3 + 2];
    float p3x = Xb[(n + 2) * 3], p3y = Xb[(n + 2) * 3 + 1], p3z = Xb[(n + 2) * 3 + 2];

    float u2x = p1x - p0x, u2y = p1y - p0y, u2z = p1z - p0z; norm3(u2x, u2y, u2z);
    float u1x = p2x - p1x, u1y = p2y - p1y, u1z = p2z - p1z; norm3(u1x, u1y, u1z);
    float u0x = p3x - p2x, u0y = p3y - p2y, u0z = p3z - p2z; norm3(u0x, u0y, u0z);

    float n2x = u2y * u1z - u2z * u1y, n2y = u2z * u1x - u2x * u1z, n2z = u2x * u1y - u2y * u1x;
    norm3(n2x, n2y, n2z);
    float n1x = u1y * u0z - u1z * u0y, n1y = u1z * u0x - u1x * u0z, n1z = u1x * u0y - u1y * u0x;
    norm3(n1x, n1y, n1z);

    float cosA = -(u1x * u0x + u1y * u0y + u1z * u0z);
    cosA = fminf(fmaxf(cosA, -1.f + EPSF), 1.f - EPSF);
    float A = acosf(cosA);
    float cosD = n2x * n1x + n2y * n1y + n2z * n1z;
    cosD = fminf(fmaxf(cosD, -1.f + EPSF), 1.f - EPSF);
    float sg = sgnf(u2x * n1x + u2y * n1y + u2z * n1z);
    float Dih = sg * acosf(cosD);

    ad[0] = cosf(A);
    ad[1] = sinf(A) * cosf(Dih);
    ad[2] = sinf(A) * sinf(Dih);

    float o1x = u2x - u1x, o1y = u2y - u1y, o1z = u2z - u1z; norm3(o1x, o1y, o1z);
    float cx = o1y * n2z - o1z * n2y, cy = o1z * n2x - o1x * n2z, cz = o1x * n2y - o1y * n2x;
    of[0] = o1x; of[1] = o1y; of[2] = o1z;
    of[3] = n2x; of[4] = n2y; of[5] = n2z;
    of[6] = cx;  of[7] = cy;  of[8] = cz;
}

// ---------- FRONT: knn (blocks 0..1023) | pack (1024..3679) | orient (3680..3695) ----------

__global__ __launch_bounds__(256) void front_kernel(const float* __restrict__ X,
                                                    const float* __restrict__ mask,
                                                    int* __restrict__ E_idx,
                                                    float* __restrict__ D_nb,
                                                    const float* __restrict__ We,
                                                    const float* __restrict__ Wq,
                                                    const float* __restrict__ lW1,
                                                    const float* __restrict__ lW2,
                                                    const float* __restrict__ lW3,
                                                    const float* __restrict__ lWi,
                                                    const float* __restrict__ lWo,
                                                    const float* __restrict__ Wv,
                                                    short* __restrict__ WeP,
                                                    short* __restrict__ WqP,
                                                    short* __restrict__ W1bP,
                                                    short* __restrict__ W2P,
                                                    short* __restrict__ W3P,
                                                    short* __restrict__ WiP,
                                                    short* __restrict__ WoP,
                                                    short* __restrict__ W1acP,
                                                    short* __restrict__ WvP,
                                                    float* __restrict__ ADb,
                                                    float* __restrict__ Ofb) {
    int blk = blockIdx.x;
    if (blk < KNN_BLK) {
        knn_body(blk, X, mask, E_idx, D_nb);
    } else if (blk < KNN_BLK + PACK_BLK) {
        pack_body((blk - KNN_BLK) * 256 + threadIdx.x,
                  We, Wq, lW1, lW2, lW3, lWi, lWo, Wv,
                  WeP, WqP, W1bP, W2P, W3P, WiP, WoP, W1acP, WvP);
    } else {
        orient_body((blk - KNN_BLK - PACK_BLK) * 256 + threadIdx.x, X, ADb, Ofb);
    }
}

// ---------- MID: edge_feat (blocks 0..4095) | node_feat16 (4096..4351) ----------
// edge_feat: waves split over OUTPUT col-tiles (nt); hEbH output staged through
// LDS (AeH reuse) for coalesced short8 stores instead of 32 scalar 2B stores.

__global__ __launch_bounds__(128) void mid_kernel(const float* __restrict__ X,
                                                  const int* __restrict__ E_idx,
                                                  const float* __restrict__ D_nb,
                                                  const float* __restrict__ Of,
                                                  const float* __restrict__ be,
                                                  const float* __restrict__ ge,
                                                  const float* __restrict__ he,
                                                  const float* __restrict__ bq,
                                                  const short* __restrict__ WeP,
                                                  const short* __restrict__ WqP,
                                                  unsigned short* __restrict__ hEbH,
                                                  const float* __restrict__ AD,
                                                  const float* __restrict__ Wn,
                                                  const float* __restrict__ bn,
                                                  const float* __restrict__ gn,
                                                  const float* __restrict__ hn,
                                                  const short* __restrict__ WvP,
                                                  const float* __restrict__ bv,
                                                  const short* __restrict__ W1acP0,
                                                  const float* __restrict__ b1_0,
                                                  float* __restrict__ hV,
                                                  float* __restrict__ P,
                                                  float* __restrict__ Q) {
    __shared__ __align__(16) char smemRaw[15872];

    if (blockIdx.x < (unsigned)(BB * NN)) {
        // ----- edge_feat body -----
        short* AefH = (short*)smemRaw;                 // 32*72*2   = 4608 B
        short* AeH  = (short*)(smemRaw + 4608);        // 32*136*2  = 8704 B
        float* beS  = (float*)(smemRaw + 13312);       // 512 B
        float* geS  = beS + HH;
        float* heS  = geS + HH;
        float* bqS  = heS + HH;
        float* redSe = (float*)(smemRaw + 15360);      // [2][2][32] = 512 B

        int bid = blockIdx.x; int b = bid >> 11, n = bid & 2047; int tid = threadIdx.x;
        int lane = tid & 63, w = tid >> 6;
        beS[tid] = be[tid]; geS[tid] = ge[tid]; heS[tid] = he[tid]; bqS[tid] = bq[tid];
        {
            unsigned* Az = (unsigned*)AefH;
            for (int i = tid; i < 32 * 72 / 2; i += 128) Az[i] = 0u;
        }
        __syncthreads();

        int part = tid >> 5, k = tid & 31;
        int e = E_idx[(size_t)bid * KK + k];
        float dpos = (float)e - (float)n;
        if (part == 1 || part == 2) {
            int p0 = (part - 1) * 4;
            #pragma unroll
            for (int p = 0; p < 4; p++) {
                // freq = 10000^(-(p0+p)/8) = 10^(-(p0+p)/2) — compile-time constants
                float fr = (part == 1)
                    ? ((p == 0) ? 1.f : (p == 1) ? 0.31622776601683794f
                       : (p == 2) ? 0.1f : 0.031622776601683791f)
                    : ((p == 0) ? 0.01f : (p == 1) ? 0.0031622776601683794f
                       : (p == 2) ? 0.001f : 0.00031622776601683794f);
                float ang = dpos * fr;
                AefH[k * 72 + p0 + p]     = (short)f2bf(__cosf(ang));
                AefH[k * 72 + 8 + p0 + p] = (short)f2bf(__sinf(ang));
            }
        } else if (part == 3) {
            float Dv = D_nb[(size_t)bid * KK + k];
            #pragma unroll
            for (int i = 0; i < 16; i++) {
                float m = (20.f / 15.f) * (float)i;
                float z = (Dv - m) * 0.8f;
                AefH[k * 72 + 16 + i] = (short)f2bf(__expf(-z * z));
            }
        } else {
            const float* Omp = Of + (size_t)(b * NN + n) * 9;
            const float* Onp = Of + (size_t)(b * NN + e) * 9;
            float Om[9], On[9];
            #pragma unroll
            for (int i = 0; i < 9; i++) { Om[i] = Omp[i]; On[i] = Onp[i]; }
            float vx = X[(size_t)(b * NN + e) * 3 + 0] - X[(size_t)(b * NN + n) * 3 + 0];
            float vy = X[(size_t)(b * NN + e) * 3 + 1] - X[(size_t)(b * NN + n) * 3 + 1];
            float vz = X[(size_t)(b * NN + e) * 3 + 2] - X[(size_t)(b * NN + n) * 3 + 2];
            float t0 = Om[0] * vx + Om[1] * vy + Om[2] * vz;
            float t1 = Om[3] * vx + Om[4] * vy + Om[5] * vz;
            float t2 = Om[6] * vx + Om[7] * vy + Om[8] * vz;
            float nr = fmaxf(sqrtf(t0 * t0 + t1 * t1 + t2 * t2), 1e-12f);
            AefH[k * 72 + 32] = (short)f2bf(t0 / nr);
            AefH[k * 72 + 33] = (short)f2bf(t1 / nr);
            AefH[k * 72 + 34] = (short)f2bf(t2 / nr);
            float R[9];
            #pragma unroll
            for (int i = 0; i < 3; i++)
                #pragma unroll
                for (int l = 0; l < 3; l++)
                    R[i * 3 + l] = Om[0 + i] * On[0 + l] + Om[3 + i] * On[3 + l] + Om[6 + i] * On[6 + l];
            float Rxx = R[0], Ryy = R[4], Rzz = R[8];
            float mx = 0.5f * sqrtf(fabsf(1.f + Rxx - Ryy - Rzz));
            float my = 0.5f * sqrtf(fabsf(1.f - Rxx + Ryy - Rzz));
            float mz = 0.5f * sqrtf(fabsf(1.f - Rxx - Ryy + Rzz));
            float qx = sgnf(R[7] - R[5]) * mx;
            float qy = sgnf(R[2] - R[6]) * my;
            float qz = sgnf(R[3] - R[1]) * mz;
            float qw = 0.5f * sqrtf(fmaxf(1.f + Rxx + Ryy + Rzz, 0.f));
            float qn = fmaxf(sqrtf(qx * qx + qy * qy + qz * qz + qw * qw), 1e-12f);
            AefH[k * 72 + 35] = (short)f2bf(qx / qn);
            AefH[k * 72 + 36] = (short)f2bf(qy / qn);
            AefH[k * 72 + 37] = (short)f2bf(qz / qn);
            AefH[k * 72 + 38] = (short)f2bf(qw / qn);
        }
        __syncthreads();

        int m = lane & 15, q = lane >> 4;
        // A-frags: both row-tiles (t), this wave covers all 32 edges
        short8 aW[2][2];
        #pragma unroll
        for (int t = 0; t < 2; t++) {
            int row = (t * 16 + m) * 72;
            aW[t][0] = *(const short8*)&AefH[row + q * 8];
            aW[t][1] = *(const short8*)&AefH[row + 32 + q * 8];
        }
        f32x4 accA[4][2];   // [nt4][t]
        #pragma unroll
        for (int nt4 = 0; nt4 < 4; nt4++) {
            int ntg = w * 4 + nt4;
            const short* B0 = &WeP[((ntg * 2 + 0) * 64 + lane) * 8];
            const short* B1 = &WeP[((ntg * 2 + 1) * 64 + lane) * 8];
            short8 b0h = *(const short8*)B0, b0l = *(const short8*)(B0 + 8192);
            short8 b1h = *(const short8*)B1, b1l = *(const short8*)(B1 + 8192);
            float bc = beS[ntg * 16 + m];
            #pragma unroll
            for (int t = 0; t < 2; t++) {
                f32x4 acc = {bc, bc, bc, bc};
                acc = MFMA16(aW[t][0], b0h, acc);
                acc = MFMA16(aW[t][0], b0l, acc);
                acc = MFMA16(aW[t][1], b1h, acc);
                acc = MFMA16(aW[t][1], b1l, acc);
                accA[nt4][t] = acc;
            }
        }
        // cross-wave LN: partial su/sq per row over this wave's 64 cols
        #pragma unroll
        for (int t = 0; t < 2; t++)
            #pragma unroll
            for (int r = 0; r < 4; r++) {
                float su = accA[0][t][r] + accA[1][t][r] + accA[2][t][r] + accA[3][t][r];
                float sq2 = accA[0][t][r] * accA[0][t][r] + accA[1][t][r] * accA[1][t][r]
                          + accA[2][t][r] * accA[2][t][r] + accA[3][t][r] * accA[3][t][r];
                #pragma unroll
                for (int off = 1; off <= 8; off <<= 1) {
                    su += __shfl_xor(su, off); sq2 += __shfl_xor(sq2, off);
                }
                if (m == 0) {
                    int row = t * 16 + q * 4 + r;
                    redSe[(w * 2 + 0) * 32 + row] = su;
                    redSe[(w * 2 + 1) * 32 + row] = sq2;
                }
            }
        __syncthreads();
        float muA[2][4], invA[2][4];
        #pragma unroll
        for (int t = 0; t < 2; t++)
            #pragma unroll
            for (int r = 0; r < 4; r++) {
                int row = t * 16 + q * 4 + r;
                float S  = redSe[0 * 32 + row] + redSe[2 * 32 + row];
                float Q2 = redSe[1 * 32 + row] + redSe[3 * 32 + row];
                float mu = S * (1.f / HH);
                float var = (Q2 - (float)HH * mu * mu) * (1.f / (HH - 1));
                muA[t][r] = mu;
                invA[t][r] = 1.f / (sqrtf(var + EPSF) + EPSF);
            }
        #pragma unroll
        for (int nt4 = 0; nt4 < 4; nt4++) {
            int col = (w * 4 + nt4) * 16 + m;
            float g = geS[col], hh = heS[col];
            #pragma unroll
            for (int t = 0; t < 2; t++)
                #pragma unroll
                for (int r = 0; r < 4; r++) {
                    int edge = t * 16 + q * 4 + r;
                    float y = g * (accA[nt4][t][r] - muA[t][r]) * invA[t][r] + hh;
                    AeH[edge * 136 + col] = (short)f2bf(y);
                }
        }
        __syncthreads();

        short8 ah[2][4];
        #pragma unroll
        for (int t = 0; t < 2; t++)
            #pragma unroll
            for (int kc = 0; kc < 4; kc++)
                ah[t][kc] = *(const short8*)&AeH[(t * 16 + m) * 136 + kc * 32 + q * 8];
        __syncthreads();   // all A-frag preloads done — AeH becomes output staging

        #pragma unroll
        for (int nt4 = 0; nt4 < 4; nt4++) {
            int ntg = w * 4 + nt4;
            int col = ntg * 16 + m;
            short8 qh[4], ql[4];
            #pragma unroll
            for (int kc = 0; kc < 4; kc++) {
                const short* Bp = &WqP[((ntg * 4 + kc) * 64 + lane) * 8];
                qh[kc] = *(const short8*)Bp;
                ql[kc] = *(const short8*)(Bp + 16384);
            }
            float bc = bqS[col];
            #pragma unroll
            for (int t = 0; t < 2; t++) {
                f32x4 acc = {bc, bc, bc, bc};
                #pragma unroll
                for (int kc = 0; kc < 4; kc++) {
                    acc = MFMA16(ah[t][kc], qh[kc], acc);
                    acc = MFMA16(ah[t][kc], ql[kc], acc);
                }
                #pragma unroll
                for (int r = 0; r < 4; r++) {
                    int edge = t * 16 + q * 4 + r;
                    AeH[edge * 136 + col] = (short)f2bf(acc[r]);
                }
            }
        }
        __syncthreads();

        // coalesced copy-out: 512 short8 chunks, 4 per thread (256B contiguous/row)
        {
            unsigned short* outp = hEbH + (size_t)bid * (KK * HH);
            #pragma unroll
            for (int it = 0; it < 4; it++) {
                int idx = it * 128 + tid;       // 0..511
                int row = idx >> 4, c8 = idx & 15;
                *(short8*)(outp + row * HH + c8 * 8) = *(const short8*)&AeH[row * 136 + c8 * 8];
            }
        }
    } else {
        // ----- node_feat body: 16 nodes per block, MFMA path -----
        short* yH  = (short*)smemRaw;                  // 16*136*2 = 4352 B
        short* hvH = (short*)(smemRaw + 4352);         // 4352 B

        int nb = blockIdx.x - BB * NN;
        int g0 = nb * 16;
        int tid = threadIdx.x;
        int lane = tid & 63, w = tid >> 6;
        int m = lane & 15, q = lane >> 4;

        // step 1: V = AD @ Wn + bn, per-node LN -> y (bf16 in LDS)
        {
            int i = tid >> 3;          // node 0..15
            int j = tid & 7;           // column group (16 cols each)
            int h0 = j * 16;
            const float* ad = AD + (size_t)(g0 + i) * 3;
            float a0 = ad[0], a1 = ad[1], a2 = ad[2];
            float v[16];
            float su = 0.f, sq = 0.f;
            #pragma unroll
            for (int c = 0; c < 16; c++) {
                int h = h0 + c;
                float t = bn[h] + a0 * Wn[h] + a1 * Wn[HH + h] + a2 * Wn[2 * HH + h];
                v[c] = t; su += t; sq += t * t;
            }
            #pragma unroll
            for (int off = 1; off <= 4; off <<= 1) {
                su += __shfl_xor(su, off); sq += __shfl_xor(sq, off);
            }
            float mu = su * (1.f / HH);
            float var = (sq - (float)HH * mu * mu) * (1.f / (HH - 1));
            float inv = 1.f / (sqrtf(var + EPSF) + EPSF);
            #pragma unroll
            for (int c = 0; c < 16; c++) {
                int h = h0 + c;
                yH[i * 136 + h] = (short)f2bf(gn[h] * (v[c] - mu) * inv + hn[h]);
            }
        }
        __syncthreads();

        // step 2: hV = y @ Wv + bv  (wave handles 4 of 8 col-tiles)
        short8 ayh[4];
        #pragma unroll
        for (int kc = 0; kc < 4; kc++)
            ayh[kc] = *(const short8*)&yH[m * 136 + kc * 32 + q * 8];
        #pragma unroll
        for (int u = 0; u < 4; u++) {
            int nt = w * 4 + u;
            int col = nt * 16 + m;
            float bc = bv[col];
            f32x4 a = {bc, bc, bc, bc};
            #pragma unroll
            for (int kc = 0; kc < 4; kc++) {
                const short* Bp = &WvP[((nt * 4 + kc) * 64 + lane) * 8];
                short8 bh = *(const short8*)Bp, bl = *(const short8*)(Bp + 16384);
                a = MFMA16(ayh[kc], bh, a);
                a = MFMA16(ayh[kc], bl, a);
            }
            #pragma unroll
            for (int r = 0; r < 4; r++) {
                int rw = q * 4 + r;
                hV[(size_t)(g0 + rw) * HH + col] = a[r];
                hvH[rw * 136 + col] = (short)f2bf(a[r]);
            }
        }
        __syncthreads();

        // step 3: layer-0 premix P/Q = hV @ W1_0[a|c] (+b1 for P), via packed W1acP[0]
        short8 avh[4];
        #pragma unroll
        for (int kc = 0; kc < 4; kc++)
            avh[kc] = *(const short8*)&hvH[m * 136 + kc * 32 + q * 8];
        #pragma unroll
        for (int u = 0; u < 8; u++) {
            int nt = w * 8 + u;
            int col = nt * 16 + m;
            float b0 = (nt < 8) ? b1_0[col] : 0.f;
            f32x4 a = {b0, b0, b0, b0};
            #pragma unroll
            for (int kc = 0; kc < 4; kc++) {
                const short* Bp = &W1acP0[((nt * 4 + kc) * 64 + lane) * 8];
                short8 bh = *(const short8*)Bp, bl = *(const short8*)(Bp + 32768);
                a = MFMA16(avh[kc], bh, a);
                a = MFMA16(avh[kc], bl, a);
            }
            #pragma unroll
            for (int r = 0; r < 4; r++) {
                size_t rw = g0 + q * 4 + r;
                if (nt < 8) P[rw * HH + col] = a[r];
                else        Q[rw * HH + (col - 128)] = a[r];
            }
        }
    }
}

// ---------- message kernel: block = 2 nodes, 4 waves, 2 nt-tiles per wave ----------
// (r7 form) A-side staged in LDS; weights loaded once per nt-tile per wave and
// reused for both nodes. Q gathers hoisted to registers before the staging
// barrier so their latency overlaps the LDS staging drain.

__global__ __launch_bounds__(256) void msg_kernel(const float* __restrict__ mask,
                                                  const int* __restrict__ E_idx,
                                                  const unsigned short* __restrict__ hEbH,
                                                  const float* __restrict__ P,
                                                  const float* __restrict__ Q,
                                                  const short* __restrict__ W1bP,
                                                  const short* __restrict__ W2P,
                                                  const float* __restrict__ b2,
                                                  float* __restrict__ sOut,
                                                  float* __restrict__ cntOut) {
    __shared__ short stg[2][32 * 136];   // staged h_E (bf16) per node
    __shared__ short AmH[2][32 * 136];   // m1 (bf16) per node

    int tid = threadIdx.x;
    int w = tid >> 6, lane = tid & 63;
    int gA = blockIdx.x * 2;             // nodes gA, gA+1 (same batch: NN even)
    int b = gA >> 11;
    int m = lane & 15, q = lane >> 4;

    // ---- stage hEbH for both nodes (fully coalesced short8 loads) ----
    {
        const short8* src = (const short8*)(hEbH + (size_t)gA * (KK * HH));
        #pragma unroll
        for (int it = 0; it < 4; it++) {
            int idx = it * 256 + tid;        // 0..1023 short8 chunks
            int nd = idx >> 9;
            int rem = idx & 511;
            int e = rem >> 4;                // edge
            int c8 = rem & 15;               // col/8
            short8 v = src[idx];
            *(short8*)&stg[nd][e * 136 + c8 * 8] = v;
        }
    }

    int qbase[2][2][4]; float mt[2][2][4];
    #pragma unroll
    for (int nd = 0; nd < 2; nd++) {
        float maskv = mask[gA + nd];
        #pragma unroll
        for (int t = 0; t < 2; t++)
            #pragma unroll
            for (int r = 0; r < 4; r++) {
                int row = t * 16 + q * 4 + r;
                int e = E_idx[(size_t)(gA + nd) * KK + row];
                qbase[nd][t][r] = (b * NN + e) * HH;
                mt[nd][t][r] = maskv * mask[b * NN + e];
            }
    }
    if (w < 2) {
        // wave w (0,1) produces cnt for node w
        float c8 = mt[w][0][0] + mt[w][0][1] + mt[w][0][2] + mt[w][0][3]
                 + mt[w][1][0] + mt[w][1][1] + mt[w][1][2] + mt[w][1][3];
        c8 += __shfl_xor(c8, 16);
        c8 += __shfl_xor(c8, 32);
        if (lane == 0) cntOut[gA + w] = c8;
    }

    float preg[2][2], b2reg[2];
    #pragma unroll
    for (int u = 0; u < 2; u++) {
        int colg = (w * 2 + u) * 16 + m;
        b2reg[u] = b2[colg];
        preg[0][u] = P[(size_t)gA * HH + colg];
        preg[1][u] = P[(size_t)(gA + 1) * HH + colg];
    }

    // prefetch all Q gathers (32 scattered loads) — overlap with staging barrier
    float qv[2][2][2][4];   // [u][nd][t][r]
    #pragma unroll
    for (int u = 0; u < 2; u++) {
        int colg = (w * 2 + u) * 16 + m;
        #pragma unroll
        for (int nd = 0; nd < 2; nd++)
            #pragma unroll
            for (int t = 0; t < 2; t++)
                #pragma unroll
                for (int r = 0; r < 4; r++)
                    qv[u][nd][t][r] = Q[(size_t)qbase[nd][t][r] + colg];
    }
    __syncthreads();

    // phase 1: m1 = relu(P + Q[nbr] + h_E @ W1b) — wave handles 2 nt tiles, both nodes
    #pragma unroll
    for (int u = 0; u < 2; u++) {
        int ntg = w * 2 + u;
        int colg = ntg * 16 + m;
        short8 bh[4], bl[4];
        #pragma unroll
        for (int kc = 0; kc < 4; kc++) {
            const short* Bp = &W1bP[((ntg * 4 + kc) * 64 + lane) * 8];
            bh[kc] = *(const short8*)Bp;
            bl[kc] = *(const short8*)(Bp + 16384);
        }
        #pragma unroll
        for (int nd = 0; nd < 2; nd++) {
            f32x4 t0 = {0.f, 0.f, 0.f, 0.f}, t1 = {0.f, 0.f, 0.f, 0.f};
            #pragma unroll
            for (int kc = 0; kc < 4; kc++) {
                short8 a0 = *(const short8*)&stg[nd][(0 * 16 + m) * 136 + kc * 32 + q * 8];
                short8 a1 = *(const short8*)&stg[nd][(1 * 16 + m) * 136 + kc * 32 + q * 8];
                t0 = MFMA16(a0, bh[kc], t0);
                t0 = MFMA16(a0, bl[kc], t0);
                t1 = MFMA16(a1, bh[kc], t1);
                t1 = MFMA16(a1, bl[kc], t1);
            }
            float pp = preg[nd][u];
            #pragma unroll
            for (int r = 0; r < 4; r++) {
                float v0 = fmaxf(t0[r] + pp + qv[u][nd][0][r], 0.f);
                AmH[nd][(q * 4 + r) * 136 + colg] = (short)f2bf(v0);
                float v1 = fmaxf(t1[r] + pp + qv[u][nd][1][r], 0.f);
                AmH[nd][(16 + q * 4 + r) * 136 + colg] = (short)f2bf(v1);
            }
        }
    }
    __syncthreads();

    // phase 2: m2 = relu(m1 @ W2 + b2); masked sum over 32 edges
    #pragma unroll
    for (int u = 0; u < 2; u++) {
        int ntg = w * 2 + u;
        short8 bh[4], bl[4];
        #pragma unroll
        for (int kc = 0; kc < 4; kc++) {
            const short* Bp = &W2P[((ntg * 4 + kc) * 64 + lane) * 8];
            bh[kc] = *(const short8*)Bp;
            bl[kc] = *(const short8*)(Bp + 16384);
        }
        float bc = b2reg[u];
        #pragma unroll
        for (int nd = 0; nd < 2; nd++) {
            f32x4 a0 = {bc, bc, bc, bc}, a1 = {bc, bc, bc, bc};
            #pragma unroll
            for (int kc = 0; kc < 4; kc++) {
                short8 m0 = *(const short8*)&AmH[nd][(0 * 16 + m) * 136 + kc * 32 + q * 8];
                short8 m1 = *(const short8*)&AmH[nd][(1 * 16 + m) * 136 + kc * 32 + q * 8];
                a0 = MFMA16(m0, bh[kc], a0);
                a0 = MFMA16(m0, bl[kc], a0);
                a1 = MFMA16(m1, bh[kc], a1);
                a1 = MFMA16(m1, bl[kc], a1);
            }
            float part = 0.f;
            #pragma unroll
            for (int r = 0; r < 4; r++)
                part += fmaxf(a0[r], 0.f) * mt[nd][0][r] + fmaxf(a1[r], 0.f) * mt[nd][1][r];
            part += __shfl_xor(part, 16);
            part += __shfl_xor(part, 32);
            if (q == 0) sOut[(size_t)(gA + nd) * HH + ntg * 16 + m] = part;
        }
    }
}

// ---------- node kernel: 8 waves (512 threads), 16 nodes/block ----------

#define HSTR 520   // LDS stride (shorts) for 512-wide hidden staging

__global__ __launch_bounds__(512, 2) void node_kernel(const float* __restrict__ mask,
                                                      const float* __restrict__ sbuf,
                                                      const float* __restrict__ cntb,
                                                      const float* __restrict__ hVin,
                                                      const short* __restrict__ W3P,
                                                      const float* __restrict__ b3,
                                                      const short* __restrict__ WiP,
                                                      const float* __restrict__ biN,
                                                      const short* __restrict__ WoP,
                                                      const float* __restrict__ boN,
                                                      const float* __restrict__ g0,
                                                      const float* __restrict__ h0,
                                                      const float* __restrict__ g1,
                                                      const float* __restrict__ h1,
                                                      const short* __restrict__ W1P,
                                                      const float* __restrict__ b1n,
                                                      float* __restrict__ hVout,
                                                      float* __restrict__ Pn,
                                                      float* __restrict__ Qn) {
    __shared__ short rbH[16 * 136];
    __shared__ short hbH[16 * HSTR];
    __shared__ float redS[8][2][16];
    __shared__ float g0S[128], h0S[128], g1S[128], h1S[128], b3S[128], boS[128], b1S[128];
    __shared__ float biS[512];

    int tid = threadIdx.x;
    int w = tid >> 6, lane = tid & 63;
    int m = lane & 15, q = lane >> 4;
    int rowT = blockIdx.x * 16;

    if (tid < 128) {
        int i = tid;
        g0S[i] = g0[i]; h0S[i] = h0[i]; g1S[i] = g1[i]; h1S[i] = h1[i];
        b3S[i] = b3[i]; boS[i] = boN[i]; b1S[i] = W1P ? b1n[i] : 0.f;
    }
    biS[tid] = biN[tid];
    __syncthreads();

    short8 ash[4];
    #pragma unroll
    for (int kc = 0; kc < 4; kc++) {
        const float* sp = &sbuf[(size_t)(rowT + m) * HH + kc * 32 + q * 8];
        f32x4 x0 = *(const f32x4*)sp;
        f32x4 x1 = *(const f32x4*)(sp + 4);
        ash[kc] = cvt8h(x0, x1);
    }
    float cntr[4];
    #pragma unroll
    for (int r = 0; r < 4; r++) cntr[r] = cntb[rowT + q * 4 + r];

    // W3: wave w owns col-tile w
    f32x4 vC;
    {
        f32x4 a = {0.f, 0.f, 0.f, 0.f};
        #pragma unroll
        for (int kc = 0; kc < 4; kc++) {
            const short* Bp = &W3P[((w * 4 + kc) * 64 + lane) * 8];
            short8 bh = *(const short8*)Bp, bl = *(const short8*)(Bp + 16384);
            a = MFMA16(ash[kc], bh, a);
            a = MFMA16(ash[kc], bl, a);
        }
        int col = w * 16 + m;
        #pragma unroll
        for (int r = 0; r < 4; r++) {
            float tv = (a[r] + cntr[r] * b3S[col]) * (1.f / 30.f);
            a[r] = hVin[(size_t)(rowT + q * 4 + r) * HH + col] + tv;
        }
        vC = a;
    }

    // LN0 (cross-8-wave)
    {
        float su[4], sq[4];
        #pragma unroll
        for (int r = 0; r < 4; r++) { float v = vC[r]; su[r] = v; sq[r] = v * v; }
        #pragma unroll
        for (int off = 1; off <= 8; off <<= 1)
            #pragma unroll
            for (int r = 0; r < 4; r++) { su[r] += __shfl_xor(su[r], off); sq[r] += __shfl_xor(sq[r], off); }
        if (m == 0) {
            #pragma unroll
            for (int r = 0; r < 4; r++) { redS[w][0][q * 4 + r] = su[r]; redS[w][1][q * 4 + r] = sq[r]; }
        }
    }
    __syncthreads();
    float mu[4], inv[4];
    #pragma unroll
    for (int r = 0; r < 4; r++) {
        int row = q * 4 + r;
        float S = 0.f, Q2 = 0.f;
        #pragma unroll
        for (int ww = 0; ww < 8; ww++) { S += redS[ww][0][row]; Q2 += redS[ww][1][row]; }
        mu[r] = S * (1.f / HH);
        float var = (Q2 - (float)HH * mu[r] * mu[r]) * (1.f / (HH - 1));
        inv[r] = 1.f / (sqrtf(var + EPSF) + EPSF);
    }
    {
        int col = w * 16 + m;
        #pragma unroll
        for (int r = 0; r < 4; r++) {
            vC[r] = g0S[col] * (vC[r] - mu[r]) * inv[r] + h0S[col];
            rbH[(q * 4 + r) * 136 + col] = (short)f2bf(vC[r]);
        }
    }
    __syncthreads();

    short8 avh[4];
    #pragma unroll
    for (int kc = 0; kc < 4; kc++)
        avh[kc] = *(const short8*)&rbH[m * 136 + kc * 32 + q * 8];

    // FFN-in: wave's 64 hidden cols (4 of 32 tiles)
    #pragma unroll
    for (int u = 0; u < 4; u++) {
        int nt = w * 4 + u;
        int jcol = nt * 16 + m;
        float bb = biS[jcol];
        f32x4 a = {bb, bb, bb, bb};
        #pragma unroll
        for (int kc = 0; kc < 4; kc++) {
            const short* Bp = &WiP[((nt * 4 + kc) * 64 + lane) * 8];
            short8 bh = *(const short8*)Bp, bl = *(const short8*)(Bp + 65536);
            a = MFMA16(avh[kc], bh, a);
            a = MFMA16(avh[kc], bl, a);
        }
        #pragma unroll
        for (int r = 0; r < 4; r++)
            hbH[(q * 4 + r) * HSTR + jcol] = (short)f2bf(fmaxf(a[r], 0.f));
    }
    __syncthreads();

    // FFN-out: wave's col-tile w over ALL 512 hidden
    f32x4 oC = {0.f, 0.f, 0.f, 0.f};
    for (int kc2 = 0; kc2 < 16; kc2++) {
        short8 ahh = *(const short8*)&hbH[m * HSTR + kc2 * 32 + q * 8];
        const short* Bp = &WoP[((w * 16 + kc2) * 64 + lane) * 8];
        short8 bh = *(const short8*)Bp, bl = *(const short8*)(Bp + 65536);
        oC = MFMA16(ahh, bh, oC);
        oC = MFMA16(ahh, bl, oC);
    }
    {
        int col = w * 16 + m;
        #pragma unroll
        for (int r = 0; r < 4; r++)
            oC[r] += boS[col] + vC[r];
    }

    // LN1 (cross-8-wave)
    {
        float su[4], sq[4];
        #pragma unroll
        for (int r = 0; r < 4; r++) { float v = oC[r]; su[r] = v; sq[r] = v * v; }
        #pragma unroll
        for (int off = 1; off <= 8; off <<= 1)
            #pragma unroll
            for (int r = 0; r < 4; r++) { su[r] += __shfl_xor(su[r], off); sq[r] += __shfl_xor(sq[r], off); }
        __syncthreads();   // redS reuse
        if (m == 0) {
            #pragma unroll
            for (int r = 0; r < 4; r++) { redS[w][0][q * 4 + r] = su[r]; redS[w][1][q * 4 + r] = sq[r]; }
        }
    }
    __syncthreads();
    #pragma unroll
    for (int r = 0; r < 4; r++) {
        int row = q * 4 + r;
        float S = 0.f, Q2 = 0.f;
        #pragma unroll
        for (int ww = 0; ww < 8; ww++) { S += redS[ww][0][row]; Q2 += redS[ww][1][row]; }
        mu[r] = S * (1.f / HH);
        float var = (Q2 - (float)HH * mu[r] * mu[r]) * (1.f / (HH - 1));
        inv[r] = 1.f / (sqrtf(var + EPSF) + EPSF);
    }
    float mk[4];
    #pragma unroll
    for (int r = 0; r < 4; r++) mk[r] = mask[rowT + q * 4 + r];
    {
        int col = w * 16 + m;
        #pragma unroll
        for (int r = 0; r < 4; r++) {
            float y = g1S[col] * (oC[r] - mu[r]) * inv[r] + h1S[col];
            y *= mk[r];
            oC[r] = y;
            hVout[(size_t)(rowT + q * 4 + r) * HH + col] = y;
        }
    }

    // fused next-layer premix (wave's 2 of 16 col-tiles)
    if (W1P) {
        __syncthreads();
        {
            int col = w * 16 + m;
            #pragma unroll
            for (int r = 0; r < 4; r++)
                rbH[(q * 4 + r) * 136 + col] = (short)f2bf(oC[r]);
        }
        __syncthreads();
        short8 ayh[4];
        #pragma unroll
        for (int kc = 0; kc < 4; kc++)
            ayh[kc] = *(const short8*)&rbH[m * 136 + kc * 32 + q * 8];
        #pragma unroll
        for (int u = 0; u < 2; u++) {
            int nt = w * 2 + u;
            int col = nt * 16 + m;
            float b0 = (nt < 8) ? b1S[col] : 0.f;
            f32x4 a = {b0, b0, b0, b0};
            #pragma unroll
            for (int kc = 0; kc < 4; kc++) {
                const short* Bp = &W1P[((nt * 4 + kc) * 64 + lane) * 8];
                short8 bh = *(const short8*)Bp, bl = *(const short8*)(Bp + 32768);
                a = MFMA16(ayh[kc], bh, a);
                a = MFMA16(ayh[kc], bl, a);
            }
            #pragma unroll
            for (int r = 0; r < 4; r++) {
                size_t row = rowT + q * 4 + r;
                if (nt < 8) Pn[row * HH + col] = a[r];
                else        Qn[row * HH + (col - 128)] = a[r];
            }
        }
    }
}

// ---------- launch ----------

extern "C" void kernel_launch(void* const* d_in, const int* in_sizes, int n_in,
                              void* d_out, int out_size, void* d_ws, size_t ws_size,
                              hipStream_t stream) {
    const float* X    = (const float*)d_in[0];
    const float* mask = (const float*)d_in[1];
    const float* Wn   = (const float*)d_in[2];
    const float* bn   = (const float*)d_in[3];
    const float* gn   = (const float*)d_in[4];
    const float* hn   = (const float*)d_in[5];
    const float* We   = (const float*)d_in[6];
    const float* be   = (const float*)d_in[7];
    const float* ge   = (const float*)d_in[8];
    const float* he   = (const float*)d_in[9];
    const float* Wv   = (const float*)d_in[10];
    const float* bv   = (const float*)d_in[11];
    const float* Wq   = (const float*)d_in[12];
    const float* bq   = (const float*)d_in[13];
    const float* lW1  = (const float*)d_in[14];
    const float* lb1  = (const float*)d_in[15];
    const float* lW2  = (const float*)d_in[16];
    const float* lb2  = (const float*)d_in[17];
    const float* lW3  = (const float*)d_in[18];
    const float* lb3  = (const float*)d_in[19];
    const float* lWi  = (const float*)d_in[20];
    const float* lbi  = (const float*)d_in[21];
    const float* lWo  = (const float*)d_in[22];
    const float* lbo  = (const float*)d_in[23];
    const float* lg0  = (const float*)d_in[24];
    const float* lh0  = (const float*)d_in[25];
    const float* lg1  = (const float*)d_in[26];
    const float* lh1  = (const float*)d_in[27];

    char* ws = (char*)d_ws;
    size_t off = 0;
    auto alloc = [&](size_t nbytes) { void* p = ws + off; off += (nbytes + 15) & ~(size_t)15; return p; };
    int*   E_idx = (int*)  alloc((size_t)BB * NN * KK * 4);
    float* D_nb  = (float*)alloc((size_t)BB * NN * KK * 4);
    float* ADb   = (float*)alloc((size_t)BB * NN * 3 * 4);
    float* Ofb   = (float*)alloc((size_t)BB * NN * 9 * 4);
    float* hV    = (float*)alloc((size_t)BB * NN * HH * 4);
    unsigned short* hEbH = (unsigned short*)alloc((size_t)BB * NN * KK * HH * 2);
    float* Pb    = (float*)alloc((size_t)BB * NN * HH * 4);
    float* Qb    = (float*)alloc((size_t)BB * NN * HH * 4);
    float* sBuf  = (float*)alloc((size_t)BB * NN * HH * 4);
    float* cntB  = (float*)alloc((size_t)BB * NN * 4);
    short* WeP   = (short*)alloc(2 * 8192 * 2);
    short* WqP   = (short*)alloc(2 * 16384 * 2);
    short* W1bP  = (short*)alloc(3 * 2 * 16384 * 2);
    short* W2P   = (short*)alloc(3 * 2 * 16384 * 2);
    short* W3P   = (short*)alloc(3 * 2 * 16384 * 2);
    short* WiP   = (short*)alloc(3 * 2 * 65536 * 2);
    short* WoP   = (short*)alloc(3 * 2 * 65536 * 2);
    short* W1acP = (short*)alloc(3 * 2 * 32768 * 2);
    short* WvP   = (short*)alloc(2 * 16384 * 2);
    if (off > ws_size) return;

    // Dispatch 1: knn | pack | orient (mutually independent)
    front_kernel<<<KNN_BLK + PACK_BLK + ORIENT_BLK, 256, 0, stream>>>(
        X, mask, E_idx, D_nb,
        We, Wq, lW1, lW2, lW3, lWi, lWo, Wv,
        WeP, WqP, W1bP, W2P, W3P, WiP, WoP, W1acP, WvP,
        ADb, Ofb);

    // Dispatch 2: edge_feat | node_feat16 (mutually independent; both need dispatch 1)
    mid_kernel<<<BB * NN + BB * NN / 16, 128, 0, stream>>>(
        X, E_idx, D_nb, Ofb, be, ge, he, bq, WeP, WqP, hEbH,
        ADb, Wn, bn, gn, hn, WvP, bv, W1acP, lb1, hV, Pb, Qb);

    for (int l = 0; l < 3; l++) {
        int last = (l == 2);
        msg_kernel<<<BB * NN / 2, 256, 0, stream>>>(
            mask, E_idx, hEbH, Pb, Qb,
            W1bP + (size_t)l * 32768,
            W2P + (size_t)l * 32768, lb2 + (size_t)l * HH,
            sBuf, cntB);
        node_kernel<<<BB * NN / 16, 512, 0, stream>>>(
            mask, sBuf, cntB, hV,
            W3P + (size_t)l * 32768, lb3 + (size_t)l * HH,
            WiP + (size_t)l * 131072, lbi + (size_t)l * DFF,
            WoP + (size_t)l * 131072, lbo + (size_t)l * HH,
            lg0 + (size_t)l * HH, lh0 + (size_t)l * HH,
            lg1 + (size_t)l * HH, lh1 + (size_t)l * HH,
            last ? nullptr : (W1acP + (size_t)(l + 1) * 65536),
            last ? nullptr : (lb1 + (size_t)(l + 1) * HH),
            last ? (float*)d_out : hV,
            Pb, Qb);
    }
}

// Round 16
// 293.503 us; speedup vs baseline: 1.0917x; 1.0142x over previous
//
#include <hip/hip_runtime.h>
#include <math.h>

typedef __attribute__((ext_vector_type(8))) short short8;
typedef __attribute__((ext_vector_type(4))) float f32x4;

#define BB 2
#define NN 2048
#define KK 32
#define HH 128
#define DFF 512
#define EPSF 1e-6f
#define INFV 1e30f

#define KNN_BLK 1024
#define PACK_BLK 2656
#define ORIENT_BLK 16

#define MFMA16(a, b, c) __builtin_amdgcn_mfma_f32_16x16x32_bf16((a), (b), (c), 0, 0, 0)

// ---------- helpers ----------

__device__ __forceinline__ unsigned short f2bf(float f) {
    unsigned u = __float_as_uint(f);
    u += 0x7fffu + ((u >> 16) & 1u);          // round-to-nearest-even
    return (unsigned short)(u >> 16);
}

__device__ __forceinline__ float bf2f(unsigned short h) {
    return __uint_as_float(((unsigned)h) << 16);
}

// split x into hi+lo bf16 pair — WEIGHTS only (systematic error must stay split)
__device__ __forceinline__ void f2bf2(float x, short& hi, short& lo) {
    unsigned short h = f2bf(x);
    hi = (short)h;
    lo = (short)f2bf(x - bf2f(h));
}

// pack 8 floats -> hi-plane short8
__device__ __forceinline__ short8 cvt8h(f32x4 a, f32x4 b) {
    short8 h8;
    #pragma unroll
    for (int i = 0; i < 4; i++) h8[i] = (short)f2bf(a[i]);
    #pragma unroll
    for (int i = 0; i < 4; i++) h8[4 + i] = (short)f2bf(b[i]);
    return h8;
}

__device__ __forceinline__ float sgnf(float x) {
    return (x > 0.f) ? 1.f : ((x < 0.f) ? -1.f : 0.f);
}

__device__ __forceinline__ void norm3(float& x, float& y, float& z) {
    float n = sqrtf(x * x + y * y + z * z);
    n = fmaxf(n, 1e-12f);
    x /= n; y /= n; z /= n;
}

// ---------- device bodies ----------

__device__ void knn_body(int bid4, const float* __restrict__ X,
                         const float* __restrict__ mask,
                         int* __restrict__ E_idx,
                         float* __restrict__ D_nb) {
    int w = threadIdx.x >> 6, lane = threadIdx.x & 63;
    int g = bid4 * 4 + w;
    int b = g >> 11, n = g & 2047;
    const float* Xb = X + (size_t)b * NN * 3;
    const float* mb = mask + (size_t)b * NN;

    float xn0 = Xb[n * 3], xn1 = Xb[n * 3 + 1], xn2 = Xb[n * 3 + 2];
    float mn = mb[n];

    float Dv[32], m2a[32];
    float lmax = -1e30f;
    #pragma unroll
    for (int s = 0; s < 32; s++) {
        int j = s * 64 + lane;
        float dx = Xb[j * 3] - xn0, dy = Xb[j * 3 + 1] - xn1, dz = Xb[j * 3 + 2] - xn2;
        float d = sqrtf(dx * dx + dy * dy + dz * dz + EPSF);
        float m2 = mn * mb[j];
        float v = m2 * d;
        Dv[s] = v; m2a[s] = m2;
        lmax = fmaxf(lmax, v);
    }
    #pragma unroll
    for (int off = 1; off <= 32; off <<= 1) lmax = fmaxf(lmax, __shfl_xor(lmax, off));
    float Dmax = lmax;
    #pragma unroll
    for (int s = 0; s < 32; s++) Dv[s] += (1.f - m2a[s]) * Dmax;

    // per-lane top-4 sorted list (strict < keeps earliest slot on exact ties).
    // 4-deep => refill (full masked rescan) only on a lane's 4th win: E[refills]≈0.15
    // per wave vs ~8 with top-2 — removes ~2700 VALU ops/wave.
    float l1 = INFV, l2 = INFV, l3 = INFV, l4 = INFV;
    int s1 = 0, s2 = 0, s3 = 0, s4 = 0;
    #pragma unroll
    for (int s = 0; s < 32; s++) {
        float v = Dv[s];
        bool lt1 = v < l1, lt2 = v < l2, lt3 = v < l3, lt4 = v < l4;
        float o1 = l1, o2 = l2, o3 = l3;
        int os1 = s1, os2 = s2, os3 = s3;
        l1 = lt1 ? v : l1;                    s1 = lt1 ? s : s1;
        l2 = lt1 ? o1 : (lt2 ? v : l2);       s2 = lt1 ? os1 : (lt2 ? s : s2);
        l3 = lt2 ? o2 : (lt3 ? v : l3);       s3 = lt2 ? os2 : (lt3 ? s : s3);
        l4 = lt3 ? o3 : (lt4 ? v : l4);       s4 = lt3 ? os3 : (lt4 ? s : s4);
    }

    unsigned used = 0u;
    float keepd = 0.f; int keepj = 0;

    for (int s = 0; s < KK; s++) {
        float m = l1;
        #pragma unroll
        for (int off = 1; off <= 32; off <<= 1) m = fminf(m, __shfl_xor(m, off));
        unsigned long long ball = __ballot(l1 == m);
        int jwin;
        if (__popcll(ball) == 1) {
            int src = (int)(__ffsll((long long)ball) - 1);
            jwin = __shfl(s1 * 64 + lane, src);
        } else {
            int jme = (l1 == m) ? (s1 * 64 + lane) : 0x7FFFFFFF;
            jwin = jme;
            #pragma unroll
            for (int off = 1; off <= 32; off <<= 1) jwin = min(jwin, __shfl_xor(jwin, off));
        }
        if (lane == s) { keepd = m; keepj = jwin; }
        if (lane == (jwin & 63)) {
            used |= 1u << s1;
            l1 = l2; s1 = s2;
            l2 = l3; s2 = s3;
            l3 = l4; s3 = s4;
            l4 = INFV;
            if (l1 >= INFV) {   // rare refill (4th win of this lane)
                l1 = INFV; l2 = INFV; l3 = INFV; l4 = INFV;
                #pragma unroll
                for (int i = 0; i < 32; i++) {
                    float v = ((used >> i) & 1u) ? INFV : Dv[i];
                    bool lt1 = v < l1, lt2 = v < l2, lt3 = v < l3, lt4 = v < l4;
                    float o1 = l1, o2 = l2, o3 = l3;
                    int os1 = s1, os2 = s2, os3 = s3;
                    l1 = lt1 ? v : l1;                    s1 = lt1 ? i : s1;
                    l2 = lt1 ? o1 : (lt2 ? v : l2);       s2 = lt1 ? os1 : (lt2 ? i : s2);
                    l3 = lt2 ? o2 : (lt3 ? v : l3);       s3 = lt2 ? os2 : (lt3 ? i : s3);
                    l4 = lt3 ? o3 : (lt4 ? v : l4);       s4 = lt3 ? os3 : (lt4 ? i : s4);
                }
            }
        }
    }
    if (lane < KK) {
        E_idx[(size_t)g * KK + lane] = keepj;
        D_nb[(size_t)g * KK + lane] = keepd;
    }
}

__device__ __forceinline__ void packB(const float* __restrict__ src, short* __restrict__ dH,
                                      short* __restrict__ dL, int e, int KC, int N, int Kreal) {
    int j = e & 7, ln = (e >> 3) & 63, t = e >> 9;
    int kc = t % KC, nt = t / KC;
    int k = kc * 32 + (ln >> 4) * 8 + j;
    int n = nt * 16 + (ln & 15);
    float v = (k < Kreal) ? src[(size_t)k * N + n] : 0.f;
    short hi, lo; f2bf2(v, hi, lo);
    dH[e] = hi; dL[e] = lo;
}

__device__ void pack_body(int e,
                          const float* __restrict__ We, const float* __restrict__ Wq,
                          const float* __restrict__ lW1, const float* __restrict__ lW2,
                          const float* __restrict__ lW3, const float* __restrict__ lWi,
                          const float* __restrict__ lWo, const float* __restrict__ Wv,
                          short* __restrict__ WeP, short* __restrict__ WqP,
                          short* __restrict__ W1bP, short* __restrict__ W2P,
                          short* __restrict__ W3P, short* __restrict__ WiP,
                          short* __restrict__ WoP, short* __restrict__ W1acP,
                          short* __restrict__ WvP) {
    if (e < 8192) { packB(We, WeP, WeP + 8192, e, 2, 128, 39); return; }
    e -= 8192;
    if (e < 16384) { packB(Wq, WqP, WqP + 16384, e, 4, 128, 128); return; }
    e -= 16384;
    if (e < 49152) {
        int l = e >> 14, r = e & 16383;
        packB(lW1 + (size_t)l * 49152 + 16384, W1bP + l * 32768, W1bP + l * 32768 + 16384, r, 4, 128, 128);
        return;
    }
    e -= 49152;
    if (e < 49152) {
        int l = e >> 14, r = e & 16383;
        packB(lW2 + (size_t)l * 16384, W2P + l * 32768, W2P + l * 32768 + 16384, r, 4, 128, 128);
        return;
    }
    e -= 49152;
    if (e < 49152) {
        int l = e >> 14, r = e & 16383;
        packB(lW3 + (size_t)l * 16384, W3P + l * 32768, W3P + l * 32768 + 16384, r, 4, 128, 128);
        return;
    }
    e -= 49152;
    if (e < 196608) {
        int l = e / 65536, r = e % 65536;
        packB(lWi + (size_t)l * 65536, WiP + l * 131072, WiP + l * 131072 + 65536, r, 4, 512, 128);
        return;
    }
    e -= 196608;
    if (e < 196608) {
        int l = e / 65536, r = e % 65536;
        packB(lWo + (size_t)l * 65536, WoP + l * 131072, WoP + l * 131072 + 65536, r, 16, 128, 512);
        return;
    }
    e -= 196608;
    if (e < 98304) {
        int l = e / 32768, r = e % 32768;
        int j = r & 7, ln = (r >> 3) & 63, t = r >> 9;
        int kc = t & 3, nt = t >> 2;
        int k = kc * 32 + (ln >> 4) * 8 + j;
        int n = nt * 16 + (ln & 15);
        const float* base = lW1 + (size_t)l * 49152;
        float v = (n < 128) ? base[(size_t)k * 128 + n] : base[(size_t)(256 + k) * 128 + (n - 128)];
        short hi, lo; f2bf2(v, hi, lo);
        short* dH = W1acP + l * 65536;
        dH[r] = hi; dH[32768 + r] = lo;
        return;
    }
    e -= 98304;
    // Wv pack (16384 elements)
    packB(Wv, WvP, WvP + 16384, e, 4, 128, 128);
}

__device__ void orient_body(int t, const float* __restrict__ X,
                            float* __restrict__ AD, float* __restrict__ Of) {
    if (t >= BB * NN) return;
    int b = t / NN, n = t % NN;
    float* ad = AD + (size_t)t * 3;
    float* of = Of + (size_t)t * 9;
    if (n < 1 || n > NN - 3) {
        ad[0] = ad[1] = ad[2] = 0.f;
        #pragma unroll
        for (int i = 0; i < 9; i++) of[i] = 0.f;
        return;
    }
    const float* Xb = X + (size_t)b * NN * 3;
    float p0x = Xb[(n - 1) * 3], p0y = Xb[(n - 1) * 3 + 1], p0z = Xb[(n - 1) * 3 + 2];
    float p1x = Xb[n * 3],       p1y = Xb[n * 3 + 1],       p1z = Xb[n * 3 + 2];
    float p2x = Xb[(n + 1) * 3], p2y = Xb[(n + 1) * 3 + 1], p2z = Xb[(n + 1) * 3 + 2];
    float p3x = Xb[(n + 2) * 3], p3y = Xb[(n + 2) * 3 + 1], p3z = Xb[(n + 2) * 3 + 2];

    float u2x = p1x - p0x, u2y = p1y - p0y, u2z = p1z - p0z; norm3(u2x, u2y, u2z);
    float u1x = p2x - p1x, u1y = p2y - p1y, u1z = p2z - p1z; norm3(u1x, u1y, u1z);
    float u0x = p3x - p2x, u0y = p3y - p2y, u0z = p3z - p2z; norm3(u0x, u0y, u0z);

    float n2x = u2y * u1z - u2z * u1y, n2y = u2z * u1x - u2x * u1z, n2z = u2x * u1y - u2y * u1x;
    norm3(n2x, n2y, n2z);
    float n1x = u1y * u0z - u1z * u0y, n1y = u1z * u0x - u1x * u0z, n1z = u1x * u0y - u1y * u0x;
    norm3(n1x, n1y, n1z);

    float cosA = -(u1x * u0x + u1y * u0y + u1z * u0z);
    cosA = fminf(fmaxf(cosA, -1.f + EPSF), 1.f - EPSF);
    float A = acosf(cosA);
    float cosD = n2x * n1x + n2y * n1y + n2z * n1z;
    cosD = fminf(fmaxf(cosD, -1.f + EPSF), 1.f - EPSF);
    float sg = sgnf(u2x * n1x + u2y * n1y + u2z * n1z);
    float Dih = sg * acosf(cosD);

    ad[0] = cosf(A);
    ad[1] = sinf(A) * cosf(Dih);
    ad[2] = sinf(A) * sinf(Dih);

    float o1x = u2x - u1x, o1y = u2y - u1y, o1z = u2z - u1z; norm3(o1x, o1y, o1z);
    float cx = o1y * n2z - o1z * n2y, cy = o1z * n2x - o1x * n2z, cz = o1x * n2y - o1y * n2x;
    of[0] = o1x; of[1] = o1y; of[2] = o1z;
    of[3] = n2x; of[4] = n2y; of[5] = n2z;
    of[6] = cx;  of[7] = cy;  of[8] = cz;
}

// ---------- FRONT: knn (blocks 0..1023) | pack (1024..3679) | orient (3680..3695) ----------

__global__ __launch_bounds__(256) void front_kernel(const float* __restrict__ X,
                                                    const float* __restrict__ mask,
                                                    int* __restrict__ E_idx,
                                                    float* __restrict__ D_nb,
                                                    const float* __restrict__ We,
                                                    const float* __restrict__ Wq,
                                                    const float* __restrict__ lW1,
                                                    const float* __restrict__ lW2,
                                                    const float* __restrict__ lW3,
                                                    const float* __restrict__ lWi,
                                                    const float* __restrict__ lWo,
                                                    const float* __restrict__ Wv,
                                                    short* __restrict__ WeP,
                                                    short* __restrict__ WqP,
                                                    short* __restrict__ W1bP,
                                                    short* __restrict__ W2P,
                                                    short* __restrict__ W3P,
                                                    short* __restrict__ WiP,
                                                    short* __restrict__ WoP,
                                                    short* __restrict__ W1acP,
                                                    short* __restrict__ WvP,
                                                    float* __restrict__ ADb,
                                                    float* __restrict__ Ofb) {
    int blk = blockIdx.x;
    if (blk < KNN_BLK) {
        knn_body(blk, X, mask, E_idx, D_nb);
    } else if (blk < KNN_BLK + PACK_BLK) {
        pack_body((blk - KNN_BLK) * 256 + threadIdx.x,
                  We, Wq, lW1, lW2, lW3, lWi, lWo, Wv,
                  WeP, WqP, W1bP, W2P, W3P, WiP, WoP, W1acP, WvP);
    } else {
        orient_body((blk - KNN_BLK - PACK_BLK) * 256 + threadIdx.x, X, ADb, Ofb);
    }
}

// ---------- MID: edge_feat (blocks 0..4095) | node_feat16 (4096..4351) ----------
// edge_feat: waves split over OUTPUT col-tiles (nt); hEbH output staged through
// LDS (AeH reuse) for coalesced short8 stores instead of 32 scalar 2B stores.

__global__ __launch_bounds__(128) void mid_kernel(const float* __restrict__ X,
                                                  const int* __restrict__ E_idx,
                                                  const float* __restrict__ D_nb,
                                                  const float* __restrict__ Of,
                                                  const float* __restrict__ be,
                                                  const float* __restrict__ ge,
                                                  const float* __restrict__ he,
                                                  const float* __restrict__ bq,
                                                  const short* __restrict__ WeP,
                                                  const short* __restrict__ WqP,
                                                  unsigned short* __restrict__ hEbH,
                                                  const float* __restrict__ AD,
                                                  const float* __restrict__ Wn,
                                                  const float* __restrict__ bn,
                                                  const float* __restrict__ gn,
                                                  const float* __restrict__ hn,
                                                  const short* __restrict__ WvP,
                                                  const float* __restrict__ bv,
                                                  const short* __restrict__ W1acP0,
                                                  const float* __restrict__ b1_0,
                                                  float* __restrict__ hV,
                                                  float* __restrict__ P,
                                                  float* __restrict__ Q) {
    __shared__ __align__(16) char smemRaw[15872];

    if (blockIdx.x < (unsigned)(BB * NN)) {
        // ----- edge_feat body -----
        short* AefH = (short*)smemRaw;                 // 32*72*2   = 4608 B
        short* AeH  = (short*)(smemRaw + 4608);        // 32*136*2  = 8704 B
        float* beS  = (float*)(smemRaw + 13312);       // 512 B
        float* geS  = beS + HH;
        float* heS  = geS + HH;
        float* bqS  = heS + HH;
        float* redSe = (float*)(smemRaw + 15360);      // [2][2][32] = 512 B

        int bid = blockIdx.x; int b = bid >> 11, n = bid & 2047; int tid = threadIdx.x;
        int lane = tid & 63, w = tid >> 6;
        beS[tid] = be[tid]; geS[tid] = ge[tid]; heS[tid] = he[tid]; bqS[tid] = bq[tid];
        {
            unsigned* Az = (unsigned*)AefH;
            for (int i = tid; i < 32 * 72 / 2; i += 128) Az[i] = 0u;
        }
        __syncthreads();

        int part = tid >> 5, k = tid & 31;
        int e = E_idx[(size_t)bid * KK + k];
        float dpos = (float)e - (float)n;
        if (part == 1 || part == 2) {
            int p0 = (part - 1) * 4;
            #pragma unroll
            for (int p = 0; p < 4; p++) {
                // freq = 10000^(-(p0+p)/8) = 10^(-(p0+p)/2) — compile-time constants
                float fr = (part == 1)
                    ? ((p == 0) ? 1.f : (p == 1) ? 0.31622776601683794f
                       : (p == 2) ? 0.1f : 0.031622776601683791f)
                    : ((p == 0) ? 0.01f : (p == 1) ? 0.0031622776601683794f
                       : (p == 2) ? 0.001f : 0.00031622776601683794f);
                float ang = dpos * fr;
                AefH[k * 72 + p0 + p]     = (short)f2bf(__cosf(ang));
                AefH[k * 72 + 8 + p0 + p] = (short)f2bf(__sinf(ang));
            }
        } else if (part == 3) {
            float Dv = D_nb[(size_t)bid * KK + k];
            #pragma unroll
            for (int i = 0; i < 16; i++) {
                float m = (20.f / 15.f) * (float)i;
                float z = (Dv - m) * 0.8f;
                AefH[k * 72 + 16 + i] = (short)f2bf(__expf(-z * z));
            }
        } else {
            const float* Omp = Of + (size_t)(b * NN + n) * 9;
            const float* Onp = Of + (size_t)(b * NN + e) * 9;
            float Om[9], On[9];
            #pragma unroll
            for (int i = 0; i < 9; i++) { Om[i] = Omp[i]; On[i] = Onp[i]; }
            float vx = X[(size_t)(b * NN + e) * 3 + 0] - X[(size_t)(b * NN + n) * 3 + 0];
            float vy = X[(size_t)(b * NN + e) * 3 + 1] - X[(size_t)(b * NN + n) * 3 + 1];
            float vz = X[(size_t)(b * NN + e) * 3 + 2] - X[(size_t)(b * NN + n) * 3 + 2];
            float t0 = Om[0] * vx + Om[1] * vy + Om[2] * vz;
            float t1 = Om[3] * vx + Om[4] * vy + Om[5] * vz;
            float t2 = Om[6] * vx + Om[7] * vy + Om[8] * vz;
            float nr = fmaxf(sqrtf(t0 * t0 + t1 * t1 + t2 * t2), 1e-12f);
            AefH[k * 72 + 32] = (short)f2bf(t0 / nr);
            AefH[k * 72 + 33] = (short)f2bf(t1 / nr);
            AefH[k * 72 + 34] = (short)f2bf(t2 / nr);
            float R[9];
            #pragma unroll
            for (int i = 0; i < 3; i++)
                #pragma unroll
                for (int l = 0; l < 3; l++)
                    R[i * 3 + l] = Om[0 + i] * On[0 + l] + Om[3 + i] * On[3 + l] + Om[6 + i] * On[6 + l];
            float Rxx = R[0], Ryy = R[4], Rzz = R[8];
            float mx = 0.5f * sqrtf(fabsf(1.f + Rxx - Ryy - Rzz));
            float my = 0.5f * sqrtf(fabsf(1.f - Rxx + Ryy - Rzz));
            float mz = 0.5f * sqrtf(fabsf(1.f - Rxx - Ryy + Rzz));
            float qx = sgnf(R[7] - R[5]) * mx;
            float qy = sgnf(R[2] - R[6]) * my;
            float qz = sgnf(R[3] - R[1]) * mz;
            float qw = 0.5f * sqrtf(fmaxf(1.f + Rxx + Ryy + Rzz, 0.f));
            float qn = fmaxf(sqrtf(qx * qx + qy * qy + qz * qz + qw * qw), 1e-12f);
            AefH[k * 72 + 35] = (short)f2bf(qx / qn);
            AefH[k * 72 + 36] = (short)f2bf(qy / qn);
            AefH[k * 72 + 37] = (short)f2bf(qz / qn);
            AefH[k * 72 + 38] = (short)f2bf(qw / qn);
        }
        __syncthreads();

        int m = lane & 15, q = lane >> 4;
        // A-frags: both row-tiles (t), this wave covers all 32 edges
        short8 aW[2][2];
        #pragma unroll
        for (int t = 0; t < 2; t++) {
            int row = (t * 16 + m) * 72;
            aW[t][0] = *(const short8*)&AefH[row + q * 8];
            aW[t][1] = *(const short8*)&AefH[row + 32 + q * 8];
        }
        f32x4 accA[4][2];   // [nt4][t]
        #pragma unroll
        for (int nt4 = 0; nt4 < 4; nt4++) {
            int ntg = w * 4 + nt4;
            const short* B0 = &WeP[((ntg * 2 + 0) * 64 + lane) * 8];
            const short* B1 = &WeP[((ntg * 2 + 1) * 64 + lane) * 8];
            short8 b0h = *(const short8*)B0, b0l = *(const short8*)(B0 + 8192);
            short8 b1h = *(const short8*)B1, b1l = *(const short8*)(B1 + 8192);
            float bc = beS[ntg * 16 + m];
            #pragma unroll
            for (int t = 0; t < 2; t++) {
                f32x4 acc = {bc, bc, bc, bc};
                acc = MFMA16(aW[t][0], b0h, acc);
                acc = MFMA16(aW[t][0], b0l, acc);
                acc = MFMA16(aW[t][1], b1h, acc);
                acc = MFMA16(aW[t][1], b1l, acc);
                accA[nt4][t] = acc;
            }
        }
        // cross-wave LN: partial su/sq per row over this wave's 64 cols
        #pragma unroll
        for (int t = 0; t < 2; t++)
            #pragma unroll
            for (int r = 0; r < 4; r++) {
                float su = accA[0][t][r] + accA[1][t][r] + accA[2][t][r] + accA[3][t][r];
                float sq2 = accA[0][t][r] * accA[0][t][r] + accA[1][t][r] * accA[1][t][r]
                          + accA[2][t][r] * accA[2][t][r] + accA[3][t][r] * accA[3][t][r];
                #pragma unroll
                for (int off = 1; off <= 8; off <<= 1) {
                    su += __shfl_xor(su, off); sq2 += __shfl_xor(sq2, off);
                }
                if (m == 0) {
                    int row = t * 16 + q * 4 + r;
                    redSe[(w * 2 + 0) * 32 + row] = su;
                    redSe[(w * 2 + 1) * 32 + row] = sq2;
                }
            }
        __syncthreads();
        float muA[2][4], invA[2][4];
        #pragma unroll
        for (int t = 0; t < 2; t++)
            #pragma unroll
            for (int r = 0; r < 4; r++) {
                int row = t * 16 + q * 4 + r;
                float S  = redSe[0 * 32 + row] + redSe[2 * 32 + row];
                float Q2 = redSe[1 * 32 + row] + redSe[3 * 32 + row];
                float mu = S * (1.f / HH);
                float var = (Q2 - (float)HH * mu * mu) * (1.f / (HH - 1));
                muA[t][r] = mu;
                invA[t][r] = 1.f / (sqrtf(var + EPSF) + EPSF);
            }
        #pragma unroll
        for (int nt4 = 0; nt4 < 4; nt4++) {
            int col = (w * 4 + nt4) * 16 + m;
            float g = geS[col], hh = heS[col];
            #pragma unroll
            for (int t = 0; t < 2; t++)
                #pragma unroll
                for (int r = 0; r < 4; r++) {
                    int edge = t * 16 + q * 4 + r;
                    float y = g * (accA[nt4][t][r] - muA[t][r]) * invA[t][r] + hh;
                    AeH[edge * 136 + col] = (short)f2bf(y);
                }
        }
        __syncthreads();

        short8 ah[2][4];
        #pragma unroll
        for (int t = 0; t < 2; t++)
            #pragma unroll
            for (int kc = 0; kc < 4; kc++)
                ah[t][kc] = *(const short8*)&AeH[(t * 16 + m) * 136 + kc * 32 + q * 8];
        __syncthreads();   // all A-frag preloads done — AeH becomes output staging

        #pragma unroll
        for (int nt4 = 0; nt4 < 4; nt4++) {
            int ntg = w * 4 + nt4;
            int col = ntg * 16 + m;
            short8 qh[4], ql[4];
            #pragma unroll
            for (int kc = 0; kc < 4; kc++) {
                const short* Bp = &WqP[((ntg * 4 + kc) * 64 + lane) * 8];
                qh[kc] = *(const short8*)Bp;
                ql[kc] = *(const short8*)(Bp + 16384);
            }
            float bc = bqS[col];
            #pragma unroll
            for (int t = 0; t < 2; t++) {
                f32x4 acc = {bc, bc, bc, bc};
                #pragma unroll
                for (int kc = 0; kc < 4; kc++) {
                    acc = MFMA16(ah[t][kc], qh[kc], acc);
                    acc = MFMA16(ah[t][kc], ql[kc], acc);
                }
                #pragma unroll
                for (int r = 0; r < 4; r++) {
                    int edge = t * 16 + q * 4 + r;
                    AeH[edge * 136 + col] = (short)f2bf(acc[r]);
                }
            }
        }
        __syncthreads();

        // coalesced copy-out: 512 short8 chunks, 4 per thread (256B contiguous/row)
        {
            unsigned short* outp = hEbH + (size_t)bid * (KK * HH);
            #pragma unroll
            for (int it = 0; it < 4; it++) {
                int idx = it * 128 + tid;       // 0..511
                int row = idx >> 4, c8 = idx & 15;
                *(short8*)(outp + row * HH + c8 * 8) = *(const short8*)&AeH[row * 136 + c8 * 8];
            }
        }
    } else {
        // ----- node_feat body: 16 nodes per block, MFMA path -----
        short* yH  = (short*)smemRaw;                  // 16*136*2 = 4352 B
        short* hvH = (short*)(smemRaw + 4352);         // 4352 B

        int nb = blockIdx.x - BB * NN;
        int g0 = nb * 16;
        int tid = threadIdx.x;
        int lane = tid & 63, w = tid >> 6;
        int m = lane & 15, q = lane >> 4;

        // step 1: V = AD @ Wn + bn, per-node LN -> y (bf16 in LDS)
        {
            int i = tid >> 3;          // node 0..15
            int j = tid & 7;           // column group (16 cols each)
            int h0 = j * 16;
            const float* ad = AD + (size_t)(g0 + i) * 3;
            float a0 = ad[0], a1 = ad[1], a2 = ad[2];
            float v[16];
            float su = 0.f, sq = 0.f;
            #pragma unroll
            for (int c = 0; c < 16; c++) {
                int h = h0 + c;
                float t = bn[h] + a0 * Wn[h] + a1 * Wn[HH + h] + a2 * Wn[2 * HH + h];
                v[c] = t; su += t; sq += t * t;
            }
            #pragma unroll
            for (int off = 1; off <= 4; off <<= 1) {
                su += __shfl_xor(su, off); sq += __shfl_xor(sq, off);
            }
            float mu = su * (1.f / HH);
            float var = (sq - (float)HH * mu * mu) * (1.f / (HH - 1));
            float inv = 1.f / (sqrtf(var + EPSF) + EPSF);
            #pragma unroll
            for (int c = 0; c < 16; c++) {
                int h = h0 + c;
                yH[i * 136 + h] = (short)f2bf(gn[h] * (v[c] - mu) * inv + hn[h]);
            }
        }
        __syncthreads();

        // step 2: hV = y @ Wv + bv  (wave handles 4 of 8 col-tiles)
        short8 ayh[4];
        #pragma unroll
        for (int kc = 0; kc < 4; kc++)
            ayh[kc] = *(const short8*)&yH[m * 136 + kc * 32 + q * 8];
        #pragma unroll
        for (int u = 0; u < 4; u++) {
            int nt = w * 4 + u;
            int col = nt * 16 + m;
            float bc = bv[col];
            f32x4 a = {bc, bc, bc, bc};
            #pragma unroll
            for (int kc = 0; kc < 4; kc++) {
                const short* Bp = &WvP[((nt * 4 + kc) * 64 + lane) * 8];
                short8 bh = *(const short8*)Bp, bl = *(const short8*)(Bp + 16384);
                a = MFMA16(ayh[kc], bh, a);
                a = MFMA16(ayh[kc], bl, a);
            }
            #pragma unroll
            for (int r = 0; r < 4; r++) {
                int rw = q * 4 + r;
                hV[(size_t)(g0 + rw) * HH + col] = a[r];
                hvH[rw * 136 + col] = (short)f2bf(a[r]);
            }
        }
        __syncthreads();

        // step 3: layer-0 premix P/Q = hV @ W1_0[a|c] (+b1 for P), via packed W1acP[0]
        short8 avh[4];
        #pragma unroll
        for (int kc = 0; kc < 4; kc++)
            avh[kc] = *(const short8*)&hvH[m * 136 + kc * 32 + q * 8];
        #pragma unroll
        for (int u = 0; u < 8; u++) {
            int nt = w * 8 + u;
            int col = nt * 16 + m;
            float b0 = (nt < 8) ? b1_0[col] : 0.f;
            f32x4 a = {b0, b0, b0, b0};
            #pragma unroll
            for (int kc = 0; kc < 4; kc++) {
                const short* Bp = &W1acP0[((nt * 4 + kc) * 64 + lane) * 8];
                short8 bh = *(const short8*)Bp, bl = *(const short8*)(Bp + 32768);
                a = MFMA16(avh[kc], bh, a);
                a = MFMA16(avh[kc], bl, a);
            }
            #pragma unroll
            for (int r = 0; r < 4; r++) {
                size_t rw = g0 + q * 4 + r;
                if (nt < 8) P[rw * HH + col] = a[r];
                else        Q[rw * HH + (col - 128)] = a[r];
            }
        }
    }
}

// ---------- message kernel: block = 2 nodes, 4 waves, 2 nt-tiles per wave ----------
// (r7 form) A-side staged in LDS; weights loaded once per nt-tile per wave and
// reused for both nodes. Q gathers hoisted to registers before the staging
// barrier so their latency overlaps the LDS staging drain.

__global__ __launch_bounds__(256) void msg_kernel(const float* __restrict__ mask,
                                                  const int* __restrict__ E_idx,
                                                  const unsigned short* __restrict__ hEbH,
                                                  const float* __restrict__ P,
                                                  const float* __restrict__ Q,
                                                  const short* __restrict__ W1bP,
                                                  const short* __restrict__ W2P,
                                                  const float* __restrict__ b2,
                                                  float* __restrict__ sOut,
                                                  float* __restrict__ cntOut) {
    __shared__ short stg[2][32 * 136];   // staged h_E (bf16) per node
    __shared__ short AmH[2][32 * 136];   // m1 (bf16) per node

    int tid = threadIdx.x;
    int w = tid >> 6, lane = tid & 63;
    int gA = blockIdx.x * 2;             // nodes gA, gA+1 (same batch: NN even)
    int b = gA >> 11;
    int m = lane & 15, q = lane >> 4;

    // ---- stage hEbH for both nodes (fully coalesced short8 loads) ----
    {
        const short8* src = (const short8*)(hEbH + (size_t)gA * (KK * HH));
        #pragma unroll
        for (int it = 0; it < 4; it++) {
            int idx = it * 256 + tid;        // 0..1023 short8 chunks
            int nd = idx >> 9;
            int rem = idx & 511;
            int e = rem >> 4;                // edge
            int c8 = rem & 15;               // col/8
            short8 v = src[idx];
            *(short8*)&stg[nd][e * 136 + c8 * 8] = v;
        }
    }

    int qbase[2][2][4]; float mt[2][2][4];
    #pragma unroll
    for (int nd = 0; nd < 2; nd++) {
        float maskv = mask[gA + nd];
        #pragma unroll
        for (int t = 0; t < 2; t++)
            #pragma unroll
            for (int r = 0; r < 4; r++) {
                int row = t * 16 + q * 4 + r;
                int e = E_idx[(size_t)(gA + nd) * KK + row];
                qbase[nd][t][r] = (b * NN + e) * HH;
                mt[nd][t][r] = maskv * mask[b * NN + e];
            }
    }
    if (w < 2) {
        // wave w (0,1) produces cnt for node w
        float c8 = mt[w][0][0] + mt[w][0][1] + mt[w][0][2] + mt[w][0][3]
                 + mt[w][1][0] + mt[w][1][1] + mt[w][1][2] + mt[w][1][3];
        c8 += __shfl_xor(c8, 16);
        c8 += __shfl_xor(c8, 32);
        if (lane == 0) cntOut[gA + w] = c8;
    }

    float preg[2][2], b2reg[2];
    #pragma unroll
    for (int u = 0; u < 2; u++) {
        int colg = (w * 2 + u) * 16 + m;
        b2reg[u] = b2[colg];
        preg[0][u] = P[(size_t)gA * HH + colg];
        preg[1][u] = P[(size_t)(gA + 1) * HH + colg];
    }

    // prefetch all Q gathers (32 scattered loads) — overlap with staging barrier
    float qv[2][2][2][4];   // [u][nd][t][r]
    #pragma unroll
    for (int u = 0; u < 2; u++) {
        int colg = (w * 2 + u) * 16 + m;
        #pragma unroll
        for (int nd = 0; nd < 2; nd++)
            #pragma unroll
            for (int t = 0; t < 2; t++)
                #pragma unroll
                for (int r = 0; r < 4; r++)
                    qv[u][nd][t][r] = Q[(size_t)qbase[nd][t][r] + colg];
    }
    __syncthreads();

    // phase 1: m1 = relu(P + Q[nbr] + h_E @ W1b) — wave handles 2 nt tiles, both nodes
    #pragma unroll
    for (int u = 0; u < 2; u++) {
        int ntg = w * 2 + u;
        int colg = ntg * 16 + m;
        short8 bh[4], bl[4];
        #pragma unroll
        for (int kc = 0; kc < 4; kc++) {
            const short* Bp = &W1bP[((ntg * 4 + kc) * 64 + lane) * 8];
            bh[kc] = *(const short8*)Bp;
            bl[kc] = *(const short8*)(Bp + 16384);
        }
        #pragma unroll
        for (int nd = 0; nd < 2; nd++) {
            f32x4 t0 = {0.f, 0.f, 0.f, 0.f}, t1 = {0.f, 0.f, 0.f, 0.f};
            #pragma unroll
            for (int kc = 0; kc < 4; kc++) {
                short8 a0 = *(const short8*)&stg[nd][(0 * 16 + m) * 136 + kc * 32 + q * 8];
                short8 a1 = *(const short8*)&stg[nd][(1 * 16 + m) * 136 + kc * 32 + q * 8];
                t0 = MFMA16(a0, bh[kc], t0);
                t0 = MFMA16(a0, bl[kc], t0);
                t1 = MFMA16(a1, bh[kc], t1);
                t1 = MFMA16(a1, bl[kc], t1);
            }
            float pp = preg[nd][u];
            #pragma unroll
            for (int r = 0; r < 4; r++) {
                float v0 = fmaxf(t0[r] + pp + qv[u][nd][0][r], 0.f);
                AmH[nd][(q * 4 + r) * 136 + colg] = (short)f2bf(v0);
                float v1 = fmaxf(t1[r] + pp + qv[u][nd][1][r], 0.f);
                AmH[nd][(16 + q * 4 + r) * 136 + colg] = (short)f2bf(v1);
            }
        }
    }
    __syncthreads();

    // phase 2: m2 = relu(m1 @ W2 + b2); masked sum over 32 edges
    #pragma unroll
    for (int u = 0; u < 2; u++) {
        int ntg = w * 2 + u;
        short8 bh[4], bl[4];
        #pragma unroll
        for (int kc = 0; kc < 4; kc++) {
            const short* Bp = &W2P[((ntg * 4 + kc) * 64 + lane) * 8];
            bh[kc] = *(const short8*)Bp;
            bl[kc] = *(const short8*)(Bp + 16384);
        }
        float bc = b2reg[u];
        #pragma unroll
        for (int nd = 0; nd < 2; nd++) {
            f32x4 a0 = {bc, bc, bc, bc}, a1 = {bc, bc, bc, bc};
            #pragma unroll
            for (int kc = 0; kc < 4; kc++) {
                short8 m0 = *(const short8*)&AmH[nd][(0 * 16 + m) * 136 + kc * 32 + q * 8];
                short8 m1 = *(const short8*)&AmH[nd][(1 * 16 + m) * 136 + kc * 32 + q * 8];
                a0 = MFMA16(m0, bh[kc], a0);
                a0 = MFMA16(m0, bl[kc], a0);
                a1 = MFMA16(m1, bh[kc], a1);
                a1 = MFMA16(m1, bl[kc], a1);
            }
            float part = 0.f;
            #pragma unroll
            for (int r = 0; r < 4; r++)
                part += fmaxf(a0[r], 0.f) * mt[nd][0][r] + fmaxf(a1[r], 0.f) * mt[nd][1][r];
            part += __shfl_xor(part, 16);
            part += __shfl_xor(part, 32);
            if (q == 0) sOut[(size_t)(gA + nd) * HH + ntg * 16 + m] = part;
        }
    }
}

// ---------- node kernel: 8 waves (512 threads), 16 nodes/block ----------
// hVin residual + LN1 mask loads hoisted to kernel top: their L2 latency drains
// under the W3/FFN MFMA work instead of stalling the LN barriers.

#define HSTR 520   // LDS stride (shorts) for 512-wide hidden staging

__global__ __launch_bounds__(512, 2) void node_kernel(const float* __restrict__ mask,
                                                      const float* __restrict__ sbuf,
                                                      const float* __restrict__ cntb,
                                                      const float* __restrict__ hVin,
                                                      const short* __restrict__ W3P,
                                                      const float* __restrict__ b3,
                                                      const short* __restrict__ WiP,
                                                      const float* __restrict__ biN,
                                                      const short* __restrict__ WoP,
                                                      const float* __restrict__ boN,
                                                      const float* __restrict__ g0,
                                                      const float* __restrict__ h0,
                                                      const float* __restrict__ g1,
                                                      const float* __restrict__ h1,
                                                      const short* __restrict__ W1P,
                                                      const float* __restrict__ b1n,
                                                      float* __restrict__ hVout,
                                                      float* __restrict__ Pn,
                                                      float* __restrict__ Qn) {
    __shared__ short rbH[16 * 136];
    __shared__ short hbH[16 * HSTR];
    __shared__ float redS[8][2][16];
    __shared__ float g0S[128], h0S[128], g1S[128], h1S[128], b3S[128], boS[128], b1S[128];
    __shared__ float biS[512];

    int tid = threadIdx.x;
    int w = tid >> 6, lane = tid & 63;
    int m = lane & 15, q = lane >> 4;
    int rowT = blockIdx.x * 16;

    if (tid < 128) {
        int i = tid;
        g0S[i] = g0[i]; h0S[i] = h0[i]; g1S[i] = g1[i]; h1S[i] = h1[i];
        b3S[i] = b3[i]; boS[i] = boN[i]; b1S[i] = W1P ? b1n[i] : 0.f;
    }
    biS[tid] = biN[tid];

    // hoisted independent global loads (drain under MFMA work below)
    short8 ash[4];
    #pragma unroll
    for (int kc = 0; kc < 4; kc++) {
        const float* sp = &sbuf[(size_t)(rowT + m) * HH + kc * 32 + q * 8];
        f32x4 x0 = *(const f32x4*)sp;
        f32x4 x1 = *(const f32x4*)(sp + 4);
        ash[kc] = cvt8h(x0, x1);
    }
    float cntr[4], hvr[4], mk[4];
    {
        int col = w * 16 + m;
        #pragma unroll
        for (int r = 0; r < 4; r++) {
            cntr[r] = cntb[rowT + q * 4 + r];
            hvr[r]  = hVin[(size_t)(rowT + q * 4 + r) * HH + col];
            mk[r]   = mask[rowT + q * 4 + r];
        }
    }
    __syncthreads();

    // W3: wave w owns col-tile w
    f32x4 vC;
    {
        f32x4 a = {0.f, 0.f, 0.f, 0.f};
        #pragma unroll
        for (int kc = 0; kc < 4; kc++) {
            const short* Bp = &W3P[((w * 4 + kc) * 64 + lane) * 8];
            short8 bh = *(const short8*)Bp, bl = *(const short8*)(Bp + 16384);
            a = MFMA16(ash[kc], bh, a);
            a = MFMA16(ash[kc], bl, a);
        }
        int col = w * 16 + m;
        #pragma unroll
        for (int r = 0; r < 4; r++) {
            float tv = (a[r] + cntr[r] * b3S[col]) * (1.f / 30.f);
            a[r] = hvr[r] + tv;
        }
        vC = a;
    }

    // LN0 (cross-8-wave)
    {
        float su[4], sq[4];
        #pragma unroll
        for (int r = 0; r < 4; r++) { float v = vC[r]; su[r] = v; sq[r] = v * v; }
        #pragma unroll
        for (int off = 1; off <= 8; off <<= 1)
            #pragma unroll
            for (int r = 0; r < 4; r++) { su[r] += __shfl_xor(su[r], off); sq[r] += __shfl_xor(sq[r], off); }
        if (m == 0) {
            #pragma unroll
            for (int r = 0; r < 4; r++) { redS[w][0][q * 4 + r] = su[r]; redS[w][1][q * 4 + r] = sq[r]; }
        }
    }
    __syncthreads();
    float mu[4], inv[4];
    #pragma unroll
    for (int r = 0; r < 4; r++) {
        int row = q * 4 + r;
        float S = 0.f, Q2 = 0.f;
        #pragma unroll
        for (int ww = 0; ww < 8; ww++) { S += redS[ww][0][row]; Q2 += redS[ww][1][row]; }
        mu[r] = S * (1.f / HH);
        float var = (Q2 - (float)HH * mu[r] * mu[r]) * (1.f / (HH - 1));
        inv[r] = 1.f / (sqrtf(var + EPSF) + EPSF);
    }
    {
        int col = w * 16 + m;
        #pragma unroll
        for (int r = 0; r < 4; r++) {
            vC[r] = g0S[col] * (vC[r] - mu[r]) * inv[r] + h0S[col];
            rbH[(q * 4 + r) * 136 + col] = (short)f2bf(vC[r]);
        }
    }
    __syncthreads();

    short8 avh[4];
    #pragma unroll
    for (int kc = 0; kc < 4; kc++)
        avh[kc] = *(const short8*)&rbH[m * 136 + kc * 32 + q * 8];

    // FFN-in: wave's 64 hidden cols (4 of 32 tiles)
    #pragma unroll
    for (int u = 0; u < 4; u++) {
        int nt = w * 4 + u;
        int jcol = nt * 16 + m;
        float bb = biS[jcol];
        f32x4 a = {bb, bb, bb, bb};
        #pragma unroll
        for (int kc = 0; kc < 4; kc++) {
            const short* Bp = &WiP[((nt * 4 + kc) * 64 + lane) * 8];
            short8 bh = *(const short8*)Bp, bl = *(const short8*)(Bp + 65536);
            a = MFMA16(avh[kc], bh, a);
            a = MFMA16(avh[kc], bl, a);
        }
        #pragma unroll
        for (int r = 0; r < 4; r++)
            hbH[(q * 4 + r) * HSTR + jcol] = (short)f2bf(fmaxf(a[r], 0.f));
    }
    __syncthreads();

    // FFN-out: wave's col-tile w over ALL 512 hidden
    f32x4 oC = {0.f, 0.f, 0.f, 0.f};
    for (int kc2 = 0; kc2 < 16; kc2++) {
        short8 ahh = *(const short8*)&hbH[m * HSTR + kc2 * 32 + q * 8];
        const short* Bp = &WoP[((w * 16 + kc2) * 64 + lane) * 8];
        short8 bh = *(const short8*)Bp, bl = *(const short8*)(Bp + 65536);
        oC = MFMA16(ahh, bh, oC);
        oC = MFMA16(ahh, bl, oC);
    }
    {
        int col = w * 16 + m;
        #pragma unroll
        for (int r = 0; r < 4; r++)
            oC[r] += boS[col] + vC[r];
    }

    // LN1 (cross-8-wave)
    {
        float su[4], sq[4];
        #pragma unroll
        for (int r = 0; r < 4; r++) { float v = oC[r]; su[r] = v; sq[r] = v * v; }
        #pragma unroll
        for (int off = 1; off <= 8; off <<= 1)
            #pragma unroll
            for (int r = 0; r < 4; r++) { su[r] += __shfl_xor(su[r], off); sq[r] += __shfl_xor(sq[r], off); }
        __syncthreads();   // redS reuse
        if (m == 0) {
            #pragma unroll
            for (int r = 0; r < 4; r++) { redS[w][0][q * 4 + r] = su[r]; redS[w][1][q * 4 + r] = sq[r]; }
        }
    }
    __syncthreads();
    #pragma unroll
    for (int r = 0; r < 4; r++) {
        int row = q * 4 + r;
        float S = 0.f, Q2 = 0.f;
        #pragma unroll
        for (int ww = 0; ww < 8; ww++) { S += redS[ww][0][row]; Q2 += redS[ww][1][row]; }
        mu[r] = S * (1.f / HH);
        float var = (Q2 - (float)HH * mu[r] * mu[r]) * (1.f / (HH - 1));
        inv[r] = 1.f / (sqrtf(var + EPSF) + EPSF);
    }
    {
        int col = w * 16 + m;
        #pragma unroll
        for (int r = 0; r < 4; r++) {
            float y = g1S[col] * (oC[r] - mu[r]) * inv[r] + h1S[col];
            y *= mk[r];
            oC[r] = y;
            hVout[(size_t)(rowT + q * 4 + r) * HH + col] = y;
        }
    }

    // fused next-layer premix (wave's 2 of 16 col-tiles)
    if (W1P) {
        __syncthreads();
        {
            int col = w * 16 + m;
            #pragma unroll
            for (int r = 0; r < 4; r++)
                rbH[(q * 4 + r) * 136 + col] = (short)f2bf(oC[r]);
        }
        __syncthreads();
        short8 ayh[4];
        #pragma unroll
        for (int kc = 0; kc < 4; kc++)
            ayh[kc] = *(const short8*)&rbH[m * 136 + kc * 32 + q * 8];
        #pragma unroll
        for (int u = 0; u < 2; u++) {
            int nt = w * 2 + u;
            int col = nt * 16 + m;
            float b0 = (nt < 8) ? b1S[col] : 0.f;
            f32x4 a = {b0, b0, b0, b0};
            #pragma unroll
            for (int kc = 0; kc < 4; kc++) {
                const short* Bp = &W1P[((nt * 4 + kc) * 64 + lane) * 8];
                short8 bh = *(const short8*)Bp, bl = *(const short8*)(Bp + 32768);
                a = MFMA16(ayh[kc], bh, a);
                a = MFMA16(ayh[kc], bl, a);
            }
            #pragma unroll
            for (int r = 0; r < 4; r++) {
                size_t row = rowT + q * 4 + r;
                if (nt < 8) Pn[row * HH + col] = a[r];
                else        Qn[row * HH + (col - 128)] = a[r];
            }
        }
    }
}

// ---------- launch ----------

extern "C" void kernel_launch(void* const* d_in, const int* in_sizes, int n_in,
                              void* d_out, int out_size, void* d_ws, size_t ws_size,
                              hipStream_t stream) {
    const float* X    = (const float*)d_in[0];
    const float* mask = (const float*)d_in[1];
    const float* Wn   = (const float*)d_in[2];
    const float* bn   = (const float*)d_in[3];
    const float* gn   = (const float*)d_in[4];
    const float* hn   = (const float*)d_in[5];
    const float* We   = (const float*)d_in[6];
    const float* be   = (const float*)d_in[7];
    const float* ge   = (const float*)d_in[8];
    const float* he   = (const float*)d_in[9];
    const float* Wv   = (const float*)d_in[10];
    const float* bv   = (const float*)d_in[11];
    const float* Wq   = (const float*)d_in[12];
    const float* bq   = (const float*)d_in[13];
    const float* lW1  = (const float*)d_in[14];
    const float* lb1  = (const float*)d_in[15];
    const float* lW2  = (const float*)d_in[16];
    const float* lb2  = (const float*)d_in[17];
    const float* lW3  = (const float*)d_in[18];
    const float* lb3  = (const float*)d_in[19];
    const float* lWi  = (const float*)d_in[20];
    const float* lbi  = (const float*)d_in[21];
    const float* lWo  = (const float*)d_in[22];
    const float* lbo  = (const float*)d_in[23];
    const float* lg0  = (const float*)d_in[24];
    const float* lh0  = (const float*)d_in[25];
    const float* lg1  = (const float*)d_in[26];
    const float* lh1  = (const float*)d_in[27];

    char* ws = (char*)d_ws;
    size_t off = 0;
    auto alloc = [&](size_t nbytes) { void* p = ws + off; off += (nbytes + 15) & ~(size_t)15; return p; };
    int*   E_idx = (int*)  alloc((size_t)BB * NN * KK * 4);
    float* D_nb  = (float*)alloc((size_t)BB * NN * KK * 4);
    float* ADb   = (float*)alloc((size_t)BB * NN * 3 * 4);
    float* Ofb   = (float*)alloc((size_t)BB * NN * 9 * 4);
    float* hV    = (float*)alloc((size_t)BB * NN * HH * 4);
    unsigned short* hEbH = (unsigned short*)alloc((size_t)BB * NN * KK * HH * 2);
    float* Pb    = (float*)alloc((size_t)BB * NN * HH * 4);
    float* Qb    = (float*)alloc((size_t)BB * NN * HH * 4);
    float* sBuf  = (float*)alloc((size_t)BB * NN * HH * 4);
    float* cntB  = (float*)alloc((size_t)BB * NN * 4);
    short* WeP   = (short*)alloc(2 * 8192 * 2);
    short* WqP   = (short*)alloc(2 * 16384 * 2);
    short* W1bP  = (short*)alloc(3 * 2 * 16384 * 2);
    short* W2P   = (short*)alloc(3 * 2 * 16384 * 2);
    short* W3P   = (short*)alloc(3 * 2 * 16384 * 2);
    short* WiP   = (short*)alloc(3 * 2 * 65536 * 2);
    short* WoP   = (short*)alloc(3 * 2 * 65536 * 2);
    short* W1acP = (short*)alloc(3 * 2 * 32768 * 2);
    short* WvP   = (short*)alloc(2 * 16384 * 2);
    if (off > ws_size) return;

    // Dispatch 1: knn | pack | orient (mutually independent)
    front_kernel<<<KNN_BLK + PACK_BLK + ORIENT_BLK, 256, 0, stream>>>(
        X, mask, E_idx, D_nb,
        We, Wq, lW1, lW2, lW3, lWi, lWo, Wv,
        WeP, WqP, W1bP, W2P, W3P, WiP, WoP, W1acP, WvP,
        ADb, Ofb);

    // Dispatch 2: edge_feat | node_feat16 (mutually independent; both need dispatch 1)
    mid_kernel<<<BB * NN + BB * NN / 16, 128, 0, stream>>>(
        X, E_idx, D_nb, Ofb, be, ge, he, bq, WeP, WqP, hEbH,
        ADb, Wn, bn, gn, hn, WvP, bv, W1acP, lb1, hV, Pb, Qb);

    for (int l = 0; l < 3; l++) {
        int last = (l == 2);
        msg_kernel<<<BB * NN / 2, 256, 0, stream>>>(
            mask, E_idx, hEbH, Pb, Qb,
            W1bP + (size_t)l * 32768,
            W2P + (size_t)l * 32768, lb2 + (size_t)l * HH,
            sBuf, cntB);
        node_kernel<<<BB * NN / 16, 512, 0, stream>>>(
            mask, sBuf, cntB, hV,
            W3P + (size_t)l * 32768, lb3 + (size_t)l * HH,
            WiP + (size_t)l * 131072, lbi + (size_t)l * DFF,
            WoP + (size_t)l * 131072, lbo + (size_t)l * HH,
            lg0 + (size_t)l * HH, lh0 + (size_t)l * HH,
            lg1 + (size_t)l * HH, lh1 + (size_t)l * HH,
            last ? nullptr : (W1acP + (size_t)(l + 1) * 65536),
            last ? nullptr : (lb1 + (size_t)(l + 1) * HH),
            last ? (float*)d_out : hV,
            Pb, Qb);
    }
}

// Round 17
// 291.425 us; speedup vs baseline: 1.0995x; 1.0071x over previous
//
#include <hip/hip_runtime.h>
#include <math.h>

typedef __attribute__((ext_vector_type(8))) short short8;
typedef __attribute__((ext_vector_type(4))) float f32x4;

#define BB 2
#define NN 2048
#define KK 32
#define HH 128
#define DFF 512
#define EPSF 1e-6f
#define INFV 1e30f

#define KNN_BLK 1024
#define PACK_BLK 2656
#define ORIENT_BLK 16

#define MFMA16(a, b, c) __builtin_amdgcn_mfma_f32_16x16x32_bf16((a), (b), (c), 0, 0, 0)

// ---------- helpers ----------

__device__ __forceinline__ unsigned short f2bf(float f) {
    unsigned u = __float_as_uint(f);
    u += 0x7fffu + ((u >> 16) & 1u);          // round-to-nearest-even
    return (unsigned short)(u >> 16);
}

__device__ __forceinline__ float bf2f(unsigned short h) {
    return __uint_as_float(((unsigned)h) << 16);
}

// split x into hi+lo bf16 pair — WEIGHTS only (systematic error must stay split)
__device__ __forceinline__ void f2bf2(float x, short& hi, short& lo) {
    unsigned short h = f2bf(x);
    hi = (short)h;
    lo = (short)f2bf(x - bf2f(h));
}

// pack 8 floats -> hi-plane short8
__device__ __forceinline__ short8 cvt8h(f32x4 a, f32x4 b) {
    short8 h8;
    #pragma unroll
    for (int i = 0; i < 4; i++) h8[i] = (short)f2bf(a[i]);
    #pragma unroll
    for (int i = 0; i < 4; i++) h8[4 + i] = (short)f2bf(b[i]);
    return h8;
}

__device__ __forceinline__ float sgnf(float x) {
    return (x > 0.f) ? 1.f : ((x < 0.f) ? -1.f : 0.f);
}

__device__ __forceinline__ void norm3(float& x, float& y, float& z) {
    float n = sqrtf(x * x + y * y + z * z);
    n = fmaxf(n, 1e-12f);
    x /= n; y /= n; z /= n;
}

// ---------- device bodies ----------

__device__ void knn_body(int bid4, const float* __restrict__ X,
                         const float* __restrict__ mask,
                         int* __restrict__ E_idx,
                         float* __restrict__ D_nb) {
    int w = threadIdx.x >> 6, lane = threadIdx.x & 63;
    int g = bid4 * 4 + w;
    int b = g >> 11, n = g & 2047;
    const float* Xb = X + (size_t)b * NN * 3;
    const float* mb = mask + (size_t)b * NN;

    float xn0 = Xb[n * 3], xn1 = Xb[n * 3 + 1], xn2 = Xb[n * 3 + 2];
    float mn = mb[n];

    float Dv[32], m2a[32];
    float lmax = -1e30f;
    #pragma unroll
    for (int s = 0; s < 32; s++) {
        int j = s * 64 + lane;
        float dx = Xb[j * 3] - xn0, dy = Xb[j * 3 + 1] - xn1, dz = Xb[j * 3 + 2] - xn2;
        float d = sqrtf(dx * dx + dy * dy + dz * dz + EPSF);
        float m2 = mn * mb[j];
        float v = m2 * d;
        Dv[s] = v; m2a[s] = m2;
        lmax = fmaxf(lmax, v);
    }
    #pragma unroll
    for (int off = 1; off <= 32; off <<= 1) lmax = fmaxf(lmax, __shfl_xor(lmax, off));
    float Dmax = lmax;
    #pragma unroll
    for (int s = 0; s < 32; s++) Dv[s] += (1.f - m2a[s]) * Dmax;

    // per-lane top-4 sorted list (strict < keeps earliest slot on exact ties).
    // 4-deep => refill (full masked rescan) only on a lane's 4th win: E[refills]≈0.15
    // per wave vs ~8 with top-2 — removes ~2700 VALU ops/wave.
    float l1 = INFV, l2 = INFV, l3 = INFV, l4 = INFV;
    int s1 = 0, s2 = 0, s3 = 0, s4 = 0;
    #pragma unroll
    for (int s = 0; s < 32; s++) {
        float v = Dv[s];
        bool lt1 = v < l1, lt2 = v < l2, lt3 = v < l3, lt4 = v < l4;
        float o1 = l1, o2 = l2, o3 = l3;
        int os1 = s1, os2 = s2, os3 = s3;
        l1 = lt1 ? v : l1;                    s1 = lt1 ? s : s1;
        l2 = lt1 ? o1 : (lt2 ? v : l2);       s2 = lt1 ? os1 : (lt2 ? s : s2);
        l3 = lt2 ? o2 : (lt3 ? v : l3);       s3 = lt2 ? os2 : (lt3 ? s : s3);
        l4 = lt3 ? o3 : (lt4 ? v : l4);       s4 = lt3 ? os3 : (lt4 ? s : s4);
    }

    unsigned used = 0u;
    float keepd = 0.f; int keepj = 0;

    for (int s = 0; s < KK; s++) {
        float m = l1;
        #pragma unroll
        for (int off = 1; off <= 32; off <<= 1) m = fminf(m, __shfl_xor(m, off));
        unsigned long long ball = __ballot(l1 == m);
        int jwin;
        if (__popcll(ball) == 1) {
            int src = (int)(__ffsll((long long)ball) - 1);
            jwin = __shfl(s1 * 64 + lane, src);
        } else {
            int jme = (l1 == m) ? (s1 * 64 + lane) : 0x7FFFFFFF;
            jwin = jme;
            #pragma unroll
            for (int off = 1; off <= 32; off <<= 1) jwin = min(jwin, __shfl_xor(jwin, off));
        }
        if (lane == s) { keepd = m; keepj = jwin; }
        if (lane == (jwin & 63)) {
            used |= 1u << s1;
            l1 = l2; s1 = s2;
            l2 = l3; s2 = s3;
            l3 = l4; s3 = s4;
            l4 = INFV;
            if (l1 >= INFV) {   // rare refill (4th win of this lane)
                l1 = INFV; l2 = INFV; l3 = INFV; l4 = INFV;
                #pragma unroll
                for (int i = 0; i < 32; i++) {
                    float v = ((used >> i) & 1u) ? INFV : Dv[i];
                    bool lt1 = v < l1, lt2 = v < l2, lt3 = v < l3, lt4 = v < l4;
                    float o1 = l1, o2 = l2, o3 = l3;
                    int os1 = s1, os2 = s2, os3 = s3;
                    l1 = lt1 ? v : l1;                    s1 = lt1 ? i : s1;
                    l2 = lt1 ? o1 : (lt2 ? v : l2);       s2 = lt1 ? os1 : (lt2 ? i : s2);
                    l3 = lt2 ? o2 : (lt3 ? v : l3);       s3 = lt2 ? os2 : (lt3 ? i : s3);
                    l4 = lt3 ? o3 : (lt4 ? v : l4);       s4 = lt3 ? os3 : (lt4 ? i : s4);
                }
            }
        }
    }
    if (lane < KK) {
        E_idx[(size_t)g * KK + lane] = keepj;
        D_nb[(size_t)g * KK + lane] = keepd;
    }
}

__device__ __forceinline__ void packB(const float* __restrict__ src, short* __restrict__ dH,
                                      short* __restrict__ dL, int e, int KC, int N, int Kreal) {
    int j = e & 7, ln = (e >> 3) & 63, t = e >> 9;
    int kc = t % KC, nt = t / KC;
    int k = kc * 32 + (ln >> 4) * 8 + j;
    int n = nt * 16 + (ln & 15);
    float v = (k < Kreal) ? src[(size_t)k * N + n] : 0.f;
    short hi, lo; f2bf2(v, hi, lo);
    dH[e] = hi; dL[e] = lo;
}

__device__ void pack_body(int e,
                          const float* __restrict__ We, const float* __restrict__ Wq,
                          const float* __restrict__ lW1, const float* __restrict__ lW2,
                          const float* __restrict__ lW3, const float* __restrict__ lWi,
                          const float* __restrict__ lWo, const float* __restrict__ Wv,
                          short* __restrict__ WeP, short* __restrict__ WqP,
                          short* __restrict__ W1bP, short* __restrict__ W2P,
                          short* __restrict__ W3P, short* __restrict__ WiP,
                          short* __restrict__ WoP, short* __restrict__ W1acP,
                          short* __restrict__ WvP) {
    if (e < 8192) { packB(We, WeP, WeP + 8192, e, 2, 128, 39); return; }
    e -= 8192;
    if (e < 16384) { packB(Wq, WqP, WqP + 16384, e, 4, 128, 128); return; }
    e -= 16384;
    if (e < 49152) {
        int l = e >> 14, r = e & 16383;
        packB(lW1 + (size_t)l * 49152 + 16384, W1bP + l * 32768, W1bP + l * 32768 + 16384, r, 4, 128, 128);
        return;
    }
    e -= 49152;
    if (e < 49152) {
        int l = e >> 14, r = e & 16383;
        packB(lW2 + (size_t)l * 16384, W2P + l * 32768, W2P + l * 32768 + 16384, r, 4, 128, 128);
        return;
    }
    e -= 49152;
    if (e < 49152) {
        int l = e >> 14, r = e & 16383;
        packB(lW3 + (size_t)l * 16384, W3P + l * 32768, W3P + l * 32768 + 16384, r, 4, 128, 128);
        return;
    }
    e -= 49152;
    if (e < 196608) {
        int l = e / 65536, r = e % 65536;
        packB(lWi + (size_t)l * 65536, WiP + l * 131072, WiP + l * 131072 + 65536, r, 4, 512, 128);
        return;
    }
    e -= 196608;
    if (e < 196608) {
        int l = e / 65536, r = e % 65536;
        packB(lWo + (size_t)l * 65536, WoP + l * 131072, WoP + l * 131072 + 65536, r, 16, 128, 512);
        return;
    }
    e -= 196608;
    if (e < 98304) {
        int l = e / 32768, r = e % 32768;
        int j = r & 7, ln = (r >> 3) & 63, t = r >> 9;
        int kc = t & 3, nt = t >> 2;
        int k = kc * 32 + (ln >> 4) * 8 + j;
        int n = nt * 16 + (ln & 15);
        const float* base = lW1 + (size_t)l * 49152;
        float v = (n < 128) ? base[(size_t)k * 128 + n] : base[(size_t)(256 + k) * 128 + (n - 128)];
        short hi, lo; f2bf2(v, hi, lo);
        short* dH = W1acP + l * 65536;
        dH[r] = hi; dH[32768 + r] = lo;
        return;
    }
    e -= 98304;
    // Wv pack (16384 elements)
    packB(Wv, WvP, WvP + 16384, e, 4, 128, 128);
}

__device__ void orient_body(int t, const float* __restrict__ X,
                            float* __restrict__ AD, float* __restrict__ Of) {
    if (t >= BB * NN) return;
    int b = t / NN, n = t % NN;
    float* ad = AD + (size_t)t * 3;
    float* of = Of + (size_t)t * 9;
    if (n < 1 || n > NN - 3) {
        ad[0] = ad[1] = ad[2] = 0.f;
        #pragma unroll
        for (int i = 0; i < 9; i++) of[i] = 0.f;
        return;
    }
    const float* Xb = X + (size_t)b * NN * 3;
    float p0x = Xb[(n - 1) * 3], p0y = Xb[(n - 1) * 3 + 1], p0z = Xb[(n - 1) * 3 + 2];
    float p1x = Xb[n * 3],       p1y = Xb[n * 3 + 1],       p1z = Xb[n * 3 + 2];
    float p2x = Xb[(n + 1) * 3], p2y = Xb[(n + 1) * 3 + 1], p2z = Xb[(n + 1) * 3 + 2];
    float p3x = Xb[(n + 2) * 3], p3y = Xb[(n + 2) * 3 + 1], p3z = Xb[(n + 2) * 3 + 2];

    float u2x = p1x - p0x, u2y = p1y - p0y, u2z = p1z - p0z; norm3(u2x, u2y, u2z);
    float u1x = p2x - p1x, u1y = p2y - p1y, u1z = p2z - p1z; norm3(u1x, u1y, u1z);
    float u0x = p3x - p2x, u0y = p3y - p2y, u0z = p3z - p2z; norm3(u0x, u0y, u0z);

    float n2x = u2y * u1z - u2z * u1y, n2y = u2z * u1x - u2x * u1z, n2z = u2x * u1y - u2y * u1x;
    norm3(n2x, n2y, n2z);
    float n1x = u1y * u0z - u1z * u0y, n1y = u1z * u0x - u1x * u0z, n1z = u1x * u0y - u1y * u0x;
    norm3(n1x, n1y, n1z);

    float cosA = -(u1x * u0x + u1y * u0y + u1z * u0z);
    cosA = fminf(fmaxf(cosA, -1.f + EPSF), 1.f - EPSF);
    float A = acosf(cosA);
    float cosD = n2x * n1x + n2y * n1y + n2z * n1z;
    cosD = fminf(fmaxf(cosD, -1.f + EPSF), 1.f - EPSF);
    float sg = sgnf(u2x * n1x + u2y * n1y + u2z * n1z);
    float Dih = sg * acosf(cosD);

    ad[0] = cosf(A);
    ad[1] = sinf(A) * cosf(Dih);
    ad[2] = sinf(A) * sinf(Dih);

    float o1x = u2x - u1x, o1y = u2y - u1y, o1z = u2z - u1z; norm3(o1x, o1y, o1z);
    float cx = o1y * n2z - o1z * n2y, cy = o1z * n2x - o1x * n2z, cz = o1x * n2y - o1y * n2x;
    of[0] = o1x; of[1] = o1y; of[2] = o1z;
    of[3] = n2x; of[4] = n2y; of[5] = n2z;
    of[6] = cx;  of[7] = cy;  of[8] = cz;
}

// ---------- FRONT: knn (blocks 0..1023) | pack (1024..3679) | orient (3680..3695) ----------

__global__ __launch_bounds__(256) void front_kernel(const float* __restrict__ X,
                                                    const float* __restrict__ mask,
                                                    int* __restrict__ E_idx,
                                                    float* __restrict__ D_nb,
                                                    const float* __restrict__ We,
                                                    const float* __restrict__ Wq,
                                                    const float* __restrict__ lW1,
                                                    const float* __restrict__ lW2,
                                                    const float* __restrict__ lW3,
                                                    const float* __restrict__ lWi,
                                                    const float* __restrict__ lWo,
                                                    const float* __restrict__ Wv,
                                                    short* __restrict__ WeP,
                                                    short* __restrict__ WqP,
                                                    short* __restrict__ W1bP,
                                                    short* __restrict__ W2P,
                                                    short* __restrict__ W3P,
                                                    short* __restrict__ WiP,
                                                    short* __restrict__ WoP,
                                                    short* __restrict__ W1acP,
                                                    short* __restrict__ WvP,
                                                    float* __restrict__ ADb,
                                                    float* __restrict__ Ofb) {
    int blk = blockIdx.x;
    if (blk < KNN_BLK) {
        knn_body(blk, X, mask, E_idx, D_nb);
    } else if (blk < KNN_BLK + PACK_BLK) {
        pack_body((blk - KNN_BLK) * 256 + threadIdx.x,
                  We, Wq, lW1, lW2, lW3, lWi, lWo, Wv,
                  WeP, WqP, W1bP, W2P, W3P, WiP, WoP, W1acP, WvP);
    } else {
        orient_body((blk - KNN_BLK - PACK_BLK) * 256 + threadIdx.x, X, ADb, Ofb);
    }
}

// ---------- MID: edge_feat (blocks 0..4095) | node_feat16 (4096..4351) ----------
// edge_feat: independent global loads (E_idx, D_nb, Of[n], X[n]) issued at kernel
// top so their latency drains under bias staging + AefH zeroing; only the
// e-dependent gathers (Of[e], X[e]) remain after the first barrier, and e has
// long resolved by then.

__global__ __launch_bounds__(128) void mid_kernel(const float* __restrict__ X,
                                                  const int* __restrict__ E_idx,
                                                  const float* __restrict__ D_nb,
                                                  const float* __restrict__ Of,
                                                  const float* __restrict__ be,
                                                  const float* __restrict__ ge,
                                                  const float* __restrict__ he,
                                                  const float* __restrict__ bq,
                                                  const short* __restrict__ WeP,
                                                  const short* __restrict__ WqP,
                                                  unsigned short* __restrict__ hEbH,
                                                  const float* __restrict__ AD,
                                                  const float* __restrict__ Wn,
                                                  const float* __restrict__ bn,
                                                  const float* __restrict__ gn,
                                                  const float* __restrict__ hn,
                                                  const short* __restrict__ WvP,
                                                  const float* __restrict__ bv,
                                                  const short* __restrict__ W1acP0,
                                                  const float* __restrict__ b1_0,
                                                  float* __restrict__ hV,
                                                  float* __restrict__ P,
                                                  float* __restrict__ Q) {
    __shared__ __align__(16) char smemRaw[15872];

    if (blockIdx.x < (unsigned)(BB * NN)) {
        // ----- edge_feat body -----
        short* AefH = (short*)smemRaw;                 // 32*72*2   = 4608 B
        short* AeH  = (short*)(smemRaw + 4608);        // 32*136*2  = 8704 B
        float* beS  = (float*)(smemRaw + 13312);       // 512 B
        float* geS  = beS + HH;
        float* heS  = geS + HH;
        float* bqS  = heS + HH;
        float* redSe = (float*)(smemRaw + 15360);      // [2][2][32] = 512 B

        int bid = blockIdx.x; int b = bid >> 11, n = bid & 2047; int tid = threadIdx.x;
        int lane = tid & 63, w = tid >> 6;
        int part = tid >> 5, k = tid & 31;

        // --- hoisted independent global loads (issue before staging work) ---
        int e = E_idx[(size_t)bid * KK + k];
        float Dv = 0.f;
        if (part == 3) Dv = D_nb[(size_t)bid * KK + k];
        float Om[9], xn0 = 0.f, xn1 = 0.f, xn2 = 0.f;
        if (part == 0) {
            const float* Omp = Of + (size_t)(b * NN + n) * 9;
            #pragma unroll
            for (int i = 0; i < 9; i++) Om[i] = Omp[i];
            xn0 = X[(size_t)(b * NN + n) * 3 + 0];
            xn1 = X[(size_t)(b * NN + n) * 3 + 1];
            xn2 = X[(size_t)(b * NN + n) * 3 + 2];
        }

        beS[tid] = be[tid]; geS[tid] = ge[tid]; heS[tid] = he[tid]; bqS[tid] = bq[tid];
        {
            unsigned* Az = (unsigned*)AefH;
            for (int i = tid; i < 32 * 72 / 2; i += 128) Az[i] = 0u;
        }
        __syncthreads();

        float dpos = (float)e - (float)n;
        if (part == 1 || part == 2) {
            int p0 = (part - 1) * 4;
            #pragma unroll
            for (int p = 0; p < 4; p++) {
                // freq = 10000^(-(p0+p)/8) = 10^(-(p0+p)/2) — compile-time constants
                float fr = (part == 1)
                    ? ((p == 0) ? 1.f : (p == 1) ? 0.31622776601683794f
                       : (p == 2) ? 0.1f : 0.031622776601683791f)
                    : ((p == 0) ? 0.01f : (p == 1) ? 0.0031622776601683794f
                       : (p == 2) ? 0.001f : 0.00031622776601683794f);
                float ang = dpos * fr;
                AefH[k * 72 + p0 + p]     = (short)f2bf(__cosf(ang));
                AefH[k * 72 + 8 + p0 + p] = (short)f2bf(__sinf(ang));
            }
        } else if (part == 3) {
            #pragma unroll
            for (int i = 0; i < 16; i++) {
                float m = (20.f / 15.f) * (float)i;
                float z = (Dv - m) * 0.8f;
                AefH[k * 72 + 16 + i] = (short)f2bf(__expf(-z * z));
            }
        } else if (part == 0) {
            const float* Onp = Of + (size_t)(b * NN + e) * 9;
            float On[9];
            #pragma unroll
            for (int i = 0; i < 9; i++) On[i] = Onp[i];
            float vx = X[(size_t)(b * NN + e) * 3 + 0] - xn0;
            float vy = X[(size_t)(b * NN + e) * 3 + 1] - xn1;
            float vz = X[(size_t)(b * NN + e) * 3 + 2] - xn2;
            float t0 = Om[0] * vx + Om[1] * vy + Om[2] * vz;
            float t1 = Om[3] * vx + Om[4] * vy + Om[5] * vz;
            float t2 = Om[6] * vx + Om[7] * vy + Om[8] * vz;
            float nr = fmaxf(sqrtf(t0 * t0 + t1 * t1 + t2 * t2), 1e-12f);
            AefH[k * 72 + 32] = (short)f2bf(t0 / nr);
            AefH[k * 72 + 33] = (short)f2bf(t1 / nr);
            AefH[k * 72 + 34] = (short)f2bf(t2 / nr);
            float R[9];
            #pragma unroll
            for (int i = 0; i < 3; i++)
                #pragma unroll
                for (int l = 0; l < 3; l++)
                    R[i * 3 + l] = Om[0 + i] * On[0 + l] + Om[3 + i] * On[3 + l] + Om[6 + i] * On[6 + l];
            float Rxx = R[0], Ryy = R[4], Rzz = R[8];
            float mx = 0.5f * sqrtf(fabsf(1.f + Rxx - Ryy - Rzz));
            float my = 0.5f * sqrtf(fabsf(1.f - Rxx + Ryy - Rzz));
            float mz = 0.5f * sqrtf(fabsf(1.f - Rxx - Ryy + Rzz));
            float qx = sgnf(R[7] - R[5]) * mx;
            float qy = sgnf(R[2] - R[6]) * my;
            float qz = sgnf(R[3] - R[1]) * mz;
            float qw = 0.5f * sqrtf(fmaxf(1.f + Rxx + Ryy + Rzz, 0.f));
            float qn = fmaxf(sqrtf(qx * qx + qy * qy + qz * qz + qw * qw), 1e-12f);
            AefH[k * 72 + 35] = (short)f2bf(qx / qn);
            AefH[k * 72 + 36] = (short)f2bf(qy / qn);
            AefH[k * 72 + 37] = (short)f2bf(qz / qn);
            AefH[k * 72 + 38] = (short)f2bf(qw / qn);
        }
        __syncthreads();

        int m = lane & 15, q = lane >> 4;
        // A-frags: both row-tiles (t), this wave covers all 32 edges
        short8 aW[2][2];
        #pragma unroll
        for (int t = 0; t < 2; t++) {
            int row = (t * 16 + m) * 72;
            aW[t][0] = *(const short8*)&AefH[row + q * 8];
            aW[t][1] = *(const short8*)&AefH[row + 32 + q * 8];
        }
        f32x4 accA[4][2];   // [nt4][t]
        #pragma unroll
        for (int nt4 = 0; nt4 < 4; nt4++) {
            int ntg = w * 4 + nt4;
            const short* B0 = &WeP[((ntg * 2 + 0) * 64 + lane) * 8];
            const short* B1 = &WeP[((ntg * 2 + 1) * 64 + lane) * 8];
            short8 b0h = *(const short8*)B0, b0l = *(const short8*)(B0 + 8192);
            short8 b1h = *(const short8*)B1, b1l = *(const short8*)(B1 + 8192);
            float bc = beS[ntg * 16 + m];
            #pragma unroll
            for (int t = 0; t < 2; t++) {
                f32x4 acc = {bc, bc, bc, bc};
                acc = MFMA16(aW[t][0], b0h, acc);
                acc = MFMA16(aW[t][0], b0l, acc);
                acc = MFMA16(aW[t][1], b1h, acc);
                acc = MFMA16(aW[t][1], b1l, acc);
                accA[nt4][t] = acc;
            }
        }
        // cross-wave LN: partial su/sq per row over this wave's 64 cols
        #pragma unroll
        for (int t = 0; t < 2; t++)
            #pragma unroll
            for (int r = 0; r < 4; r++) {
                float su = accA[0][t][r] + accA[1][t][r] + accA[2][t][r] + accA[3][t][r];
                float sq2 = accA[0][t][r] * accA[0][t][r] + accA[1][t][r] * accA[1][t][r]
                          + accA[2][t][r] * accA[2][t][r] + accA[3][t][r] * accA[3][t][r];
                #pragma unroll
                for (int off = 1; off <= 8; off <<= 1) {
                    su += __shfl_xor(su, off); sq2 += __shfl_xor(sq2, off);
                }
                if (m == 0) {
                    int row = t * 16 + q * 4 + r;
                    redSe[(w * 2 + 0) * 32 + row] = su;
                    redSe[(w * 2 + 1) * 32 + row] = sq2;
                }
            }
        __syncthreads();
        float muA[2][4], invA[2][4];
        #pragma unroll
        for (int t = 0; t < 2; t++)
            #pragma unroll
            for (int r = 0; r < 4; r++) {
                int row = t * 16 + q * 4 + r;
                float S  = redSe[0 * 32 + row] + redSe[2 * 32 + row];
                float Q2 = redSe[1 * 32 + row] + redSe[3 * 32 + row];
                float mu = S * (1.f / HH);
                float var = (Q2 - (float)HH * mu * mu) * (1.f / (HH - 1));
                muA[t][r] = mu;
                invA[t][r] = 1.f / (sqrtf(var + EPSF) + EPSF);
            }
        #pragma unroll
        for (int nt4 = 0; nt4 < 4; nt4++) {
            int col = (w * 4 + nt4) * 16 + m;
            float g = geS[col], hh = heS[col];
            #pragma unroll
            for (int t = 0; t < 2; t++)
                #pragma unroll
                for (int r = 0; r < 4; r++) {
                    int edge = t * 16 + q * 4 + r;
                    float y = g * (accA[nt4][t][r] - muA[t][r]) * invA[t][r] + hh;
                    AeH[edge * 136 + col] = (short)f2bf(y);
                }
        }
        __syncthreads();

        short8 ah[2][4];
        #pragma unroll
        for (int t = 0; t < 2; t++)
            #pragma unroll
            for (int kc = 0; kc < 4; kc++)
                ah[t][kc] = *(const short8*)&AeH[(t * 16 + m) * 136 + kc * 32 + q * 8];
        __syncthreads();   // all A-frag preloads done — AeH becomes output staging

        #pragma unroll
        for (int nt4 = 0; nt4 < 4; nt4++) {
            int ntg = w * 4 + nt4;
            int col = ntg * 16 + m;
            short8 qh[4], ql[4];
            #pragma unroll
            for (int kc = 0; kc < 4; kc++) {
                const short* Bp = &WqP[((ntg * 4 + kc) * 64 + lane) * 8];
                qh[kc] = *(const short8*)Bp;
                ql[kc] = *(const short8*)(Bp + 16384);
            }
            float bc = bqS[col];
            #pragma unroll
            for (int t = 0; t < 2; t++) {
                f32x4 acc = {bc, bc, bc, bc};
                #pragma unroll
                for (int kc = 0; kc < 4; kc++) {
                    acc = MFMA16(ah[t][kc], qh[kc], acc);
                    acc = MFMA16(ah[t][kc], ql[kc], acc);
                }
                #pragma unroll
                for (int r = 0; r < 4; r++) {
                    int edge = t * 16 + q * 4 + r;
                    AeH[edge * 136 + col] = (short)f2bf(acc[r]);
                }
            }
        }
        __syncthreads();

        // coalesced copy-out: 512 short8 chunks, 4 per thread (256B contiguous/row)
        {
            unsigned short* outp = hEbH + (size_t)bid * (KK * HH);
            #pragma unroll
            for (int it = 0; it < 4; it++) {
                int idx = it * 128 + tid;       // 0..511
                int row = idx >> 4, c8 = idx & 15;
                *(short8*)(outp + row * HH + c8 * 8) = *(const short8*)&AeH[row * 136 + c8 * 8];
            }
        }
    } else {
        // ----- node_feat body: 16 nodes per block, MFMA path -----
        short* yH  = (short*)smemRaw;                  // 16*136*2 = 4352 B
        short* hvH = (short*)(smemRaw + 4352);         // 4352 B

        int nb = blockIdx.x - BB * NN;
        int g0 = nb * 16;
        int tid = threadIdx.x;
        int lane = tid & 63, w = tid >> 6;
        int m = lane & 15, q = lane >> 4;

        // step 1: V = AD @ Wn + bn, per-node LN -> y (bf16 in LDS)
        {
            int i = tid >> 3;          // node 0..15
            int j = tid & 7;           // column group (16 cols each)
            int h0 = j * 16;
            const float* ad = AD + (size_t)(g0 + i) * 3;
            float a0 = ad[0], a1 = ad[1], a2 = ad[2];
            float v[16];
            float su = 0.f, sq = 0.f;
            #pragma unroll
            for (int c = 0; c < 16; c++) {
                int h = h0 + c;
                float t = bn[h] + a0 * Wn[h] + a1 * Wn[HH + h] + a2 * Wn[2 * HH + h];
                v[c] = t; su += t; sq += t * t;
            }
            #pragma unroll
            for (int off = 1; off <= 4; off <<= 1) {
                su += __shfl_xor(su, off); sq += __shfl_xor(sq, off);
            }
            float mu = su * (1.f / HH);
            float var = (sq - (float)HH * mu * mu) * (1.f / (HH - 1));
            float inv = 1.f / (sqrtf(var + EPSF) + EPSF);
            #pragma unroll
            for (int c = 0; c < 16; c++) {
                int h = h0 + c;
                yH[i * 136 + h] = (short)f2bf(gn[h] * (v[c] - mu) * inv + hn[h]);
            }
        }
        __syncthreads();

        // step 2: hV = y @ Wv + bv  (wave handles 4 of 8 col-tiles)
        short8 ayh[4];
        #pragma unroll
        for (int kc = 0; kc < 4; kc++)
            ayh[kc] = *(const short8*)&yH[m * 136 + kc * 32 + q * 8];
        #pragma unroll
        for (int u = 0; u < 4; u++) {
            int nt = w * 4 + u;
            int col = nt * 16 + m;
            float bc = bv[col];
            f32x4 a = {bc, bc, bc, bc};
            #pragma unroll
            for (int kc = 0; kc < 4; kc++) {
                const short* Bp = &WvP[((nt * 4 + kc) * 64 + lane) * 8];
                short8 bh = *(const short8*)Bp, bl = *(const short8*)(Bp + 16384);
                a = MFMA16(ayh[kc], bh, a);
                a = MFMA16(ayh[kc], bl, a);
            }
            #pragma unroll
            for (int r = 0; r < 4; r++) {
                int rw = q * 4 + r;
                hV[(size_t)(g0 + rw) * HH + col] = a[r];
                hvH[rw * 136 + col] = (short)f2bf(a[r]);
            }
        }
        __syncthreads();

        // step 3: layer-0 premix P/Q = hV @ W1_0[a|c] (+b1 for P), via packed W1acP[0]
        short8 avh[4];
        #pragma unroll
        for (int kc = 0; kc < 4; kc++)
            avh[kc] = *(const short8*)&hvH[m * 136 + kc * 32 + q * 8];
        #pragma unroll
        for (int u = 0; u < 8; u++) {
            int nt = w * 8 + u;
            int col = nt * 16 + m;
            float b0 = (nt < 8) ? b1_0[col] : 0.f;
            f32x4 a = {b0, b0, b0, b0};
            #pragma unroll
            for (int kc = 0; kc < 4; kc++) {
                const short* Bp = &W1acP0[((nt * 4 + kc) * 64 + lane) * 8];
                short8 bh = *(const short8*)Bp, bl = *(const short8*)(Bp + 32768);
                a = MFMA16(avh[kc], bh, a);
                a = MFMA16(avh[kc], bl, a);
            }
            #pragma unroll
            for (int r = 0; r < 4; r++) {
                size_t rw = g0 + q * 4 + r;
                if (nt < 8) P[rw * HH + col] = a[r];
                else        Q[rw * HH + (col - 128)] = a[r];
            }
        }
    }
}

// ---------- message kernel: block = 2 nodes, 4 waves, 2 nt-tiles per wave ----------
// (r7 form) A-side staged in LDS; weights loaded once per nt-tile per wave and
// reused for both nodes. Q gathers hoisted to registers before the staging
// barrier so their latency overlaps the LDS staging drain.

__global__ __launch_bounds__(256) void msg_kernel(const float* __restrict__ mask,
                                                  const int* __restrict__ E_idx,
                                                  const unsigned short* __restrict__ hEbH,
                                                  const float* __restrict__ P,
                                                  const float* __restrict__ Q,
                                                  const short* __restrict__ W1bP,
                                                  const short* __restrict__ W2P,
                                                  const float* __restrict__ b2,
                                                  float* __restrict__ sOut,
                                                  float* __restrict__ cntOut) {
    __shared__ short stg[2][32 * 136];   // staged h_E (bf16) per node
    __shared__ short AmH[2][32 * 136];   // m1 (bf16) per node

    int tid = threadIdx.x;
    int w = tid >> 6, lane = tid & 63;
    int gA = blockIdx.x * 2;             // nodes gA, gA+1 (same batch: NN even)
    int b = gA >> 11;
    int m = lane & 15, q = lane >> 4;

    // ---- stage hEbH for both nodes (fully coalesced short8 loads) ----
    {
        const short8* src = (const short8*)(hEbH + (size_t)gA * (KK * HH));
        #pragma unroll
        for (int it = 0; it < 4; it++) {
            int idx = it * 256 + tid;        // 0..1023 short8 chunks
            int nd = idx >> 9;
            int rem = idx & 511;
            int e = rem >> 4;                // edge
            int c8 = rem & 15;               // col/8
            short8 v = src[idx];
            *(short8*)&stg[nd][e * 136 + c8 * 8] = v;
        }
    }

    int qbase[2][2][4]; float mt[2][2][4];
    #pragma unroll
    for (int nd = 0; nd < 2; nd++) {
        float maskv = mask[gA + nd];
        #pragma unroll
        for (int t = 0; t < 2; t++)
            #pragma unroll
            for (int r = 0; r < 4; r++) {
                int row = t * 16 + q * 4 + r;
                int e = E_idx[(size_t)(gA + nd) * KK + row];
                qbase[nd][t][r] = (b * NN + e) * HH;
                mt[nd][t][r] = maskv * mask[b * NN + e];
            }
    }
    if (w < 2) {
        // wave w (0,1) produces cnt for node w
        float c8 = mt[w][0][0] + mt[w][0][1] + mt[w][0][2] + mt[w][0][3]
                 + mt[w][1][0] + mt[w][1][1] + mt[w][1][2] + mt[w][1][3];
        c8 += __shfl_xor(c8, 16);
        c8 += __shfl_xor(c8, 32);
        if (lane == 0) cntOut[gA + w] = c8;
    }

    float preg[2][2], b2reg[2];
    #pragma unroll
    for (int u = 0; u < 2; u++) {
        int colg = (w * 2 + u) * 16 + m;
        b2reg[u] = b2[colg];
        preg[0][u] = P[(size_t)gA * HH + colg];
        preg[1][u] = P[(size_t)(gA + 1) * HH + colg];
    }

    // prefetch all Q gathers (32 scattered loads) — overlap with staging barrier
    float qv[2][2][2][4];   // [u][nd][t][r]
    #pragma unroll
    for (int u = 0; u < 2; u++) {
        int colg = (w * 2 + u) * 16 + m;
        #pragma unroll
        for (int nd = 0; nd < 2; nd++)
            #pragma unroll
            for (int t = 0; t < 2; t++)
                #pragma unroll
                for (int r = 0; r < 4; r++)
                    qv[u][nd][t][r] = Q[(size_t)qbase[nd][t][r] + colg];
    }
    __syncthreads();

    // phase 1: m1 = relu(P + Q[nbr] + h_E @ W1b) — wave handles 2 nt tiles, both nodes
    #pragma unroll
    for (int u = 0; u < 2; u++) {
        int ntg = w * 2 + u;
        int colg = ntg * 16 + m;
        short8 bh[4], bl[4];
        #pragma unroll
        for (int kc = 0; kc < 4; kc++) {
            const short* Bp = &W1bP[((ntg * 4 + kc) * 64 + lane) * 8];
            bh[kc] = *(const short8*)Bp;
            bl[kc] = *(const short8*)(Bp + 16384);
        }
        #pragma unroll
        for (int nd = 0; nd < 2; nd++) {
            f32x4 t0 = {0.f, 0.f, 0.f, 0.f}, t1 = {0.f, 0.f, 0.f, 0.f};
            #pragma unroll
            for (int kc = 0; kc < 4; kc++) {
                short8 a0 = *(const short8*)&stg[nd][(0 * 16 + m) * 136 + kc * 32 + q * 8];
                short8 a1 = *(const short8*)&stg[nd][(1 * 16 + m) * 136 + kc * 32 + q * 8];
                t0 = MFMA16(a0, bh[kc], t0);
                t0 = MFMA16(a0, bl[kc], t0);
                t1 = MFMA16(a1, bh[kc], t1);
                t1 = MFMA16(a1, bl[kc], t1);
            }
            float pp = preg[nd][u];
            #pragma unroll
            for (int r = 0; r < 4; r++) {
                float v0 = fmaxf(t0[r] + pp + qv[u][nd][0][r], 0.f);
                AmH[nd][(q * 4 + r) * 136 + colg] = (short)f2bf(v0);
                float v1 = fmaxf(t1[r] + pp + qv[u][nd][1][r], 0.f);
                AmH[nd][(16 + q * 4 + r) * 136 + colg] = (short)f2bf(v1);
            }
        }
    }
    __syncthreads();

    // phase 2: m2 = relu(m1 @ W2 + b2); masked sum over 32 edges
    #pragma unroll
    for (int u = 0; u < 2; u++) {
        int ntg = w * 2 + u;
        short8 bh[4], bl[4];
        #pragma unroll
        for (int kc = 0; kc < 4; kc++) {
            const short* Bp = &W2P[((ntg * 4 + kc) * 64 + lane) * 8];
            bh[kc] = *(const short8*)Bp;
            bl[kc] = *(const short8*)(Bp + 16384);
        }
        float bc = b2reg[u];
        #pragma unroll
        for (int nd = 0; nd < 2; nd++) {
            f32x4 a0 = {bc, bc, bc, bc}, a1 = {bc, bc, bc, bc};
            #pragma unroll
            for (int kc = 0; kc < 4; kc++) {
                short8 m0 = *(const short8*)&AmH[nd][(0 * 16 + m) * 136 + kc * 32 + q * 8];
                short8 m1 = *(const short8*)&AmH[nd][(1 * 16 + m) * 136 + kc * 32 + q * 8];
                a0 = MFMA16(m0, bh[kc], a0);
                a0 = MFMA16(m0, bl[kc], a0);
                a1 = MFMA16(m1, bh[kc], a1);
                a1 = MFMA16(m1, bl[kc], a1);
            }
            float part = 0.f;
            #pragma unroll
            for (int r = 0; r < 4; r++)
                part += fmaxf(a0[r], 0.f) * mt[nd][0][r] + fmaxf(a1[r], 0.f) * mt[nd][1][r];
            part += __shfl_xor(part, 16);
            part += __shfl_xor(part, 32);
            if (q == 0) sOut[(size_t)(gA + nd) * HH + ntg * 16 + m] = part;
        }
    }
}

// ---------- node kernel: 8 waves (512 threads), 16 nodes/block ----------
// hVin residual + LN1 mask loads hoisted to kernel top: their L2 latency drains
// under the W3/FFN MFMA work instead of stalling the LN barriers.

#define HSTR 520   // LDS stride (shorts) for 512-wide hidden staging

__global__ __launch_bounds__(512, 2) void node_kernel(const float* __restrict__ mask,
                                                      const float* __restrict__ sbuf,
                                                      const float* __restrict__ cntb,
                                                      const float* __restrict__ hVin,
                                                      const short* __restrict__ W3P,
                                                      const float* __restrict__ b3,
                                                      const short* __restrict__ WiP,
                                                      const float* __restrict__ biN,
                                                      const short* __restrict__ WoP,
                                                      const float* __restrict__ boN,
                                                      const float* __restrict__ g0,
                                                      const float* __restrict__ h0,
                                                      const float* __restrict__ g1,
                                                      const float* __restrict__ h1,
                                                      const short* __restrict__ W1P,
                                                      const float* __restrict__ b1n,
                                                      float* __restrict__ hVout,
                                                      float* __restrict__ Pn,
                                                      float* __restrict__ Qn) {
    __shared__ short rbH[16 * 136];
    __shared__ short hbH[16 * HSTR];
    __shared__ float redS[8][2][16];
    __shared__ float g0S[128], h0S[128], g1S[128], h1S[128], b3S[128], boS[128], b1S[128];
    __shared__ float biS[512];

    int tid = threadIdx.x;
    int w = tid >> 6, lane = tid & 63;
    int m = lane & 15, q = lane >> 4;
    int rowT = blockIdx.x * 16;

    if (tid < 128) {
        int i = tid;
        g0S[i] = g0[i]; h0S[i] = h0[i]; g1S[i] = g1[i]; h1S[i] = h1[i];
        b3S[i] = b3[i]; boS[i] = boN[i]; b1S[i] = W1P ? b1n[i] : 0.f;
    }
    biS[tid] = biN[tid];

    // hoisted independent global loads (drain under MFMA work below)
    short8 ash[4];
    #pragma unroll
    for (int kc = 0; kc < 4; kc++) {
        const float* sp = &sbuf[(size_t)(rowT + m) * HH + kc * 32 + q * 8];
        f32x4 x0 = *(const f32x4*)sp;
        f32x4 x1 = *(const f32x4*)(sp + 4);
        ash[kc] = cvt8h(x0, x1);
    }
    float cntr[4], hvr[4], mk[4];
    {
        int col = w * 16 + m;
        #pragma unroll
        for (int r = 0; r < 4; r++) {
            cntr[r] = cntb[rowT + q * 4 + r];
            hvr[r]  = hVin[(size_t)(rowT + q * 4 + r) * HH + col];
            mk[r]   = mask[rowT + q * 4 + r];
        }
    }
    __syncthreads();

    // W3: wave w owns col-tile w
    f32x4 vC;
    {
        f32x4 a = {0.f, 0.f, 0.f, 0.f};
        #pragma unroll
        for (int kc = 0; kc < 4; kc++) {
            const short* Bp = &W3P[((w * 4 + kc) * 64 + lane) * 8];
            short8 bh = *(const short8*)Bp, bl = *(const short8*)(Bp + 16384);
            a = MFMA16(ash[kc], bh, a);
            a = MFMA16(ash[kc], bl, a);
        }
        int col = w * 16 + m;
        #pragma unroll
        for (int r = 0; r < 4; r++) {
            float tv = (a[r] + cntr[r] * b3S[col]) * (1.f / 30.f);
            a[r] = hvr[r] + tv;
        }
        vC = a;
    }

    // LN0 (cross-8-wave)
    {
        float su[4], sq[4];
        #pragma unroll
        for (int r = 0; r < 4; r++) { float v = vC[r]; su[r] = v; sq[r] = v * v; }
        #pragma unroll
        for (int off = 1; off <= 8; off <<= 1)
            #pragma unroll
            for (int r = 0; r < 4; r++) { su[r] += __shfl_xor(su[r], off); sq[r] += __shfl_xor(sq[r], off); }
        if (m == 0) {
            #pragma unroll
            for (int r = 0; r < 4; r++) { redS[w][0][q * 4 + r] = su[r]; redS[w][1][q * 4 + r] = sq[r]; }
        }
    }
    __syncthreads();
    float mu[4], inv[4];
    #pragma unroll
    for (int r = 0; r < 4; r++) {
        int row = q * 4 + r;
        float S = 0.f, Q2 = 0.f;
        #pragma unroll
        for (int ww = 0; ww < 8; ww++) { S += redS[ww][0][row]; Q2 += redS[ww][1][row]; }
        mu[r] = S * (1.f / HH);
        float var = (Q2 - (float)HH * mu[r] * mu[r]) * (1.f / (HH - 1));
        inv[r] = 1.f / (sqrtf(var + EPSF) + EPSF);
    }
    {
        int col = w * 16 + m;
        #pragma unroll
        for (int r = 0; r < 4; r++) {
            vC[r] = g0S[col] * (vC[r] - mu[r]) * inv[r] + h0S[col];
            rbH[(q * 4 + r) * 136 + col] = (short)f2bf(vC[r]);
        }
    }
    __syncthreads();

    short8 avh[4];
    #pragma unroll
    for (int kc = 0; kc < 4; kc++)
        avh[kc] = *(const short8*)&rbH[m * 136 + kc * 32 + q * 8];

    // FFN-in: wave's 64 hidden cols (4 of 32 tiles)
    #pragma unroll
    for (int u = 0; u < 4; u++) {
        int nt = w * 4 + u;
        int jcol = nt * 16 + m;
        float bb = biS[jcol];
        f32x4 a = {bb, bb, bb, bb};
        #pragma unroll
        for (int kc = 0; kc < 4; kc++) {
            const short* Bp = &WiP[((nt * 4 + kc) * 64 + lane) * 8];
            short8 bh = *(const short8*)Bp, bl = *(const short8*)(Bp + 65536);
            a = MFMA16(avh[kc], bh, a);
            a = MFMA16(avh[kc], bl, a);
        }
        #pragma unroll
        for (int r = 0; r < 4; r++)
            hbH[(q * 4 + r) * HSTR + jcol] = (short)f2bf(fmaxf(a[r], 0.f));
    }
    __syncthreads();

    // FFN-out: wave's col-tile w over ALL 512 hidden
    f32x4 oC = {0.f, 0.f, 0.f, 0.f};
    for (int kc2 = 0; kc2 < 16; kc2++) {
        short8 ahh = *(const short8*)&hbH[m * HSTR + kc2 * 32 + q * 8];
        const short* Bp = &WoP[((w * 16 + kc2) * 64 + lane) * 8];
        short8 bh = *(const short8*)Bp, bl = *(const short8*)(Bp + 65536);
        oC = MFMA16(ahh, bh, oC);
        oC = MFMA16(ahh, bl, oC);
    }
    {
        int col = w * 16 + m;
        #pragma unroll
        for (int r = 0; r < 4; r++)
            oC[r] += boS[col] + vC[r];
    }

    // LN1 (cross-8-wave)
    {
        float su[4], sq[4];
        #pragma unroll
        for (int r = 0; r < 4; r++) { float v = oC[r]; su[r] = v; sq[r] = v * v; }
        #pragma unroll
        for (int off = 1; off <= 8; off <<= 1)
            #pragma unroll
            for (int r = 0; r < 4; r++) { su[r] += __shfl_xor(su[r], off); sq[r] += __shfl_xor(sq[r], off); }
        __syncthreads();   // redS reuse
        if (m == 0) {
            #pragma unroll
            for (int r = 0; r < 4; r++) { redS[w][0][q * 4 + r] = su[r]; redS[w][1][q * 4 + r] = sq[r]; }
        }
    }
    __syncthreads();
    #pragma unroll
    for (int r = 0; r < 4; r++) {
        int row = q * 4 + r;
        float S = 0.f, Q2 = 0.f;
        #pragma unroll
        for (int ww = 0; ww < 8; ww++) { S += redS[ww][0][row]; Q2 += redS[ww][1][row]; }
        mu[r] = S * (1.f / HH);
        float var = (Q2 - (float)HH * mu[r] * mu[r]) * (1.f / (HH - 1));
        inv[r] = 1.f / (sqrtf(var + EPSF) + EPSF);
    }
    {
        int col = w * 16 + m;
        #pragma unroll
        for (int r = 0; r < 4; r++) {
            float y = g1S[col] * (oC[r] - mu[r]) * inv[r] + h1S[col];
            y *= mk[r];
            oC[r] = y;
            hVout[(size_t)(rowT + q * 4 + r) * HH + col] = y;
        }
    }

    // fused next-layer premix (wave's 2 of 16 col-tiles)
    if (W1P) {
        __syncthreads();
        {
            int col = w * 16 + m;
            #pragma unroll
            for (int r = 0; r < 4; r++)
                rbH[(q * 4 + r) * 136 + col] = (short)f2bf(oC[r]);
        }
        __syncthreads();
        short8 ayh[4];
        #pragma unroll
        for (int kc = 0; kc < 4; kc++)
            ayh[kc] = *(const short8*)&rbH[m * 136 + kc * 32 + q * 8];
        #pragma unroll
        for (int u = 0; u < 2; u++) {
            int nt = w * 2 + u;
            int col = nt * 16 + m;
            float b0 = (nt < 8) ? b1S[col] : 0.f;
            f32x4 a = {b0, b0, b0, b0};
            #pragma unroll
            for (int kc = 0; kc < 4; kc++) {
                const short* Bp = &W1P[((nt * 4 + kc) * 64 + lane) * 8];
                short8 bh = *(const short8*)Bp, bl = *(const short8*)(Bp + 32768);
                a = MFMA16(ayh[kc], bh, a);
                a = MFMA16(ayh[kc], bl, a);
            }
            #pragma unroll
            for (int r = 0; r < 4; r++) {
                size_t row = rowT + q * 4 + r;
                if (nt < 8) Pn[row * HH + col] = a[r];
                else        Qn[row * HH + (col - 128)] = a[r];
            }
        }
    }
}

// ---------- launch ----------

extern "C" void kernel_launch(void* const* d_in, const int* in_sizes, int n_in,
                              void* d_out, int out_size, void* d_ws, size_t ws_size,
                              hipStream_t stream) {
    const float* X    = (const float*)d_in[0];
    const float* mask = (const float*)d_in[1];
    const float* Wn   = (const float*)d_in[2];
    const float* bn   = (const float*)d_in[3];
    const float* gn   = (const float*)d_in[4];
    const float* hn   = (const float*)d_in[5];
    const float* We   = (const float*)d_in[6];
    const float* be   = (const float*)d_in[7];
    const float* ge   = (const float*)d_in[8];
    const float* he   = (const float*)d_in[9];
    const float* Wv   = (const float*)d_in[10];
    const float* bv   = (const float*)d_in[11];
    const float* Wq   = (const float*)d_in[12];
    const float* bq   = (const float*)d_in[13];
    const float* lW1  = (const float*)d_in[14];
    const float* lb1  = (const float*)d_in[15];
    const float* lW2  = (const float*)d_in[16];
    const float* lb2  = (const float*)d_in[17];
    const float* lW3  = (const float*)d_in[18];
    const float* lb3  = (const float*)d_in[19];
    const float* lWi  = (const float*)d_in[20];
    const float* lbi  = (const float*)d_in[21];
    const float* lWo  = (const float*)d_in[22];
    const float* lbo  = (const float*)d_in[23];
    const float* lg0  = (const float*)d_in[24];
    const float* lh0  = (const float*)d_in[25];
    const float* lg1  = (const float*)d_in[26];
    const float* lh1  = (const float*)d_in[27];

    char* ws = (char*)d_ws;
    size_t off = 0;
    auto alloc = [&](size_t nbytes) { void* p = ws + off; off += (nbytes + 15) & ~(size_t)15; return p; };
    int*   E_idx = (int*)  alloc((size_t)BB * NN * KK * 4);
    float* D_nb  = (float*)alloc((size_t)BB * NN * KK * 4);
    float* ADb   = (float*)alloc((size_t)BB * NN * 3 * 4);
    float* Ofb   = (float*)alloc((size_t)BB * NN * 9 * 4);
    float* hV    = (float*)alloc((size_t)BB * NN * HH * 4);
    unsigned short* hEbH = (unsigned short*)alloc((size_t)BB * NN * KK * HH * 2);
    float* Pb    = (float*)alloc((size_t)BB * NN * HH * 4);
    float* Qb    = (float*)alloc((size_t)BB * NN * HH * 4);
    float* sBuf  = (float*)alloc((size_t)BB * NN * HH * 4);
    float* cntB  = (float*)alloc((size_t)BB * NN * 4);
    short* WeP   = (short*)alloc(2 * 8192 * 2);
    short* WqP   = (short*)alloc(2 * 16384 * 2);
    short* W1bP  = (short*)alloc(3 * 2 * 16384 * 2);
    short* W2P   = (short*)alloc(3 * 2 * 16384 * 2);
    short* W3P   = (short*)alloc(3 * 2 * 16384 * 2);
    short* WiP   = (short*)alloc(3 * 2 * 65536 * 2);
    short* WoP   = (short*)alloc(3 * 2 * 65536 * 2);
    short* W1acP = (short*)alloc(3 * 2 * 32768 * 2);
    short* WvP   = (short*)alloc(2 * 16384 * 2);
    if (off > ws_size) return;

    // Dispatch 1: knn | pack | orient (mutually independent)
    front_kernel<<<KNN_BLK + PACK_BLK + ORIENT_BLK, 256, 0, stream>>>(
        X, mask, E_idx, D_nb,
        We, Wq, lW1, lW2, lW3, lWi, lWo, Wv,
        WeP, WqP, W1bP, W2P, W3P, WiP, WoP, W1acP, WvP,
        ADb, Ofb);

    // Dispatch 2: edge_feat | node_feat16 (mutually independent; both need dispatch 1)
    mid_kernel<<<BB * NN + BB * NN / 16, 128, 0, stream>>>(
        X, E_idx, D_nb, Ofb, be, ge, he, bq, WeP, WqP, hEbH,
        ADb, Wn, bn, gn, hn, WvP, bv, W1acP, lb1, hV, Pb, Qb);

    for (int l = 0; l < 3; l++) {
        int last = (l == 2);
        msg_kernel<<<BB * NN / 2, 256, 0, stream>>>(
            mask, E_idx, hEbH, Pb, Qb,
            W1bP + (size_t)l * 32768,
            W2P + (size_t)l * 32768, lb2 + (size_t)l * HH,
            sBuf, cntB);
        node_kernel<<<BB * NN / 16, 512, 0, stream>>>(
            mask, sBuf, cntB, hV,
            W3P + (size_t)l * 32768, lb3 + (size_t)l * HH,
            WiP + (size_t)l * 131072, lbi + (size_t)l * DFF,
            WoP + (size_t)l * 131072, lbo + (size_t)l * HH,
            lg0 + (size_t)l * HH, lh0 + (size_t)l * HH,
            lg1 + (size_t)l * HH, lh1 + (size_t)l * HH,
            last ? nullptr : (W1acP + (size_t)(l + 1) * 65536),
            last ? nullptr : (lb1 + (size_t)(l + 1) * HH),
            last ? (float*)d_out : hV,
            Pb, Qb);
    }
}